// Round 5
// baseline (493.020 us; speedup 1.0000x reference)
//
#include <hip/hip_runtime.h>
#include <math.h>

#define DEV __device__ __forceinline__

DEV float sigm(float x){ return 1.f/(1.f+__expf(-x)); }
DEV float siluf(float x){ return x * sigm(x); }
DEV float softplusf(float x){ return x > 20.f ? x : log1pf(__expf(x)); }

static constexpr float NG = 131072.0f;   // group-norm element count per (b,g): 32*64*64

// ---- workspace layout (offsets in floats) ----
static constexpr size_t WS_H1    = 0;          // B*HW*128
static constexpr size_t WS_H1PRE = 1048576;    // B*HW*128 (reused as yproj)
static constexpr size_t WS_XC    = 2097152;    // B*HW*256 (spa xc; later spe xc2[tok][64])
static constexpr size_t WS_ZSIL  = 4194304;    // B*HW*256 (spa zsil; later spe xc2T[64][tok])
static constexpr size_t WS_XZ    = 6291456;    // B*HW*512  (xz x-part; later delta; later spe zsil2)
static constexpr size_t WS_DELTA = 6291456;    // B*HW*256
static constexpr size_t WS_BM    = 8388608;    // B*HW*16 (later spe proj[tok][36])
static constexpr size_t WS_CM    = 8519680;    // B*HW*16
static constexpr size_t WS_LOG   = 8650752;    // B*HW*16 (logits, stride 16, 10 used)
static constexpr size_t WS_Y     = 10485760;   // B*HW*256 (y; pe partials; spe yg; later e_pre)
static constexpr size_t WS_P     = 12582912;   // [b][chunk][4096] (after scan2: dw partials)
static constexpr size_t WS_Q     = 13107200;   // (after scan2: spe partials)
static constexpr size_t WS_HS    = 13631488;   // (after scan3: outproj partials)
static constexpr size_t WS_Y2    = 14155776;   // B*HW*128
static constexpr size_t WS_FEAT  = 15204352;   // B*HW*128
static constexpr size_t WS_STATS = 16252928;   // 64 floats: pe@0 spa@16 spe@32 ref@48
static constexpr size_t WS_PEWT  = 16253056;   // 128*128
static constexpr size_t WS_INWT  = WS_PEWT  + 16384;  // 128*512
static constexpr size_t WS_OUTWT = WS_INWT  + 65536;  // 256*128
static constexpr size_t WS_XPWT  = WS_OUTWT + 32768;  // 256*40

// ---------------- partial-stats reduction: grid = 16 (b in 0..1, j in 0..7) ----
__global__ void __launch_bounds__(256)
k_red(const float* __restrict__ part, float* __restrict__ outS, int half){
  __shared__ float red[4];
  int b = blockIdx.x >> 3, j = blockIdx.x & 7;
  float s = 0.f;
  for (int i = b*half + threadIdx.x; i < (b+1)*half; i += 256)
    s += part[(size_t)i*8 + j];
  s += __shfl_xor(s,1); s += __shfl_xor(s,2); s += __shfl_xor(s,4);
  s += __shfl_xor(s,8); s += __shfl_xor(s,16); s += __shfl_xor(s,32);
  if ((threadIdx.x & 63) == 0) red[threadIdx.x>>6] = s;
  __syncthreads();
  if (threadIdx.x == 0) outS[b*8+j] = red[0]+red[1]+red[2]+red[3];
}

// ---------------- transpose weights (spa side only) ----------------
__global__ void __launch_bounds__(256)
k_transpose(const float* __restrict__ pe_w, const float* __restrict__ in_w,
            const float* __restrict__ out_w, const float* __restrict__ xp_w,
            float* __restrict__ peT, float* __restrict__ inT,
            float* __restrict__ outT, float* __restrict__ xpT){
  int i0 = blockIdx.x*256 + threadIdx.x;
  int nt = gridDim.x*256;
  for (int k = i0; k < 128*128; k += nt){ int r = k >> 7, c = k & 127; peT[c*128 + r] = pe_w[k]; }
  for (int k = i0; k < 512*128; k += nt){ int r = k >> 7, c = k & 127; inT[c*512 + r] = in_w[k]; }
  for (int k = i0; k < 128*256; k += nt){ int r = k >> 8, c = k & 255; outT[c*128 + r] = out_w[k]; }
  for (int k = i0; k < 40*256;  k += nt){ int r = k >> 8, c = k & 255; xpT[c*40 + r] = xp_w[k]; }
}

// ---------------- pe 1x1 conv (tiled GEMM 32x64) + GN partial stats ----------
__global__ void __launch_bounds__(256)
k_pe(const float* __restrict__ x, const float* __restrict__ peT,
     const float* __restrict__ pe_b, float* __restrict__ h1pre,
     float* __restrict__ part){
  __shared__ float As[16][36];
  __shared__ float Bs[16][64];
  __shared__ float red1[2][4], red2[2][4];
  int tid = threadIdx.x;
  int bx = blockIdx.x, by = blockIdx.y;
  int m0 = bx*32, n0 = by*64;
  int b = m0 >> 12, pl0 = m0 & 4095;
  int tx = tid & 15, ty = tid >> 4;
  float acc[2][4];
  #pragma unroll
  for (int i = 0; i < 2; i++)
    #pragma unroll
    for (int j = 0; j < 4; j++) acc[i][j] = 0.f;
  for (int k0 = 0; k0 < 128; k0 += 16){
    if (tid < 128){
      int k = tid >> 3, mm = (tid & 7)*4;
      float4 a = *(const float4*)(x + ((size_t)b*128 + k0+k)*4096 + pl0 + mm);
      *(float4*)&As[k][mm] = a;
    }
    {
      int k = tid >> 4, n = (tid & 15)*4;
      *(float4*)&Bs[k][n] = *(const float4*)(peT + (size_t)(k0+k)*128 + n0+n);
    }
    __syncthreads();
    #pragma unroll
    for (int k = 0; k < 16; k++){
      float2 av = *(const float2*)&As[k][ty*2];
      float4 bv = *(const float4*)&Bs[k][tx*4];
      acc[0][0] += av.x*bv.x; acc[0][1] += av.x*bv.y; acc[0][2] += av.x*bv.z; acc[0][3] += av.x*bv.w;
      acc[1][0] += av.y*bv.x; acc[1][1] += av.y*bv.y; acc[1][2] += av.y*bv.z; acc[1][3] += av.y*bv.w;
    }
    __syncthreads();
  }
  float4 bias = *(const float4*)(pe_b + n0 + tx*4);
  float s1 = 0.f, s2 = 0.f;
  #pragma unroll
  for (int i = 0; i < 2; i++){
    float4 st;
    st.x = acc[i][0]+bias.x; st.y = acc[i][1]+bias.y;
    st.z = acc[i][2]+bias.z; st.w = acc[i][3]+bias.w;
    s1 += st.x+st.y+st.z+st.w;
    s2 += st.x*st.x + st.y*st.y + st.z*st.z + st.w*st.w;
    *(float4*)(h1pre + (size_t)(m0 + ty*2 + i)*128 + n0 + tx*4) = st;
  }
  s1 += __shfl_xor(s1,1);  s2 += __shfl_xor(s2,1);
  s1 += __shfl_xor(s1,2);  s2 += __shfl_xor(s2,2);
  s1 += __shfl_xor(s1,4);  s2 += __shfl_xor(s2,4);
  s1 += __shfl_xor(s1,16); s2 += __shfl_xor(s2,16);
  s1 += __shfl_xor(s1,32); s2 += __shfl_xor(s2,32);
  int lane = tid & 63, w = tid >> 6;
  if ((lane & 55) == 0){
    int gl = (lane >> 3) & 1;
    red1[gl][w] = s1; red2[gl][w] = s2;
  }
  __syncthreads();
  if (tid < 8){
    int gg = tid >> 1, which = tid & 1;
    int gl = gg - by*2;
    float v = 0.f;
    if (gl == 0 || gl == 1){
      v = which ? (red2[gl][0]+red2[gl][1]+red2[gl][2]+red2[gl][3])
                : (red1[gl][0]+red1[gl][1]+red1[gl][2]+red1[gl][3]);
    }
    int pblk = b*256 + (bx & 127) + by*128;
    part[(size_t)pblk*8 + tid] = v;
  }
}

// ---------------- spa in-proj GEMM 64x64, fused GN+silu on A, z-silu out -----
// grid (128,8). A = GN(h1pre)+silu (computed in staging). by==0 blocks also
// write h1. by<4 -> raw xz x-part stores; by>=4 -> silu(z) directly to zsil.
__global__ void __launch_bounds__(256)
k_xz(const float* __restrict__ h1pre, const float* __restrict__ inT,
     const float* __restrict__ stats, const float* __restrict__ gng,
     const float* __restrict__ gnb, float* __restrict__ h1,
     float* __restrict__ xz, float* __restrict__ zsil){
  __shared__ float As[16][68];
  __shared__ float Bs[16][64];
  int tid = threadIdx.x;
  int m0 = blockIdx.x*64, n0 = blockIdx.y*64;
  int tx = tid & 15, ty = tid >> 4;
  float acc[4][4];
  #pragma unroll
  for (int i = 0; i < 4; i++)
    #pragma unroll
    for (int j = 0; j < 4; j++) acc[i][j] = 0.f;
  for (int k0 = 0; k0 < 128; k0 += 16){
    {
      int m = tid >> 2, kk = (tid & 3)*4;
      int pixm = m0 + m, c0 = k0 + kk;
      int bb = pixm >> 12, g = c0 >> 5;
      float4 a = *(const float4*)(h1pre + (size_t)pixm*128 + c0);
      float mu = stats[(bb*4+g)*2] * (1.f/NG);
      float var = stats[(bb*4+g)*2+1] * (1.f/NG) - mu*mu;
      float rs = rsqrtf(var + 1e-5f);
      float4 gg = *(const float4*)(gng + c0);
      float4 gb = *(const float4*)(gnb + c0);
      float4 v;
      v.x = siluf((a.x-mu)*rs*gg.x + gb.x);
      v.y = siluf((a.y-mu)*rs*gg.y + gb.y);
      v.z = siluf((a.z-mu)*rs*gg.z + gb.z);
      v.w = siluf((a.w-mu)*rs*gg.w + gb.w);
      As[kk+0][m] = v.x; As[kk+1][m] = v.y; As[kk+2][m] = v.z; As[kk+3][m] = v.w;
      if (blockIdx.y == 0) *(float4*)(h1 + (size_t)pixm*128 + c0) = v;
    }
    {
      int k = tid >> 4, n = (tid & 15)*4;
      *(float4*)&Bs[k][n] = *(const float4*)(inT + (size_t)(k0+k)*512 + n0+n);
    }
    __syncthreads();
    #pragma unroll
    for (int k = 0; k < 16; k++){
      float4 av = *(const float4*)&As[k][ty*4];
      float4 bv = *(const float4*)&Bs[k][tx*4];
      acc[0][0] += av.x*bv.x; acc[0][1] += av.x*bv.y; acc[0][2] += av.x*bv.z; acc[0][3] += av.x*bv.w;
      acc[1][0] += av.y*bv.x; acc[1][1] += av.y*bv.y; acc[1][2] += av.y*bv.z; acc[1][3] += av.y*bv.w;
      acc[2][0] += av.z*bv.x; acc[2][1] += av.z*bv.y; acc[2][2] += av.z*bv.z; acc[2][3] += av.z*bv.w;
      acc[3][0] += av.w*bv.x; acc[3][1] += av.w*bv.y; acc[3][2] += av.w*bv.z; acc[3][3] += av.w*bv.w;
    }
    __syncthreads();
  }
  if (n0 < 256){
    #pragma unroll
    for (int i = 0; i < 4; i++){
      float4 st; st.x = acc[i][0]; st.y = acc[i][1]; st.z = acc[i][2]; st.w = acc[i][3];
      *(float4*)(xz + (size_t)(m0 + ty*4 + i)*512 + n0 + tx*4) = st;
    }
  } else {
    #pragma unroll
    for (int i = 0; i < 4; i++){
      float4 st;
      st.x = siluf(acc[i][0]); st.y = siluf(acc[i][1]);
      st.z = siluf(acc[i][2]); st.w = siluf(acc[i][3]);
      *(float4*)(zsil + (size_t)(m0 + ty*4 + i)*256 + (n0-256) + tx*4) = st;
    }
  }
}

// ---------------- causal depthwise conv K=4 + silu (x-part only) -------------
__global__ void __launch_bounds__(256)
k_conv(const float* __restrict__ xz, const float* __restrict__ cw,
       const float* __restrict__ cb, float* __restrict__ xc){
  int idx = blockIdx.x*256 + threadIdx.x;
  int d = idx & 255;
  int l = (idx >> 8) & 4095;
  int b = idx >> 20;
  float v = cb[d];
  #pragma unroll
  for (int k = 0; k < 4; k++){
    int ls = l - 3 + k;
    if (ls >= 0) v += xz[(size_t)(b*4096 + ls)*512 + d] * cw[d*4 + k];
  }
  xc[idx] = siluf(v);
}

// ---------------- x-proj (dt,B,C) + delta ----------------
__global__ void __launch_bounds__(256)
k_proj(const float* __restrict__ xc, const float* __restrict__ xpT,
       const float* __restrict__ dtw, const float* __restrict__ dtb,
       float* __restrict__ delta, float* __restrict__ Bm, float* __restrict__ Cm){
  __shared__ float xt[32][260];
  __shared__ float pr[32][40];
  int tid = threadIdx.x;
  int m0 = blockIdx.x * 32;
  for (int i = tid; i < 32*256; i += 256){
    int t = i >> 8, d = i & 255;
    xt[t][d] = xc[(size_t)(m0+t)*256 + d];
  }
  __syncthreads();
  {
    int t = tid >> 3, q = tid & 7;
    bool extra = (q < 2);
    float4 a0 = {0.f,0.f,0.f,0.f}, a1 = {0.f,0.f,0.f,0.f};
    for (int d = 0; d < 256; d++){
      float xv = xt[t][d];
      float4 w0 = *(const float4*)(xpT + (size_t)d*40 + q*4);
      a0.x += xv*w0.x; a0.y += xv*w0.y; a0.z += xv*w0.z; a0.w += xv*w0.w;
      if (extra){
        float4 w1 = *(const float4*)(xpT + (size_t)d*40 + 32 + q*4);
        a1.x += xv*w1.x; a1.y += xv*w1.y; a1.z += xv*w1.z; a1.w += xv*w1.w;
      }
    }
    *(float4*)&pr[t][q*4] = a0;
    if (extra) *(float4*)&pr[t][32+q*4] = a1;
  }
  __syncthreads();
  {
    int d = tid;
    float w[8];
    #pragma unroll
    for (int r = 0; r < 8; r++) w[r] = dtw[d*8+r];
    float bd = dtb[d];
    for (int t = 0; t < 32; t++){
      float val = bd;
      #pragma unroll
      for (int r = 0; r < 8; r++) val += pr[t][r]*w[r];
      delta[(size_t)(m0+t)*256 + d] = softplusf(val);
    }
  }
  for (int i = tid; i < 512; i += 256){
    int t = i >> 4, n = i & 15;
    Bm[(size_t)(m0+t)*16 + n] = pr[t][8+n];
    Cm[(size_t)(m0+t)*16 + n] = pr[t][24+n];
  }
}

// ---------------- scan phase 1: thread=d, n in regs. grid 128 ----------------
__global__ void __launch_bounds__(256)
k_scan1(const float* __restrict__ delta, const float* __restrict__ xc,
        const float* __restrict__ Bm, const float* __restrict__ Alog,
        float* __restrict__ P, float* __restrict__ Q){
  int blk = blockIdx.x;            // b*64 + chunk
  int b = blk >> 6, chunk = blk & 63;
  int d = threadIdx.x;
  float An[16];
  {
    const float4* ar = (const float4*)(Alog + (size_t)d*16);
    #pragma unroll
    for (int k = 0; k < 4; k++){
      float4 a = ar[k];
      An[k*4]   = -__expf(a.x); An[k*4+1] = -__expf(a.y);
      An[k*4+2] = -__expf(a.z); An[k*4+3] = -__expf(a.w);
    }
  }
  float Pv[16], Qv[16];
  #pragma unroll
  for (int n = 0; n < 16; n++){ Pv[n] = 1.f; Qv[n] = 0.f; }
  size_t row0 = (size_t)(b*4096 + chunk*64);
  for (int l = 0; l < 64; l++){
    size_t r = row0 + l;
    float dv = delta[r*256 + d];
    float xv = xc[r*256 + d];
    const float4* bmr = (const float4*)(Bm + r*16);
    float4 b0 = bmr[0], b1 = bmr[1], b2 = bmr[2], b3 = bmr[3];
    float bm[16] = {b0.x,b0.y,b0.z,b0.w, b1.x,b1.y,b1.z,b1.w,
                    b2.x,b2.y,b2.z,b2.w, b3.x,b3.y,b3.z,b3.w};
    float dBx = dv * xv;
    #pragma unroll
    for (int n = 0; n < 16; n++){
      float a = __expf(dv * An[n]);
      Qv[n] = a*Qv[n] + bm[n]*dBx;
      Pv[n] *= a;
    }
  }
  float* Pp = P + (size_t)blk*4096 + d*16;
  float* Qp = Q + (size_t)blk*4096 + d*16;
  #pragma unroll
  for (int k = 0; k < 4; k++){
    float4 pv; pv.x = Pv[k*4]; pv.y = Pv[k*4+1]; pv.z = Pv[k*4+2]; pv.w = Pv[k*4+3];
    float4 qv; qv.x = Qv[k*4]; qv.y = Qv[k*4+1]; qv.z = Qv[k*4+2]; qv.w = Qv[k*4+3];
    *(float4*)(Pp + k*4) = pv;
    *(float4*)(Qp + k*4) = qv;
  }
}

// ---------------- scan phase 2: wave-parallel affine scan over chunks --------
// grid 2048; 4 chains/block; lane = chunk.
__global__ void __launch_bounds__(256)
k_scan2(const float* __restrict__ P, const float* __restrict__ Q,
        float* __restrict__ hs){
  int chain = blockIdx.x*4 + (threadIdx.x >> 6);   // b*4096 + dn
  int lane = threadIdx.x & 63;
  int b = chain >> 12, dn = chain & 4095;
  size_t idx = (size_t)(b*64 + lane)*4096 + dn;
  float p = P[idx], q = Q[idx];
  #pragma unroll
  for (int off = 1; off < 64; off <<= 1){
    float pp = __shfl_up(p, off);
    float qp = __shfl_up(q, off);
    if (lane >= off){ q = p*qp + q; p = p*pp; }
  }
  float hprev = __shfl_up(q, 1);
  if (lane == 0) hprev = 0.f;
  hs[idx] = hprev;
}

// ---------------- scan phase 3: replay + y. thread=d, n in regs. grid 128 ----
__global__ void __launch_bounds__(256)
k_scan3(const float* __restrict__ delta, const float* __restrict__ xc,
        const float* __restrict__ Bm, const float* __restrict__ Cm,
        const float* __restrict__ zsil, const float* __restrict__ Alog,
        const float* __restrict__ Dv, const float* __restrict__ hs,
        float* __restrict__ y){
  int blk = blockIdx.x;
  int b = blk >> 6, chunk = blk & 63;
  int d = threadIdx.x;
  float An[16];
  {
    const float4* ar = (const float4*)(Alog + (size_t)d*16);
    #pragma unroll
    for (int k = 0; k < 4; k++){
      float4 a = ar[k];
      An[k*4]   = -__expf(a.x); An[k*4+1] = -__expf(a.y);
      An[k*4+2] = -__expf(a.z); An[k*4+3] = -__expf(a.w);
    }
  }
  float h[16];
  {
    const float4* hr = (const float4*)(hs + (size_t)blk*4096 + d*16);
    #pragma unroll
    for (int k = 0; k < 4; k++){
      float4 v = hr[k];
      h[k*4] = v.x; h[k*4+1] = v.y; h[k*4+2] = v.z; h[k*4+3] = v.w;
    }
  }
  float Dd = Dv[d];
  size_t row0 = (size_t)(b*4096 + chunk*64);
  for (int l = 0; l < 64; l++){
    size_t r = row0 + l;
    float dv = delta[r*256 + d];
    float xv = xc[r*256 + d];
    float zv = zsil[r*256 + d];
    const float4* bmr = (const float4*)(Bm + r*16);
    float4 b0 = bmr[0], b1 = bmr[1], b2 = bmr[2], b3 = bmr[3];
    float bm[16] = {b0.x,b0.y,b0.z,b0.w, b1.x,b1.y,b1.z,b1.w,
                    b2.x,b2.y,b2.z,b2.w, b3.x,b3.y,b3.z,b3.w};
    const float4* cmr = (const float4*)(Cm + r*16);
    float4 c0 = cmr[0], c1 = cmr[1], c2 = cmr[2], c3 = cmr[3];
    float cm[16] = {c0.x,c0.y,c0.z,c0.w, c1.x,c1.y,c1.z,c1.w,
                    c2.x,c2.y,c2.z,c2.w, c3.x,c3.y,c3.z,c3.w};
    float dBx = dv * xv;
    float ys = 0.f;
    #pragma unroll
    for (int n = 0; n < 16; n++){
      float a = __expf(dv * An[n]);
      h[n] = a*h[n] + bm[n]*dBx;
      ys += h[n]*cm[n];
    }
    y[r*256 + d] = (ys + Dd*xv) * zv;
  }
}

// ---------------- spa out-proj: tiled GEMM 32x64 + GN partial stats ----------
__global__ void __launch_bounds__(256)
k_outproj(const float* __restrict__ y, const float* __restrict__ outT,
          float* __restrict__ yproj, float* __restrict__ part){
  __shared__ float As[16][36];
  __shared__ float Bs[16][64];
  __shared__ float red1[2][4], red2[2][4];
  int tid = threadIdx.x;
  int bx = blockIdx.x, by = blockIdx.y;
  int m0 = bx*32, n0 = by*64;
  int b = m0 >> 12;
  int tx = tid & 15, ty = tid >> 4;
  float acc[2][4];
  #pragma unroll
  for (int i = 0; i < 2; i++)
    #pragma unroll
    for (int j = 0; j < 4; j++) acc[i][j] = 0.f;
  for (int k0 = 0; k0 < 256; k0 += 16){
    if (tid < 128){
      int m = tid >> 2, kk = (tid & 3)*4;
      float4 a = *(const float4*)(y + (size_t)(m0+m)*256 + k0+kk);
      As[kk+0][m] = a.x; As[kk+1][m] = a.y; As[kk+2][m] = a.z; As[kk+3][m] = a.w;
    }
    {
      int k = tid >> 4, n = (tid & 15)*4;
      *(float4*)&Bs[k][n] = *(const float4*)(outT + (size_t)(k0+k)*128 + n0+n);
    }
    __syncthreads();
    #pragma unroll
    for (int k = 0; k < 16; k++){
      float2 av = *(const float2*)&As[k][ty*2];
      float4 bv = *(const float4*)&Bs[k][tx*4];
      acc[0][0] += av.x*bv.x; acc[0][1] += av.x*bv.y; acc[0][2] += av.x*bv.z; acc[0][3] += av.x*bv.w;
      acc[1][0] += av.y*bv.x; acc[1][1] += av.y*bv.y; acc[1][2] += av.y*bv.z; acc[1][3] += av.y*bv.w;
    }
    __syncthreads();
  }
  float s1 = 0.f, s2 = 0.f;
  #pragma unroll
  for (int i = 0; i < 2; i++){
    float4 st; st.x = acc[i][0]; st.y = acc[i][1]; st.z = acc[i][2]; st.w = acc[i][3];
    s1 += st.x+st.y+st.z+st.w;
    s2 += st.x*st.x + st.y*st.y + st.z*st.z + st.w*st.w;
    *(float4*)(yproj + (size_t)(m0 + ty*2 + i)*128 + n0 + tx*4) = st;
  }
  s1 += __shfl_xor(s1,1);  s2 += __shfl_xor(s2,1);
  s1 += __shfl_xor(s1,2);  s2 += __shfl_xor(s2,2);
  s1 += __shfl_xor(s1,4);  s2 += __shfl_xor(s2,4);
  s1 += __shfl_xor(s1,16); s2 += __shfl_xor(s2,16);
  s1 += __shfl_xor(s1,32); s2 += __shfl_xor(s2,32);
  int lane = tid & 63, w = tid >> 6;
  if ((lane & 55) == 0){
    int gl = (lane >> 3) & 1;
    red1[gl][w] = s1; red2[gl][w] = s2;
  }
  __syncthreads();
  if (tid < 8){
    int gg = tid >> 1, which = tid & 1;
    int gl = gg - by*2;
    float v = 0.f;
    if (gl == 0 || gl == 1){
      v = which ? (red2[gl][0]+red2[gl][1]+red2[gl][2]+red2[gl][3])
                : (red1[gl][0]+red1[gl][1]+red1[gl][2]+red1[gl][3]);
    }
    int pblk = b*256 + (bx & 127) + by*128;
    part[(size_t)pblk*8 + tid] = v;
  }
}

// ---------------- spe A: in-proj + conv + silu (reg weights, lane=d) ----------
__global__ void __launch_bounds__(256)
k_spe_a(const float* __restrict__ h1, const float* __restrict__ in_w,
        const float* __restrict__ conv_w, const float* __restrict__ conv_b,
        float* __restrict__ xc2, float* __restrict__ xc2T,
        float* __restrict__ zsil2){
  __shared__ float s_in[4][128];
  int tid = threadIdx.x;
  int w = tid >> 6, lane = tid & 63;
  float wx[32], wz[32];
  {
    const float4* rx = (const float4*)(in_w + (size_t)lane*32);
    const float4* rz = (const float4*)(in_w + (size_t)(64+lane)*32);
    #pragma unroll
    for (int k = 0; k < 8; k++){
      float4 a = rx[k]; wx[k*4]=a.x; wx[k*4+1]=a.y; wx[k*4+2]=a.z; wx[k*4+3]=a.w;
      float4 b = rz[k]; wz[k*4]=b.x; wz[k*4+1]=b.y; wz[k*4+2]=b.z; wz[k*4+3]=b.w;
    }
  }
  float4 cwv = ((const float4*)conv_w)[lane];
  float cbv = conv_b[lane];
  for (int i = 0; i < 4; i++){
    int pix = blockIdx.x*16 + w*4 + i;
    float2 hv = ((const float2*)(h1 + (size_t)pix*128))[lane];
    s_in[w][2*lane] = hv.x; s_in[w][2*lane+1] = hv.y;
    float xpr[4], zs[4];
    #pragma unroll
    for (int l = 0; l < 4; l++){
      const float4* sv = (const float4*)&s_in[w][l*32];
      float ax = 0.f, az = 0.f;
      #pragma unroll
      for (int c4 = 0; c4 < 8; c4++){
        float4 v = sv[c4];
        ax += v.x*wx[c4*4] + v.y*wx[c4*4+1] + v.z*wx[c4*4+2] + v.w*wx[c4*4+3];
        az += v.x*wz[c4*4] + v.y*wz[c4*4+1] + v.z*wz[c4*4+2] + v.w*wz[c4*4+3];
      }
      xpr[l] = ax; zs[l] = siluf(az);
    }
    #pragma unroll
    for (int l = 0; l < 4; l++){
      float v = cbv;
      if (l >= 3) v += xpr[l-3]*cwv.x;
      if (l >= 2) v += xpr[l-2]*cwv.y;
      if (l >= 1) v += xpr[l-1]*cwv.z;
      v += xpr[l]*cwv.w;
      float sx = siluf(v);
      int tok = pix*4 + l;
      xc2 [(size_t)tok*64 + lane] = sx;
      xc2T[(size_t)lane*32768 + tok] = sx;
      zsil2[(size_t)tok*64 + lane] = zs[l];
    }
  }
}

// ---------------- spe B: x-proj GEMM, thread = token --------------------------
__global__ void __launch_bounds__(256)
k_spe_b(const float* __restrict__ xc2T, const float* __restrict__ xpw,
        float* __restrict__ proj){
  int tok = blockIdx.x*256 + threadIdx.x;
  float xcv[64];
  #pragma unroll 64
  for (int dd = 0; dd < 64; dd++) xcv[dd] = xc2T[(size_t)dd*32768 + tok];
  float* pr = proj + (size_t)tok*36;
  #pragma unroll 2
  for (int j = 0; j < 34; j++){
    const float4* wr = (const float4*)(xpw + j*64);
    float a = 0.f;
    #pragma unroll
    for (int k = 0; k < 16; k++){
      float4 wv = wr[k];
      a += xcv[k*4]*wv.x + xcv[k*4+1]*wv.y + xcv[k*4+2]*wv.z + xcv[k*4+3]*wv.w;
    }
    pr[j] = a;
  }
}

// ---------------- spe C: delta + scan + gate (lane=d, 4 pixels/wave) ----------
__global__ void __launch_bounds__(256)
k_spe_c(const float* __restrict__ xc2, const float* __restrict__ zsil2,
        const float* __restrict__ proj, const float* __restrict__ dt_w,
        const float* __restrict__ dt_b, const float* __restrict__ Alog,
        const float* __restrict__ Dvec, float* __restrict__ yg){
  int tid = threadIdx.x;
  int w = tid >> 6, lane = tid & 63;
  float2 dtwv = ((const float2*)dt_w)[lane];
  float dbv = dt_b[lane], Dd = Dvec[lane];
  float An[16];
  {
    const float4* ar = (const float4*)(Alog + (size_t)lane*16);
    #pragma unroll
    for (int k = 0; k < 4; k++){
      float4 a = ar[k];
      An[k*4]   = -__expf(a.x); An[k*4+1] = -__expf(a.y);
      An[k*4+2] = -__expf(a.z); An[k*4+3] = -__expf(a.w);
    }
  }
  for (int i = 0; i < 4; i++){
    int pix = blockIdx.x*16 + w*4 + i;
    float h[16];
    #pragma unroll
    for (int n = 0; n < 16; n++) h[n] = 0.f;
    #pragma unroll
    for (int l = 0; l < 4; l++){
      int tok = pix*4 + l;
      float pj[36];
      {
        const float4* pr = (const float4*)(proj + (size_t)tok*36);
        #pragma unroll
        for (int k = 0; k < 9; k++){
          float4 v = pr[k];
          pj[k*4]=v.x; pj[k*4+1]=v.y; pj[k*4+2]=v.z; pj[k*4+3]=v.w;
        }
      }
      float xv = xc2[(size_t)tok*64 + lane];
      float zv = zsil2[(size_t)tok*64 + lane];
      float dt = softplusf(dbv + pj[0]*dtwv.x + pj[1]*dtwv.y);
      float ys = 0.f;
      #pragma unroll
      for (int n = 0; n < 16; n++){
        float a = __expf(dt * An[n]);
        h[n] = a*h[n] + dt * pj[2+n] * xv;
        ys += h[n] * pj[18+n];
      }
      yg[(size_t)tok*64 + lane] = (ys + Dd*xv) * zv;
    }
  }
}

// ---------------- spe D: out-proj GEMM + GN partial stats ---------------------
__global__ void __launch_bounds__(256)
k_spe_d(const float* __restrict__ yg, const float* __restrict__ out_w,
        float* __restrict__ y2, float* __restrict__ part){
  __shared__ float ldsWT[64*32];
  __shared__ float bst[8];
  int tid = threadIdx.x;
  for (int i = tid; i < 2048; i += 256){
    int c2 = i >> 6, dd = i & 63;
    ldsWT[dd*32 + c2] = out_w[i];
  }
  if (tid < 8) bst[tid] = 0.f;
  __syncthreads();
  int w = tid >> 6, lane = tid & 63;
  int c2 = lane & 31, slot = lane >> 5;
  int tokbase = blockIdx.x*64 + w*16 + slot;
  float acc[8];
  #pragma unroll
  for (int i = 0; i < 8; i++) acc[i] = 0.f;
  for (int dd4 = 0; dd4 < 16; dd4++){
    float w0 = ldsWT[(dd4*4+0)*32 + c2];
    float w1 = ldsWT[(dd4*4+1)*32 + c2];
    float w2 = ldsWT[(dd4*4+2)*32 + c2];
    float w3 = ldsWT[(dd4*4+3)*32 + c2];
    #pragma unroll
    for (int i = 0; i < 8; i++){
      int tok = tokbase + 2*i;
      float4 yv = ((const float4*)(yg + (size_t)tok*64))[dd4];
      acc[i] += yv.x*w0 + yv.y*w1 + yv.z*w2 + yv.w*w3;
    }
  }
  #pragma unroll
  for (int i = 0; i < 8; i++){
    int tok = tokbase + 2*i;
    int pix = tok >> 2, l = tok & 3;
    y2[(size_t)pix*128 + l*32 + c2] = acc[i];
    float s1 = acc[i], s2 = acc[i]*acc[i];
    s1 += __shfl_xor(s1,1);  s2 += __shfl_xor(s2,1);
    s1 += __shfl_xor(s1,2);  s2 += __shfl_xor(s2,2);
    s1 += __shfl_xor(s1,4);  s2 += __shfl_xor(s2,4);
    s1 += __shfl_xor(s1,8);  s2 += __shfl_xor(s2,8);
    s1 += __shfl_xor(s1,16); s2 += __shfl_xor(s2,16);
    if (c2 == 0){
      atomicAdd(&bst[l*2+0], s1);
      atomicAdd(&bst[l*2+1], s2);
    }
  }
  __syncthreads();
  if (tid < 8) part[(size_t)blockIdx.x*8 + tid] = bst[tid];
}

// ---------------- fuse: GN(spa)+GN(spe)+h1 -> feat, logits ----------------
__global__ void __launch_bounds__(256)
k_fuse(const float* __restrict__ h1, const float* __restrict__ yproj,
       const float* __restrict__ y2, const float* __restrict__ stats,
       const float* __restrict__ spa_g, const float* __restrict__ spa_b,
       const float* __restrict__ spe_g, const float* __restrict__ spe_b,
       const float* __restrict__ fuse_w, const float* __restrict__ cls_w,
       const float* __restrict__ cls_b, float* __restrict__ feat,
       float* __restrict__ logits){
  __shared__ float ft[2][128];
  int tid = threadIdx.x;
  int pixl = tid >> 7, c = tid & 127;
  int pix = blockIdx.x*2 + pixl;
  int b = pix >> 12, g = c >> 5;
  float m1 = stats[16 + (b*4+g)*2]   * (1.f/NG);
  float v1 = stats[16 + (b*4+g)*2+1] * (1.f/NG) - m1*m1;
  float m2 = stats[32 + (b*4+g)*2]   * (1.f/NG);
  float v2 = stats[32 + (b*4+g)*2+1] * (1.f/NG) - m2*m2;
  float h = h1[(size_t)pix*128 + c];
  float sa = siluf((yproj[(size_t)pix*128+c] - m1)*rsqrtf(v1+1e-5f)*spa_g[c] + spa_b[c]) + h;
  float sp = h + siluf((y2[(size_t)pix*128+c] - m2)*rsqrtf(v2+1e-5f)*spe_g[c] + spe_b[c]);
  float e0 = __expf(fuse_w[0]), e1 = __expf(fuse_w[1]);
  float w0 = e0/(e0+e1), w1 = e1/(e0+e1);
  float f = sa*w0 + sp*w1 + h;
  feat[(size_t)pix*128+c] = f;
  ft[pixl][c] = f;
  __syncthreads();
  if (tid < 20){
    int pl = (tid >= 10) ? 1 : 0;
    int o = tid - pl*10;
    float acc = cls_b[o];
    for (int cc = 0; cc < 128; cc++) acc += ft[pl][cc]*cls_w[o*128+cc];
    logits[(size_t)(blockIdx.x*2 + pl)*16 + o] = acc;
  }
}

// ---------------- depthwise 3x3 on feat + GN partial stats ----------------
__global__ void __launch_bounds__(256)
k_dw(const float* __restrict__ feat, const float* __restrict__ dww,
     float* __restrict__ epre, float* __restrict__ part){
  __shared__ float red1[4][64], red2[4][64];
  int tid = threadIdx.x;
  int pixl = tid >> 7, c = tid & 127;
  int pix = blockIdx.x*2 + pixl;
  int b = pix >> 12, p = pix & 4095, yy = p >> 6, xx = p & 63;
  float acc = 0.f;
  for (int dy = -1; dy <= 1; dy++){
    int ny = yy + dy; if (ny < 0 || ny > 63) continue;
    for (int dx = -1; dx <= 1; dx++){
      int nx = xx + dx; if (nx < 0 || nx > 63) continue;
      acc += feat[(size_t)((b<<12)|(ny<<6)|nx)*128 + c] * dww[c*9 + (dy+1)*3 + (dx+1)];
    }
  }
  epre[(size_t)pix*128 + c] = acc;
  int g = c >> 5;
  int idx = (c & 31) | (pixl << 5);
  red1[g][idx] = acc; red2[g][idx] = acc*acc;
  __syncthreads();
  int rg = tid >> 6, ridx = tid & 63;
  for (int s = 32; s >= 1; s >>= 1){
    if (ridx < s){ red1[rg][ridx] += red1[rg][ridx+s]; red2[rg][ridx] += red2[rg][ridx+s]; }
    __syncthreads();
  }
  if (ridx == 0){
    part[(size_t)blockIdx.x*8 + rg*2+0] = red1[rg][0];
    part[(size_t)blockIdx.x*8 + rg*2+1] = red2[rg][0];
  }
}

// ---------------- edge + local avg + final output ----------------
__global__ void __launch_bounds__(256)
k_final(const float* __restrict__ epre, const float* __restrict__ logits,
        const float* __restrict__ stats, const float* __restrict__ rg_g,
        const float* __restrict__ rg_b, const float* __restrict__ pw_w,
        const float* __restrict__ pw_b, const float* __restrict__ alpha,
        float* __restrict__ outp){
  __shared__ float part[4];
  __shared__ float edge_s[2];
  int tid = threadIdx.x;
  int pixl = tid >> 7, c = tid & 127;
  int pix = blockIdx.x*2 + pixl;
  int b = pix >> 12, p = pix & 4095, yy = p >> 6, xx = p & 63;
  int g = c >> 5;
  float m = stats[48 + (b*4+g)*2]   * (1.f/NG);
  float v = stats[48 + (b*4+g)*2+1] * (1.f/NG) - m*m;
  float e = epre[(size_t)pix*128+c];
  float en = siluf((e-m)*rsqrtf(v+1e-5f)*rg_g[c] + rg_b[c]);
  float pv = en * pw_w[c];
  pv += __shfl_xor(pv,1);  pv += __shfl_xor(pv,2);  pv += __shfl_xor(pv,4);
  pv += __shfl_xor(pv,8);  pv += __shfl_xor(pv,16); pv += __shfl_xor(pv,32);
  if ((tid & 63) == 0) part[tid>>6] = pv;
  __syncthreads();
  if (tid < 2) edge_s[tid] = sigm(part[tid*2] + part[tid*2+1] + pw_b[0]);
  __syncthreads();
  if (c < 10){
    float ed = edge_s[pixl];
    int o = c;
    float lg = logits[(size_t)pix*16 + o];
    float loc = 0.f;
    for (int dy = -1; dy <= 1; dy++){
      int ny = yy+dy; if (ny < 0 || ny > 63) continue;
      for (int dx = -1; dx <= 1; dx++){
        int nx = xx+dx; if (nx < 0 || nx > 63) continue;
        loc += logits[(size_t)((b<<12)|(ny<<6)|nx)*16 + o];
      }
    }
    loc *= (1.f/9.f);
    outp[(size_t)((b*10+o)<<12) + p] = lg + alpha[0]*(1.f-ed)*(loc - lg);
  }
}

extern "C" void kernel_launch(void* const* d_in, const int* in_sizes, int n_in,
                              void* d_out, int out_size, void* d_ws, size_t ws_size,
                              hipStream_t stream){
  const float* x          = (const float*)d_in[0];
  const float* pe_w       = (const float*)d_in[1];
  const float* pe_b       = (const float*)d_in[2];
  const float* pe_gn_g    = (const float*)d_in[3];
  const float* pe_gn_b    = (const float*)d_in[4];
  const float* spa_in_w   = (const float*)d_in[5];
  const float* spa_conv_w = (const float*)d_in[6];
  const float* spa_conv_b = (const float*)d_in[7];
  const float* spa_xproj_w= (const float*)d_in[8];
  const float* spa_dt_w   = (const float*)d_in[9];
  const float* spa_dt_b   = (const float*)d_in[10];
  const float* spa_Alog   = (const float*)d_in[11];
  const float* spa_D      = (const float*)d_in[12];
  const float* spa_out_w  = (const float*)d_in[13];
  const float* spa_gn_g   = (const float*)d_in[14];
  const float* spa_gn_b   = (const float*)d_in[15];
  const float* spe_in_w   = (const float*)d_in[16];
  const float* spe_conv_w = (const float*)d_in[17];
  const float* spe_conv_b = (const float*)d_in[18];
  const float* spe_xproj_w= (const float*)d_in[19];
  const float* spe_dt_w   = (const float*)d_in[20];
  const float* spe_dt_b   = (const float*)d_in[21];
  const float* spe_Alog   = (const float*)d_in[22];
  const float* spe_D      = (const float*)d_in[23];
  const float* spe_out_w  = (const float*)d_in[24];
  const float* spe_gn_g   = (const float*)d_in[25];
  const float* spe_gn_b   = (const float*)d_in[26];
  const float* fuse_w     = (const float*)d_in[27];
  const float* cls_w      = (const float*)d_in[28];
  const float* cls_b      = (const float*)d_in[29];
  const float* ref_dw_w   = (const float*)d_in[30];
  const float* ref_gn_g   = (const float*)d_in[31];
  const float* ref_gn_b   = (const float*)d_in[32];
  const float* ref_pw_w   = (const float*)d_in[33];
  const float* ref_pw_b   = (const float*)d_in[34];
  const float* alpha      = (const float*)d_in[35];
  float* ws  = (float*)d_ws;
  float* out = (float*)d_out;

  float* partPE  = ws + WS_Y;    // dead until scan3 writes y
  float* partSPA = ws + WS_HS;   // dead after scan3
  float* partSPE = ws + WS_Q;    // dead after scan2
  float* partDW  = ws + WS_P;    // dead after scan2
  float* xc2   = ws + WS_XC;
  float* xc2T  = ws + WS_ZSIL;
  float* zsil2 = ws + WS_DELTA;
  float* proj  = ws + WS_BM;
  float* yg    = ws + WS_Y;

  k_transpose<<<64,256,0,stream>>>(pe_w, spa_in_w, spa_out_w, spa_xproj_w,
      ws+WS_PEWT, ws+WS_INWT, ws+WS_OUTWT, ws+WS_XPWT);
  k_pe<<<dim3(256,2),256,0,stream>>>(x, ws+WS_PEWT, pe_b, ws+WS_H1PRE, partPE);
  k_red<<<16,256,0,stream>>>(partPE, ws+WS_STATS+0, 256);
  k_xz<<<dim3(128,8),256,0,stream>>>(ws+WS_H1PRE, ws+WS_INWT, ws+WS_STATS,
      pe_gn_g, pe_gn_b, ws+WS_H1, ws+WS_XZ, ws+WS_ZSIL);
  k_conv<<<8192,256,0,stream>>>(ws+WS_XZ, spa_conv_w, spa_conv_b, ws+WS_XC);
  k_proj<<<256,256,0,stream>>>(ws+WS_XC, ws+WS_XPWT, spa_dt_w, spa_dt_b,
      ws+WS_DELTA, ws+WS_BM, ws+WS_CM);
  k_scan1<<<128,256,0,stream>>>(ws+WS_DELTA, ws+WS_XC, ws+WS_BM, spa_Alog,
      ws+WS_P, ws+WS_Q);
  k_scan2<<<2048,256,0,stream>>>(ws+WS_P, ws+WS_Q, ws+WS_HS);
  k_scan3<<<128,256,0,stream>>>(ws+WS_DELTA, ws+WS_XC, ws+WS_BM, ws+WS_CM,
      ws+WS_ZSIL, spa_Alog, spa_D, ws+WS_HS, ws+WS_Y);
  k_outproj<<<dim3(256,2),256,0,stream>>>(ws+WS_Y, ws+WS_OUTWT, ws+WS_H1PRE, partSPA);
  k_red<<<16,256,0,stream>>>(partSPA, ws+WS_STATS+16, 256);
  k_spe_a<<<512,256,0,stream>>>(ws+WS_H1, spe_in_w, spe_conv_w, spe_conv_b,
      xc2, xc2T, zsil2);
  k_spe_b<<<128,256,0,stream>>>(xc2T, spe_xproj_w, proj);
  k_spe_c<<<512,256,0,stream>>>(xc2, zsil2, proj, spe_dt_w, spe_dt_b,
      spe_Alog, spe_D, yg);
  k_spe_d<<<512,256,0,stream>>>(yg, spe_out_w, ws+WS_Y2, partSPE);
  k_red<<<16,256,0,stream>>>(partSPE, ws+WS_STATS+32, 256);
  k_fuse<<<4096,256,0,stream>>>(ws+WS_H1, ws+WS_H1PRE, ws+WS_Y2, ws+WS_STATS,
      spa_gn_g, spa_gn_b, spe_gn_g, spe_gn_b, fuse_w, cls_w, cls_b,
      ws+WS_FEAT, ws+WS_LOG);
  k_dw<<<4096,256,0,stream>>>(ws+WS_FEAT, ref_dw_w, ws+WS_Y, partDW);
  k_red<<<16,256,0,stream>>>(partDW, ws+WS_STATS+48, 2048);
  k_final<<<4096,256,0,stream>>>(ws+WS_Y, ws+WS_LOG, ws+WS_STATS,
      ref_gn_g, ref_gn_b, ref_pw_w, ref_pw_b, alpha, out);
  (void)in_sizes; (void)n_in; (void)out_size; (void)ws_size;
}

// Round 6
// 475.672 us; speedup vs baseline: 1.0365x; 1.0365x over previous
//
#include <hip/hip_runtime.h>
#include <math.h>

#define DEV __device__ __forceinline__

DEV float sigm(float x){ return 1.f/(1.f+__expf(-x)); }
DEV float siluf(float x){ return x * sigm(x); }
DEV float softplusf(float x){ return x > 20.f ? x : log1pf(__expf(x)); }

static constexpr float NG = 131072.0f;   // group-norm element count per (b,g): 32*64*64

// ---- workspace layout (offsets in floats) ----
static constexpr size_t WS_H1    = 0;          // B*HW*128
static constexpr size_t WS_H1PRE = 1048576;    // B*HW*128 (reused as yproj)
static constexpr size_t WS_XC    = 2097152;    // B*HW*256 (spa xc; later spe xc2[tok][64])
static constexpr size_t WS_ZSIL  = 4194304;    // B*HW*256 (spa zsil; later spe xc2T[64][tok])
static constexpr size_t WS_XZ    = 6291456;    // xz x-part; after k_conv: proj[tok][40]; later spe zsil2
static constexpr size_t WS_LOG   = 8650752;    // B*HW*16 (logits, stride 16, 10 used)
static constexpr size_t WS_Y     = 10485760;   // B*HW*256 (y; pe partials; spe yg; later e_pre)
static constexpr size_t WS_P     = 12582912;   // [b][chunk][4096] (after scan2: dw partials)
static constexpr size_t WS_Q     = 13107200;   // (after scan2: spe partials)
static constexpr size_t WS_HS    = 13631488;   // (after scan3: outproj partials)
static constexpr size_t WS_Y2    = 14155776;   // B*HW*128
static constexpr size_t WS_FEAT  = 15204352;   // B*HW*128
static constexpr size_t WS_STATS = 16252928;   // 64 floats: pe@0 spa@16 spe@32 ref@48
static constexpr size_t WS_PEWT  = 16253056;   // 128*128
static constexpr size_t WS_INWT  = WS_PEWT  + 16384;  // 128*512
static constexpr size_t WS_OUTWT = WS_INWT  + 65536;  // 256*128

// ---------------- partial-stats reduction: grid = 16 (b in 0..1, j in 0..7) ----
__global__ void __launch_bounds__(256)
k_red(const float* __restrict__ part, float* __restrict__ outS, int half){
  __shared__ float red[4];
  int b = blockIdx.x >> 3, j = blockIdx.x & 7;
  float s = 0.f;
  for (int i = b*half + threadIdx.x; i < (b+1)*half; i += 256)
    s += part[(size_t)i*8 + j];
  s += __shfl_xor(s,1); s += __shfl_xor(s,2); s += __shfl_xor(s,4);
  s += __shfl_xor(s,8); s += __shfl_xor(s,16); s += __shfl_xor(s,32);
  if ((threadIdx.x & 63) == 0) red[threadIdx.x>>6] = s;
  __syncthreads();
  if (threadIdx.x == 0) outS[b*8+j] = red[0]+red[1]+red[2]+red[3];
}

// ---------------- transpose weights (spa side only) ----------------
__global__ void __launch_bounds__(256)
k_transpose(const float* __restrict__ pe_w, const float* __restrict__ in_w,
            const float* __restrict__ out_w,
            float* __restrict__ peT, float* __restrict__ inT,
            float* __restrict__ outT){
  int i0 = blockIdx.x*256 + threadIdx.x;
  int nt = gridDim.x*256;
  for (int k = i0; k < 128*128; k += nt){ int r = k >> 7, c = k & 127; peT[c*128 + r] = pe_w[k]; }
  for (int k = i0; k < 512*128; k += nt){ int r = k >> 7, c = k & 127; inT[c*512 + r] = in_w[k]; }
  for (int k = i0; k < 128*256; k += nt){ int r = k >> 8, c = k & 255; outT[c*128 + r] = out_w[k]; }
}

// ---------------- pe 1x1 conv (tiled GEMM 32x64) + GN partial stats ----------
__global__ void __launch_bounds__(256)
k_pe(const float* __restrict__ x, const float* __restrict__ peT,
     const float* __restrict__ pe_b, float* __restrict__ h1pre,
     float* __restrict__ part){
  __shared__ float As[16][36];
  __shared__ float Bs[16][64];
  __shared__ float red1[2][4], red2[2][4];
  int tid = threadIdx.x;
  int bx = blockIdx.x, by = blockIdx.y;
  int m0 = bx*32, n0 = by*64;
  int b = m0 >> 12, pl0 = m0 & 4095;
  int tx = tid & 15, ty = tid >> 4;
  float acc[2][4];
  #pragma unroll
  for (int i = 0; i < 2; i++)
    #pragma unroll
    for (int j = 0; j < 4; j++) acc[i][j] = 0.f;
  for (int k0 = 0; k0 < 128; k0 += 16){
    if (tid < 128){
      int k = tid >> 3, mm = (tid & 7)*4;
      float4 a = *(const float4*)(x + ((size_t)b*128 + k0+k)*4096 + pl0 + mm);
      *(float4*)&As[k][mm] = a;
    }
    {
      int k = tid >> 4, n = (tid & 15)*4;
      *(float4*)&Bs[k][n] = *(const float4*)(peT + (size_t)(k0+k)*128 + n0+n);
    }
    __syncthreads();
    #pragma unroll
    for (int k = 0; k < 16; k++){
      float2 av = *(const float2*)&As[k][ty*2];
      float4 bv = *(const float4*)&Bs[k][tx*4];
      acc[0][0] += av.x*bv.x; acc[0][1] += av.x*bv.y; acc[0][2] += av.x*bv.z; acc[0][3] += av.x*bv.w;
      acc[1][0] += av.y*bv.x; acc[1][1] += av.y*bv.y; acc[1][2] += av.y*bv.z; acc[1][3] += av.y*bv.w;
    }
    __syncthreads();
  }
  float4 bias = *(const float4*)(pe_b + n0 + tx*4);
  float s1 = 0.f, s2 = 0.f;
  #pragma unroll
  for (int i = 0; i < 2; i++){
    float4 st;
    st.x = acc[i][0]+bias.x; st.y = acc[i][1]+bias.y;
    st.z = acc[i][2]+bias.z; st.w = acc[i][3]+bias.w;
    s1 += st.x+st.y+st.z+st.w;
    s2 += st.x*st.x + st.y*st.y + st.z*st.z + st.w*st.w;
    *(float4*)(h1pre + (size_t)(m0 + ty*2 + i)*128 + n0 + tx*4) = st;
  }
  s1 += __shfl_xor(s1,1);  s2 += __shfl_xor(s2,1);
  s1 += __shfl_xor(s1,2);  s2 += __shfl_xor(s2,2);
  s1 += __shfl_xor(s1,4);  s2 += __shfl_xor(s2,4);
  s1 += __shfl_xor(s1,16); s2 += __shfl_xor(s2,16);
  s1 += __shfl_xor(s1,32); s2 += __shfl_xor(s2,32);
  int lane = tid & 63, w = tid >> 6;
  if ((lane & 55) == 0){
    int gl = (lane >> 3) & 1;
    red1[gl][w] = s1; red2[gl][w] = s2;
  }
  __syncthreads();
  if (tid < 8){
    int gg = tid >> 1, which = tid & 1;
    int gl = gg - by*2;
    float v = 0.f;
    if (gl == 0 || gl == 1){
      v = which ? (red2[gl][0]+red2[gl][1]+red2[gl][2]+red2[gl][3])
                : (red1[gl][0]+red1[gl][1]+red1[gl][2]+red1[gl][3]);
    }
    int pblk = b*256 + (bx & 127) + by*128;
    part[(size_t)pblk*8 + tid] = v;
  }
}

// ---------------- spa in-proj GEMM 64x64, fused GN+silu on A, z-silu out -----
__global__ void __launch_bounds__(256)
k_xz(const float* __restrict__ h1pre, const float* __restrict__ inT,
     const float* __restrict__ stats, const float* __restrict__ gng,
     const float* __restrict__ gnb, float* __restrict__ h1,
     float* __restrict__ xz, float* __restrict__ zsil){
  __shared__ float As[16][68];
  __shared__ float Bs[16][64];
  int tid = threadIdx.x;
  int m0 = blockIdx.x*64, n0 = blockIdx.y*64;
  int tx = tid & 15, ty = tid >> 4;
  float acc[4][4];
  #pragma unroll
  for (int i = 0; i < 4; i++)
    #pragma unroll
    for (int j = 0; j < 4; j++) acc[i][j] = 0.f;
  for (int k0 = 0; k0 < 128; k0 += 16){
    {
      int m = tid >> 2, kk = (tid & 3)*4;
      int pixm = m0 + m, c0 = k0 + kk;
      int bb = pixm >> 12, g = c0 >> 5;
      float4 a = *(const float4*)(h1pre + (size_t)pixm*128 + c0);
      float mu = stats[(bb*4+g)*2] * (1.f/NG);
      float var = stats[(bb*4+g)*2+1] * (1.f/NG) - mu*mu;
      float rs = rsqrtf(var + 1e-5f);
      float4 gg = *(const float4*)(gng + c0);
      float4 gb = *(const float4*)(gnb + c0);
      float4 v;
      v.x = siluf((a.x-mu)*rs*gg.x + gb.x);
      v.y = siluf((a.y-mu)*rs*gg.y + gb.y);
      v.z = siluf((a.z-mu)*rs*gg.z + gb.z);
      v.w = siluf((a.w-mu)*rs*gg.w + gb.w);
      As[kk+0][m] = v.x; As[kk+1][m] = v.y; As[kk+2][m] = v.z; As[kk+3][m] = v.w;
      if (blockIdx.y == 0) *(float4*)(h1 + (size_t)pixm*128 + c0) = v;
    }
    {
      int k = tid >> 4, n = (tid & 15)*4;
      *(float4*)&Bs[k][n] = *(const float4*)(inT + (size_t)(k0+k)*512 + n0+n);
    }
    __syncthreads();
    #pragma unroll
    for (int k = 0; k < 16; k++){
      float4 av = *(const float4*)&As[k][ty*4];
      float4 bv = *(const float4*)&Bs[k][tx*4];
      acc[0][0] += av.x*bv.x; acc[0][1] += av.x*bv.y; acc[0][2] += av.x*bv.z; acc[0][3] += av.x*bv.w;
      acc[1][0] += av.y*bv.x; acc[1][1] += av.y*bv.y; acc[1][2] += av.y*bv.z; acc[1][3] += av.y*bv.w;
      acc[2][0] += av.z*bv.x; acc[2][1] += av.z*bv.y; acc[2][2] += av.z*bv.z; acc[2][3] += av.z*bv.w;
      acc[3][0] += av.w*bv.x; acc[3][1] += av.w*bv.y; acc[3][2] += av.w*bv.z; acc[3][3] += av.w*bv.w;
    }
    __syncthreads();
  }
  if (n0 < 256){
    #pragma unroll
    for (int i = 0; i < 4; i++){
      float4 st; st.x = acc[i][0]; st.y = acc[i][1]; st.z = acc[i][2]; st.w = acc[i][3];
      *(float4*)(xz + (size_t)(m0 + ty*4 + i)*512 + n0 + tx*4) = st;
    }
  } else {
    #pragma unroll
    for (int i = 0; i < 4; i++){
      float4 st;
      st.x = siluf(acc[i][0]); st.y = siluf(acc[i][1]);
      st.z = siluf(acc[i][2]); st.w = siluf(acc[i][3]);
      *(float4*)(zsil + (size_t)(m0 + ty*4 + i)*256 + (n0-256) + tx*4) = st;
    }
  }
}

// ---------------- causal depthwise conv K=4 + silu (x-part only) -------------
__global__ void __launch_bounds__(256)
k_conv(const float* __restrict__ xz, const float* __restrict__ cw,
       const float* __restrict__ cb, float* __restrict__ xc){
  int idx = blockIdx.x*256 + threadIdx.x;
  int d = idx & 255;
  int l = (idx >> 8) & 4095;
  int b = idx >> 20;
  float v = cb[d];
  #pragma unroll
  for (int k = 0; k < 4; k++){
    int ls = l - 3 + k;
    if (ls >= 0) v += xz[(size_t)(b*4096 + ls)*512 + d] * cw[d*4 + k];
  }
  xc[idx] = siluf(v);
}

// ---------------- x-proj tiled GEMM: proj[tok][40] ----------------
// grid 512; block = 64 tokens x 4 j-quartets (10 outputs each).
__global__ void __launch_bounds__(256)
k_proj(const float* __restrict__ xc, const float* __restrict__ xpw,
       float* __restrict__ proj){
  __shared__ float As[32][68];
  int tid = threadIdx.x;
  int t = tid & 63;
  int jq = tid >> 6;
  int tok0 = blockIdx.x * 64;
  float acc[10];
  #pragma unroll
  for (int j = 0; j < 10; j++) acc[j] = 0.f;
  const float* wbase = xpw + (size_t)jq*10*256;
  for (int k0 = 0; k0 < 256; k0 += 32){
    {
      int m = tid >> 2, kk = (tid & 3)*8;
      float4 a0 = *(const float4*)(xc + (size_t)(tok0+m)*256 + k0+kk);
      float4 a1 = *(const float4*)(xc + (size_t)(tok0+m)*256 + k0+kk+4);
      As[kk+0][m]=a0.x; As[kk+1][m]=a0.y; As[kk+2][m]=a0.z; As[kk+3][m]=a0.w;
      As[kk+4][m]=a1.x; As[kk+5][m]=a1.y; As[kk+6][m]=a1.z; As[kk+7][m]=a1.w;
    }
    __syncthreads();
    #pragma unroll
    for (int k4 = 0; k4 < 8; k4++){
      float a0 = As[k4*4+0][t];
      float a1 = As[k4*4+1][t];
      float a2 = As[k4*4+2][t];
      float a3 = As[k4*4+3][t];
      #pragma unroll
      for (int j = 0; j < 10; j++){
        float4 w = *(const float4*)(wbase + j*256 + k0 + k4*4);
        acc[j] += a0*w.x + a1*w.y + a2*w.z + a3*w.w;
      }
    }
    __syncthreads();
  }
  float* pr = proj + (size_t)(tok0+t)*40 + jq*10;
  #pragma unroll
  for (int j = 0; j < 10; j++) pr[j] = acc[j];
}

// ---------------- scan phase 1: thread=d, delta inline, n in regs ------------
__global__ void __launch_bounds__(256)
k_scan1(const float* __restrict__ proj, const float* __restrict__ xc,
        const float* __restrict__ dtw, const float* __restrict__ dtb,
        const float* __restrict__ Alog, float* __restrict__ P,
        float* __restrict__ Q){
  int blk = blockIdx.x;            // b*64 + chunk
  int b = blk >> 6, chunk = blk & 63;
  int d = threadIdx.x;
  float An[16], w8[8];
  {
    const float4* ar = (const float4*)(Alog + (size_t)d*16);
    #pragma unroll
    for (int k = 0; k < 4; k++){
      float4 a = ar[k];
      An[k*4]   = -__expf(a.x); An[k*4+1] = -__expf(a.y);
      An[k*4+2] = -__expf(a.z); An[k*4+3] = -__expf(a.w);
    }
    const float4* wr = (const float4*)(dtw + (size_t)d*8);
    float4 w0 = wr[0], w1 = wr[1];
    w8[0]=w0.x; w8[1]=w0.y; w8[2]=w0.z; w8[3]=w0.w;
    w8[4]=w1.x; w8[5]=w1.y; w8[6]=w1.z; w8[7]=w1.w;
  }
  float bd = dtb[d];
  float Pv[16], Qv[16];
  #pragma unroll
  for (int n = 0; n < 16; n++){ Pv[n] = 1.f; Qv[n] = 0.f; }
  size_t row0 = (size_t)(b*4096 + chunk*64);
  for (int l = 0; l < 64; l++){
    size_t r = row0 + l;
    const float4* pr4 = (const float4*)(proj + r*40);
    float4 p0 = pr4[0], p1 = pr4[1];
    float4 b0 = pr4[2], b1 = pr4[3], b2 = pr4[4], b3 = pr4[5];
    float bm[16] = {b0.x,b0.y,b0.z,b0.w, b1.x,b1.y,b1.z,b1.w,
                    b2.x,b2.y,b2.z,b2.w, b3.x,b3.y,b3.z,b3.w};
    float dv = bd + p0.x*w8[0] + p0.y*w8[1] + p0.z*w8[2] + p0.w*w8[3]
                  + p1.x*w8[4] + p1.y*w8[5] + p1.z*w8[6] + p1.w*w8[7];
    dv = softplusf(dv);
    float xv = xc[r*256 + d];
    float dBx = dv * xv;
    #pragma unroll
    for (int n = 0; n < 16; n++){
      float a = __expf(dv * An[n]);
      Qv[n] = a*Qv[n] + bm[n]*dBx;
      Pv[n] *= a;
    }
  }
  float* Pp = P + (size_t)blk*4096 + d*16;
  float* Qp = Q + (size_t)blk*4096 + d*16;
  #pragma unroll
  for (int k = 0; k < 4; k++){
    float4 pv; pv.x = Pv[k*4]; pv.y = Pv[k*4+1]; pv.z = Pv[k*4+2]; pv.w = Pv[k*4+3];
    float4 qv; qv.x = Qv[k*4]; qv.y = Qv[k*4+1]; qv.z = Qv[k*4+2]; qv.w = Qv[k*4+3];
    *(float4*)(Pp + k*4) = pv;
    *(float4*)(Qp + k*4) = qv;
  }
}

// ---------------- scan phase 2: LDS-tiled wave-parallel affine scan ----------
// grid 128: b = blk>>6, dn0 = (blk&63)*64. 64 chains x 64 chunks per block.
__global__ void __launch_bounds__(256)
k_scan2(const float* __restrict__ P, const float* __restrict__ Q,
        float* __restrict__ hs){
  __shared__ float Ps[64][65], Qs[64][65];
  int tid = threadIdx.x;
  int b = blockIdx.x >> 6;
  int dn0 = (blockIdx.x & 63) * 64;
  for (int i = tid; i < 64*16; i += 256){
    int ch = i >> 4, c4 = (i & 15)*4;
    size_t g = (size_t)(b*64+ch)*4096 + dn0 + c4;
    float4 p = *(const float4*)(P + g);
    float4 q = *(const float4*)(Q + g);
    Ps[ch][c4]=p.x; Ps[ch][c4+1]=p.y; Ps[ch][c4+2]=p.z; Ps[ch][c4+3]=p.w;
    Qs[ch][c4]=q.x; Qs[ch][c4+1]=q.y; Qs[ch][c4+2]=q.z; Qs[ch][c4+3]=q.w;
  }
  __syncthreads();
  int lane = tid & 63;       // chunk
  int cq = tid >> 6;         // chain quartet
  for (int pass = 0; pass < 16; pass++){
    int c = pass*4 + cq;
    float p = Ps[lane][c], q = Qs[lane][c];
    #pragma unroll
    for (int off = 1; off < 64; off <<= 1){
      float pp = __shfl_up(p, off);
      float qp = __shfl_up(q, off);
      if (lane >= off){ q = p*qp + q; p = p*pp; }
    }
    float hprev = __shfl_up(q, 1);
    if (lane == 0) hprev = 0.f;
    Ps[lane][c] = hprev;     // each chain owns its column: no race
  }
  __syncthreads();
  for (int i = tid; i < 64*16; i += 256){
    int ch = i >> 4, c4 = (i & 15)*4;
    size_t g = (size_t)(b*64+ch)*4096 + dn0 + c4;
    float4 h;
    h.x = Ps[ch][c4]; h.y = Ps[ch][c4+1]; h.z = Ps[ch][c4+2]; h.w = Ps[ch][c4+3];
    *(float4*)(hs + g) = h;
  }
}

// ---------------- scan phase 3: replay + y, delta inline ----------
__global__ void __launch_bounds__(256)
k_scan3(const float* __restrict__ proj, const float* __restrict__ xc,
        const float* __restrict__ zsil, const float* __restrict__ dtw,
        const float* __restrict__ dtb, const float* __restrict__ Alog,
        const float* __restrict__ Dv, const float* __restrict__ hs,
        float* __restrict__ y){
  int blk = blockIdx.x;
  int b = blk >> 6, chunk = blk & 63;
  int d = threadIdx.x;
  float An[16], w8[8];
  {
    const float4* ar = (const float4*)(Alog + (size_t)d*16);
    #pragma unroll
    for (int k = 0; k < 4; k++){
      float4 a = ar[k];
      An[k*4]   = -__expf(a.x); An[k*4+1] = -__expf(a.y);
      An[k*4+2] = -__expf(a.z); An[k*4+3] = -__expf(a.w);
    }
    const float4* wr = (const float4*)(dtw + (size_t)d*8);
    float4 w0 = wr[0], w1 = wr[1];
    w8[0]=w0.x; w8[1]=w0.y; w8[2]=w0.z; w8[3]=w0.w;
    w8[4]=w1.x; w8[5]=w1.y; w8[6]=w1.z; w8[7]=w1.w;
  }
  float bd = dtb[d];
  float h[16];
  {
    const float4* hr = (const float4*)(hs + (size_t)blk*4096 + d*16);
    #pragma unroll
    for (int k = 0; k < 4; k++){
      float4 v = hr[k];
      h[k*4] = v.x; h[k*4+1] = v.y; h[k*4+2] = v.z; h[k*4+3] = v.w;
    }
  }
  float Dd = Dv[d];
  size_t row0 = (size_t)(b*4096 + chunk*64);
  for (int l = 0; l < 64; l++){
    size_t r = row0 + l;
    const float4* pr4 = (const float4*)(proj + r*40);
    float4 p0 = pr4[0], p1 = pr4[1];
    float4 b0 = pr4[2], b1 = pr4[3], b2 = pr4[4], b3 = pr4[5];
    float4 c0 = pr4[6], c1 = pr4[7], c2 = pr4[8], c3 = pr4[9];
    float bm[16] = {b0.x,b0.y,b0.z,b0.w, b1.x,b1.y,b1.z,b1.w,
                    b2.x,b2.y,b2.z,b2.w, b3.x,b3.y,b3.z,b3.w};
    float cm[16] = {c0.x,c0.y,c0.z,c0.w, c1.x,c1.y,c1.z,c1.w,
                    c2.x,c2.y,c2.z,c2.w, c3.x,c3.y,c3.z,c3.w};
    float dv = bd + p0.x*w8[0] + p0.y*w8[1] + p0.z*w8[2] + p0.w*w8[3]
                  + p1.x*w8[4] + p1.y*w8[5] + p1.z*w8[6] + p1.w*w8[7];
    dv = softplusf(dv);
    float xv = xc[r*256 + d];
    float zv = zsil[r*256 + d];
    float dBx = dv * xv;
    float ys = 0.f;
    #pragma unroll
    for (int n = 0; n < 16; n++){
      float a = __expf(dv * An[n]);
      h[n] = a*h[n] + bm[n]*dBx;
      ys += h[n]*cm[n];
    }
    y[r*256 + d] = (ys + Dd*xv) * zv;
  }
}

// ---------------- spa out-proj: tiled GEMM 32x64 + GN partial stats ----------
__global__ void __launch_bounds__(256)
k_outproj(const float* __restrict__ y, const float* __restrict__ outT,
          float* __restrict__ yproj, float* __restrict__ part){
  __shared__ float As[16][36];
  __shared__ float Bs[16][64];
  __shared__ float red1[2][4], red2[2][4];
  int tid = threadIdx.x;
  int bx = blockIdx.x, by = blockIdx.y;
  int m0 = bx*32, n0 = by*64;
  int b = m0 >> 12;
  int tx = tid & 15, ty = tid >> 4;
  float acc[2][4];
  #pragma unroll
  for (int i = 0; i < 2; i++)
    #pragma unroll
    for (int j = 0; j < 4; j++) acc[i][j] = 0.f;
  for (int k0 = 0; k0 < 256; k0 += 16){
    if (tid < 128){
      int m = tid >> 2, kk = (tid & 3)*4;
      float4 a = *(const float4*)(y + (size_t)(m0+m)*256 + k0+kk);
      As[kk+0][m] = a.x; As[kk+1][m] = a.y; As[kk+2][m] = a.z; As[kk+3][m] = a.w;
    }
    {
      int k = tid >> 4, n = (tid & 15)*4;
      *(float4*)&Bs[k][n] = *(const float4*)(outT + (size_t)(k0+k)*128 + n0+n);
    }
    __syncthreads();
    #pragma unroll
    for (int k = 0; k < 16; k++){
      float2 av = *(const float2*)&As[k][ty*2];
      float4 bv = *(const float4*)&Bs[k][tx*4];
      acc[0][0] += av.x*bv.x; acc[0][1] += av.x*bv.y; acc[0][2] += av.x*bv.z; acc[0][3] += av.x*bv.w;
      acc[1][0] += av.y*bv.x; acc[1][1] += av.y*bv.y; acc[1][2] += av.y*bv.z; acc[1][3] += av.y*bv.w;
    }
    __syncthreads();
  }
  float s1 = 0.f, s2 = 0.f;
  #pragma unroll
  for (int i = 0; i < 2; i++){
    float4 st; st.x = acc[i][0]; st.y = acc[i][1]; st.z = acc[i][2]; st.w = acc[i][3];
    s1 += st.x+st.y+st.z+st.w;
    s2 += st.x*st.x + st.y*st.y + st.z*st.z + st.w*st.w;
    *(float4*)(yproj + (size_t)(m0 + ty*2 + i)*128 + n0 + tx*4) = st;
  }
  s1 += __shfl_xor(s1,1);  s2 += __shfl_xor(s2,1);
  s1 += __shfl_xor(s1,2);  s2 += __shfl_xor(s2,2);
  s1 += __shfl_xor(s1,4);  s2 += __shfl_xor(s2,4);
  s1 += __shfl_xor(s1,16); s2 += __shfl_xor(s2,16);
  s1 += __shfl_xor(s1,32); s2 += __shfl_xor(s2,32);
  int lane = tid & 63, w = tid >> 6;
  if ((lane & 55) == 0){
    int gl = (lane >> 3) & 1;
    red1[gl][w] = s1; red2[gl][w] = s2;
  }
  __syncthreads();
  if (tid < 8){
    int gg = tid >> 1, which = tid & 1;
    int gl = gg - by*2;
    float v = 0.f;
    if (gl == 0 || gl == 1){
      v = which ? (red2[gl][0]+red2[gl][1]+red2[gl][2]+red2[gl][3])
                : (red1[gl][0]+red1[gl][1]+red1[gl][2]+red1[gl][3]);
    }
    int pblk = b*256 + (bx & 127) + by*128;
    part[(size_t)pblk*8 + tid] = v;
  }
}

// ---------------- spe A: in-proj + conv + silu (reg weights, lane=d) ----------
__global__ void __launch_bounds__(256)
k_spe_a(const float* __restrict__ h1, const float* __restrict__ in_w,
        const float* __restrict__ conv_w, const float* __restrict__ conv_b,
        float* __restrict__ xc2, float* __restrict__ xc2T,
        float* __restrict__ zsil2){
  __shared__ float s_in[4][128];
  int tid = threadIdx.x;
  int w = tid >> 6, lane = tid & 63;
  float wx[32], wz[32];
  {
    const float4* rx = (const float4*)(in_w + (size_t)lane*32);
    const float4* rz = (const float4*)(in_w + (size_t)(64+lane)*32);
    #pragma unroll
    for (int k = 0; k < 8; k++){
      float4 a = rx[k]; wx[k*4]=a.x; wx[k*4+1]=a.y; wx[k*4+2]=a.z; wx[k*4+3]=a.w;
      float4 b = rz[k]; wz[k*4]=b.x; wz[k*4+1]=b.y; wz[k*4+2]=b.z; wz[k*4+3]=b.w;
    }
  }
  float4 cwv = ((const float4*)conv_w)[lane];
  float cbv = conv_b[lane];
  for (int i = 0; i < 4; i++){
    int pix = blockIdx.x*16 + w*4 + i;
    float2 hv = ((const float2*)(h1 + (size_t)pix*128))[lane];
    s_in[w][2*lane] = hv.x; s_in[w][2*lane+1] = hv.y;
    float xpr[4], zs[4];
    #pragma unroll
    for (int l = 0; l < 4; l++){
      const float4* sv = (const float4*)&s_in[w][l*32];
      float ax = 0.f, az = 0.f;
      #pragma unroll
      for (int c4 = 0; c4 < 8; c4++){
        float4 v = sv[c4];
        ax += v.x*wx[c4*4] + v.y*wx[c4*4+1] + v.z*wx[c4*4+2] + v.w*wx[c4*4+3];
        az += v.x*wz[c4*4] + v.y*wz[c4*4+1] + v.z*wz[c4*4+2] + v.w*wz[c4*4+3];
      }
      xpr[l] = ax; zs[l] = siluf(az);
    }
    #pragma unroll
    for (int l = 0; l < 4; l++){
      float v = cbv;
      if (l >= 3) v += xpr[l-3]*cwv.x;
      if (l >= 2) v += xpr[l-2]*cwv.y;
      if (l >= 1) v += xpr[l-1]*cwv.z;
      v += xpr[l]*cwv.w;
      float sx = siluf(v);
      int tok = pix*4 + l;
      xc2 [(size_t)tok*64 + lane] = sx;
      xc2T[(size_t)lane*32768 + tok] = sx;
      zsil2[(size_t)tok*64 + lane] = zs[l];
    }
  }
}

// ---------------- spe B: x-proj GEMM, thread = token --------------------------
__global__ void __launch_bounds__(256)
k_spe_b(const float* __restrict__ xc2T, const float* __restrict__ xpw,
        float* __restrict__ proj){
  int tok = blockIdx.x*256 + threadIdx.x;
  float xcv[64];
  #pragma unroll 64
  for (int dd = 0; dd < 64; dd++) xcv[dd] = xc2T[(size_t)dd*32768 + tok];
  float* pr = proj + (size_t)tok*36;
  #pragma unroll 2
  for (int j = 0; j < 34; j++){
    const float4* wr = (const float4*)(xpw + j*64);
    float a = 0.f;
    #pragma unroll
    for (int k = 0; k < 16; k++){
      float4 wv = wr[k];
      a += xcv[k*4]*wv.x + xcv[k*4+1]*wv.y + xcv[k*4+2]*wv.z + xcv[k*4+3]*wv.w;
    }
    pr[j] = a;
  }
}

// ---------------- spe C: delta + scan + gate (lane=d, 4 pixels/wave) ----------
__global__ void __launch_bounds__(256)
k_spe_c(const float* __restrict__ xc2, const float* __restrict__ zsil2,
        const float* __restrict__ proj, const float* __restrict__ dt_w,
        const float* __restrict__ dt_b, const float* __restrict__ Alog,
        const float* __restrict__ Dvec, float* __restrict__ yg){
  int tid = threadIdx.x;
  int w = tid >> 6, lane = tid & 63;
  float2 dtwv = ((const float2*)dt_w)[lane];
  float dbv = dt_b[lane], Dd = Dvec[lane];
  float An[16];
  {
    const float4* ar = (const float4*)(Alog + (size_t)lane*16);
    #pragma unroll
    for (int k = 0; k < 4; k++){
      float4 a = ar[k];
      An[k*4]   = -__expf(a.x); An[k*4+1] = -__expf(a.y);
      An[k*4+2] = -__expf(a.z); An[k*4+3] = -__expf(a.w);
    }
  }
  for (int i = 0; i < 4; i++){
    int pix = blockIdx.x*16 + w*4 + i;
    float h[16];
    #pragma unroll
    for (int n = 0; n < 16; n++) h[n] = 0.f;
    #pragma unroll
    for (int l = 0; l < 4; l++){
      int tok = pix*4 + l;
      float pj[36];
      {
        const float4* pr = (const float4*)(proj + (size_t)tok*36);
        #pragma unroll
        for (int k = 0; k < 9; k++){
          float4 v = pr[k];
          pj[k*4]=v.x; pj[k*4+1]=v.y; pj[k*4+2]=v.z; pj[k*4+3]=v.w;
        }
      }
      float xv = xc2[(size_t)tok*64 + lane];
      float zv = zsil2[(size_t)tok*64 + lane];
      float dt = softplusf(dbv + pj[0]*dtwv.x + pj[1]*dtwv.y);
      float ys = 0.f;
      #pragma unroll
      for (int n = 0; n < 16; n++){
        float a = __expf(dt * An[n]);
        h[n] = a*h[n] + dt * pj[2+n] * xv;
        ys += h[n] * pj[18+n];
      }
      yg[(size_t)tok*64 + lane] = (ys + Dd*xv) * zv;
    }
  }
}

// ---------------- spe D: out-proj GEMM + GN partial stats ---------------------
__global__ void __launch_bounds__(256)
k_spe_d(const float* __restrict__ yg, const float* __restrict__ out_w,
        float* __restrict__ y2, float* __restrict__ part){
  __shared__ float ldsWT[64*32];
  __shared__ float bst[8];
  int tid = threadIdx.x;
  for (int i = tid; i < 2048; i += 256){
    int c2 = i >> 6, dd = i & 63;
    ldsWT[dd*32 + c2] = out_w[i];
  }
  if (tid < 8) bst[tid] = 0.f;
  __syncthreads();
  int w = tid >> 6, lane = tid & 63;
  int c2 = lane & 31, slot = lane >> 5;
  int tokbase = blockIdx.x*64 + w*16 + slot;
  float acc[8];
  #pragma unroll
  for (int i = 0; i < 8; i++) acc[i] = 0.f;
  for (int dd4 = 0; dd4 < 16; dd4++){
    float w0 = ldsWT[(dd4*4+0)*32 + c2];
    float w1 = ldsWT[(dd4*4+1)*32 + c2];
    float w2 = ldsWT[(dd4*4+2)*32 + c2];
    float w3 = ldsWT[(dd4*4+3)*32 + c2];
    #pragma unroll
    for (int i = 0; i < 8; i++){
      int tok = tokbase + 2*i;
      float4 yv = ((const float4*)(yg + (size_t)tok*64))[dd4];
      acc[i] += yv.x*w0 + yv.y*w1 + yv.z*w2 + yv.w*w3;
    }
  }
  #pragma unroll
  for (int i = 0; i < 8; i++){
    int tok = tokbase + 2*i;
    int pix = tok >> 2, l = tok & 3;
    y2[(size_t)pix*128 + l*32 + c2] = acc[i];
    float s1 = acc[i], s2 = acc[i]*acc[i];
    s1 += __shfl_xor(s1,1);  s2 += __shfl_xor(s2,1);
    s1 += __shfl_xor(s1,2);  s2 += __shfl_xor(s2,2);
    s1 += __shfl_xor(s1,4);  s2 += __shfl_xor(s2,4);
    s1 += __shfl_xor(s1,8);  s2 += __shfl_xor(s2,8);
    s1 += __shfl_xor(s1,16); s2 += __shfl_xor(s2,16);
    if (c2 == 0){
      atomicAdd(&bst[l*2+0], s1);
      atomicAdd(&bst[l*2+1], s2);
    }
  }
  __syncthreads();
  if (tid < 8) part[(size_t)blockIdx.x*8 + tid] = bst[tid];
}

// ---------------- fuse: GN(spa)+GN(spe)+h1 -> feat, logits ----------------
__global__ void __launch_bounds__(256)
k_fuse(const float* __restrict__ h1, const float* __restrict__ yproj,
       const float* __restrict__ y2, const float* __restrict__ stats,
       const float* __restrict__ spa_g, const float* __restrict__ spa_b,
       const float* __restrict__ spe_g, const float* __restrict__ spe_b,
       const float* __restrict__ fuse_w, const float* __restrict__ cls_w,
       const float* __restrict__ cls_b, float* __restrict__ feat,
       float* __restrict__ logits){
  __shared__ float ft[2][128];
  int tid = threadIdx.x;
  int pixl = tid >> 7, c = tid & 127;
  int pix = blockIdx.x*2 + pixl;
  int b = pix >> 12, g = c >> 5;
  float m1 = stats[16 + (b*4+g)*2]   * (1.f/NG);
  float v1 = stats[16 + (b*4+g)*2+1] * (1.f/NG) - m1*m1;
  float m2 = stats[32 + (b*4+g)*2]   * (1.f/NG);
  float v2 = stats[32 + (b*4+g)*2+1] * (1.f/NG) - m2*m2;
  float h = h1[(size_t)pix*128 + c];
  float sa = siluf((yproj[(size_t)pix*128+c] - m1)*rsqrtf(v1+1e-5f)*spa_g[c] + spa_b[c]) + h;
  float sp = h + siluf((y2[(size_t)pix*128+c] - m2)*rsqrtf(v2+1e-5f)*spe_g[c] + spe_b[c]);
  float e0 = __expf(fuse_w[0]), e1 = __expf(fuse_w[1]);
  float w0 = e0/(e0+e1), w1 = e1/(e0+e1);
  float f = sa*w0 + sp*w1 + h;
  feat[(size_t)pix*128+c] = f;
  ft[pixl][c] = f;
  __syncthreads();
  if (tid < 20){
    int pl = (tid >= 10) ? 1 : 0;
    int o = tid - pl*10;
    float acc = cls_b[o];
    for (int cc = 0; cc < 128; cc++) acc += ft[pl][cc]*cls_w[o*128+cc];
    logits[(size_t)(blockIdx.x*2 + pl)*16 + o] = acc;
  }
}

// ---------------- depthwise 3x3 on feat + GN partial stats ----------------
__global__ void __launch_bounds__(256)
k_dw(const float* __restrict__ feat, const float* __restrict__ dww,
     float* __restrict__ epre, float* __restrict__ part){
  __shared__ float red1[4][64], red2[4][64];
  int tid = threadIdx.x;
  int pixl = tid >> 7, c = tid & 127;
  int pix = blockIdx.x*2 + pixl;
  int b = pix >> 12, p = pix & 4095, yy = p >> 6, xx = p & 63;
  float acc = 0.f;
  for (int dy = -1; dy <= 1; dy++){
    int ny = yy + dy; if (ny < 0 || ny > 63) continue;
    for (int dx = -1; dx <= 1; dx++){
      int nx = xx + dx; if (nx < 0 || nx > 63) continue;
      acc += feat[(size_t)((b<<12)|(ny<<6)|nx)*128 + c] * dww[c*9 + (dy+1)*3 + (dx+1)];
    }
  }
  epre[(size_t)pix*128 + c] = acc;
  int g = c >> 5;
  int idx = (c & 31) | (pixl << 5);
  red1[g][idx] = acc; red2[g][idx] = acc*acc;
  __syncthreads();
  int rg = tid >> 6, ridx = tid & 63;
  for (int s = 32; s >= 1; s >>= 1){
    if (ridx < s){ red1[rg][ridx] += red1[rg][ridx+s]; red2[rg][ridx] += red2[rg][ridx+s]; }
    __syncthreads();
  }
  if (ridx == 0){
    part[(size_t)blockIdx.x*8 + rg*2+0] = red1[rg][0];
    part[(size_t)blockIdx.x*8 + rg*2+1] = red2[rg][0];
  }
}

// ---------------- edge + local avg + final output ----------------
__global__ void __launch_bounds__(256)
k_final(const float* __restrict__ epre, const float* __restrict__ logits,
        const float* __restrict__ stats, const float* __restrict__ rg_g,
        const float* __restrict__ rg_b, const float* __restrict__ pw_w,
        const float* __restrict__ pw_b, const float* __restrict__ alpha,
        float* __restrict__ outp){
  __shared__ float part[4];
  __shared__ float edge_s[2];
  int tid = threadIdx.x;
  int pixl = tid >> 7, c = tid & 127;
  int pix = blockIdx.x*2 + pixl;
  int b = pix >> 12, p = pix & 4095, yy = p >> 6, xx = p & 63;
  int g = c >> 5;
  float m = stats[48 + (b*4+g)*2]   * (1.f/NG);
  float v = stats[48 + (b*4+g)*2+1] * (1.f/NG) - m*m;
  float e = epre[(size_t)pix*128+c];
  float en = siluf((e-m)*rsqrtf(v+1e-5f)*rg_g[c] + rg_b[c]);
  float pv = en * pw_w[c];
  pv += __shfl_xor(pv,1);  pv += __shfl_xor(pv,2);  pv += __shfl_xor(pv,4);
  pv += __shfl_xor(pv,8);  pv += __shfl_xor(pv,16); pv += __shfl_xor(pv,32);
  if ((tid & 63) == 0) part[tid>>6] = pv;
  __syncthreads();
  if (tid < 2) edge_s[tid] = sigm(part[tid*2] + part[tid*2+1] + pw_b[0]);
  __syncthreads();
  if (c < 10){
    float ed = edge_s[pixl];
    int o = c;
    float lg = logits[(size_t)pix*16 + o];
    float loc = 0.f;
    for (int dy = -1; dy <= 1; dy++){
      int ny = yy+dy; if (ny < 0 || ny > 63) continue;
      for (int dx = -1; dx <= 1; dx++){
        int nx = xx+dx; if (nx < 0 || nx > 63) continue;
        loc += logits[(size_t)((b<<12)|(ny<<6)|nx)*16 + o];
      }
    }
    loc *= (1.f/9.f);
    outp[(size_t)((b*10+o)<<12) + p] = lg + alpha[0]*(1.f-ed)*(loc - lg);
  }
}

extern "C" void kernel_launch(void* const* d_in, const int* in_sizes, int n_in,
                              void* d_out, int out_size, void* d_ws, size_t ws_size,
                              hipStream_t stream){
  const float* x          = (const float*)d_in[0];
  const float* pe_w       = (const float*)d_in[1];
  const float* pe_b       = (const float*)d_in[2];
  const float* pe_gn_g    = (const float*)d_in[3];
  const float* pe_gn_b    = (const float*)d_in[4];
  const float* spa_in_w   = (const float*)d_in[5];
  const float* spa_conv_w = (const float*)d_in[6];
  const float* spa_conv_b = (const float*)d_in[7];
  const float* spa_xproj_w= (const float*)d_in[8];
  const float* spa_dt_w   = (const float*)d_in[9];
  const float* spa_dt_b   = (const float*)d_in[10];
  const float* spa_Alog   = (const float*)d_in[11];
  const float* spa_D      = (const float*)d_in[12];
  const float* spa_out_w  = (const float*)d_in[13];
  const float* spa_gn_g   = (const float*)d_in[14];
  const float* spa_gn_b   = (const float*)d_in[15];
  const float* spe_in_w   = (const float*)d_in[16];
  const float* spe_conv_w = (const float*)d_in[17];
  const float* spe_conv_b = (const float*)d_in[18];
  const float* spe_xproj_w= (const float*)d_in[19];
  const float* spe_dt_w   = (const float*)d_in[20];
  const float* spe_dt_b   = (const float*)d_in[21];
  const float* spe_Alog   = (const float*)d_in[22];
  const float* spe_D      = (const float*)d_in[23];
  const float* spe_out_w  = (const float*)d_in[24];
  const float* spe_gn_g   = (const float*)d_in[25];
  const float* spe_gn_b   = (const float*)d_in[26];
  const float* fuse_w     = (const float*)d_in[27];
  const float* cls_w      = (const float*)d_in[28];
  const float* cls_b      = (const float*)d_in[29];
  const float* ref_dw_w   = (const float*)d_in[30];
  const float* ref_gn_g   = (const float*)d_in[31];
  const float* ref_gn_b   = (const float*)d_in[32];
  const float* ref_pw_w   = (const float*)d_in[33];
  const float* ref_pw_b   = (const float*)d_in[34];
  const float* alpha      = (const float*)d_in[35];
  float* ws  = (float*)d_ws;
  float* out = (float*)d_out;

  float* partPE  = ws + WS_Y;    // dead until scan3 writes y
  float* partSPA = ws + WS_HS;   // dead after scan3
  float* partSPE = ws + WS_Q;    // dead after scan2
  float* partDW  = ws + WS_P;    // dead after scan2
  float* proj  = ws + WS_XZ;     // xz region is dead after k_conv
  float* xc2   = ws + WS_XC;
  float* xc2T  = ws + WS_ZSIL;
  float* zsil2 = ws + WS_XZ;     // proj dead after scans
  float* proj2 = ws + WS_XZ + 2097152;  // spe proj [32768][36]
  float* yg    = ws + WS_Y;

  k_transpose<<<64,256,0,stream>>>(pe_w, spa_in_w, spa_out_w,
      ws+WS_PEWT, ws+WS_INWT, ws+WS_OUTWT);
  k_pe<<<dim3(256,2),256,0,stream>>>(x, ws+WS_PEWT, pe_b, ws+WS_H1PRE, partPE);
  k_red<<<16,256,0,stream>>>(partPE, ws+WS_STATS+0, 256);
  k_xz<<<dim3(128,8),256,0,stream>>>(ws+WS_H1PRE, ws+WS_INWT, ws+WS_STATS,
      pe_gn_g, pe_gn_b, ws+WS_H1, ws+WS_XZ, ws+WS_ZSIL);
  k_conv<<<8192,256,0,stream>>>(ws+WS_XZ, spa_conv_w, spa_conv_b, ws+WS_XC);
  k_proj<<<512,256,0,stream>>>(ws+WS_XC, spa_xproj_w, proj);
  k_scan1<<<128,256,0,stream>>>(proj, ws+WS_XC, spa_dt_w, spa_dt_b, spa_Alog,
      ws+WS_P, ws+WS_Q);
  k_scan2<<<128,256,0,stream>>>(ws+WS_P, ws+WS_Q, ws+WS_HS);
  k_scan3<<<128,256,0,stream>>>(proj, ws+WS_XC, ws+WS_ZSIL, spa_dt_w, spa_dt_b,
      spa_Alog, spa_D, ws+WS_HS, ws+WS_Y);
  k_outproj<<<dim3(256,2),256,0,stream>>>(ws+WS_Y, ws+WS_OUTWT, ws+WS_H1PRE, partSPA);
  k_red<<<16,256,0,stream>>>(partSPA, ws+WS_STATS+16, 256);
  k_spe_a<<<512,256,0,stream>>>(ws+WS_H1, spe_in_w, spe_conv_w, spe_conv_b,
      xc2, xc2T, zsil2);
  k_spe_b<<<128,256,0,stream>>>(xc2T, spe_xproj_w, proj2);
  k_spe_c<<<512,256,0,stream>>>(xc2, zsil2, proj2, spe_dt_w, spe_dt_b,
      spe_Alog, spe_D, yg);
  k_spe_d<<<512,256,0,stream>>>(yg, spe_out_w, ws+WS_Y2, partSPE);
  k_red<<<16,256,0,stream>>>(partSPE, ws+WS_STATS+32, 256);
  k_fuse<<<4096,256,0,stream>>>(ws+WS_H1, ws+WS_H1PRE, ws+WS_Y2, ws+WS_STATS,
      spa_gn_g, spa_gn_b, spe_gn_g, spe_gn_b, fuse_w, cls_w, cls_b,
      ws+WS_FEAT, ws+WS_LOG);
  k_dw<<<4096,256,0,stream>>>(ws+WS_FEAT, ref_dw_w, ws+WS_Y, partDW);
  k_red<<<16,256,0,stream>>>(partDW, ws+WS_STATS+48, 2048);
  k_final<<<4096,256,0,stream>>>(ws+WS_Y, ws+WS_LOG, ws+WS_STATS,
      ref_gn_g, ref_gn_b, ref_pw_w, ref_pw_b, alpha, out);
  (void)in_sizes; (void)n_in; (void)out_size; (void)ws_size;
}

// Round 7
// 422.862 us; speedup vs baseline: 1.1659x; 1.1249x over previous
//
#include <hip/hip_runtime.h>
#include <math.h>

#define DEV __device__ __forceinline__

DEV float sigm(float x){ return 1.f/(1.f+__expf(-x)); }
DEV float siluf(float x){ return x * sigm(x); }
DEV float softplusf(float x){ return x > 20.f ? x : log1pf(__expf(x)); }

static constexpr float NG = 131072.0f;   // group-norm element count per (b,g): 32*64*64

// ---- workspace layout (offsets in floats) ----
static constexpr size_t WS_H1    = 0;          // B*HW*128
static constexpr size_t WS_H1PRE = 1048576;    // h1pre; then scan P [2][128][4096]; then yproj
static constexpr size_t WS_XC    = 2097152;    // spa xc; later spe xc2
static constexpr size_t WS_ZSIL  = 4194304;    // spa zsil; later spe xc2T
static constexpr size_t WS_XZ    = 6291456;    // xz x-part; then proj[8192][40]; later spe zsil2
static constexpr size_t WS_LOG   = 8650752;    // logits (stride 16)
static constexpr size_t WS_Y     = 10485760;   // pe partials; y; spe yg; e_pre
static constexpr size_t WS_QB    = 12582912;   // scan Q [2][128][4096] (1M); after scan2: partials
static constexpr size_t WS_HSB   = 13631488;   // scan hs [2][128][4096] (1M; overlaps old Y2 half)
static constexpr size_t WS_Y2    = 14155776;   // B*HW*128 (written after scan3)
static constexpr size_t WS_FEAT  = 15204352;   // B*HW*128
static constexpr size_t WS_STATS = 16252928;   // 64 floats: pe@0 spa@16 spe@32 ref@48
static constexpr size_t WS_PEWT  = 16253056;   // 128*128
static constexpr size_t WS_INWT  = WS_PEWT  + 16384;  // 128*512
static constexpr size_t WS_OUTWT = WS_INWT  + 65536;  // 256*128

// ---------------- partial-stats reduction: grid = 16 (b in 0..1, j in 0..7) ----
__global__ void __launch_bounds__(256)
k_red(const float* __restrict__ part, float* __restrict__ outS, int half){
  __shared__ float red[4];
  int b = blockIdx.x >> 3, j = blockIdx.x & 7;
  float s = 0.f;
  for (int i = b*half + threadIdx.x; i < (b+1)*half; i += 256)
    s += part[(size_t)i*8 + j];
  s += __shfl_xor(s,1); s += __shfl_xor(s,2); s += __shfl_xor(s,4);
  s += __shfl_xor(s,8); s += __shfl_xor(s,16); s += __shfl_xor(s,32);
  if ((threadIdx.x & 63) == 0) red[threadIdx.x>>6] = s;
  __syncthreads();
  if (threadIdx.x == 0) outS[b*8+j] = red[0]+red[1]+red[2]+red[3];
}

// ---------------- transpose weights (spa side only) ----------------
__global__ void __launch_bounds__(256)
k_transpose(const float* __restrict__ pe_w, const float* __restrict__ in_w,
            const float* __restrict__ out_w,
            float* __restrict__ peT, float* __restrict__ inT,
            float* __restrict__ outT){
  int i0 = blockIdx.x*256 + threadIdx.x;
  int nt = gridDim.x*256;
  for (int k = i0; k < 128*128; k += nt){ int r = k >> 7, c = k & 127; peT[c*128 + r] = pe_w[k]; }
  for (int k = i0; k < 512*128; k += nt){ int r = k >> 7, c = k & 127; inT[c*512 + r] = in_w[k]; }
  for (int k = i0; k < 128*256; k += nt){ int r = k >> 8, c = k & 255; outT[c*128 + r] = out_w[k]; }
}

// ---------------- pe 1x1 conv (tiled GEMM 32x64) + GN partial stats ----------
__global__ void __launch_bounds__(256)
k_pe(const float* __restrict__ x, const float* __restrict__ peT,
     const float* __restrict__ pe_b, float* __restrict__ h1pre,
     float* __restrict__ part){
  __shared__ float As[16][36];
  __shared__ float Bs[16][64];
  __shared__ float red1[2][4], red2[2][4];
  int tid = threadIdx.x;
  int bx = blockIdx.x, by = blockIdx.y;
  int m0 = bx*32, n0 = by*64;
  int b = m0 >> 12, pl0 = m0 & 4095;
  int tx = tid & 15, ty = tid >> 4;
  float acc[2][4];
  #pragma unroll
  for (int i = 0; i < 2; i++)
    #pragma unroll
    for (int j = 0; j < 4; j++) acc[i][j] = 0.f;
  for (int k0 = 0; k0 < 128; k0 += 16){
    if (tid < 128){
      int k = tid >> 3, mm = (tid & 7)*4;
      float4 a = *(const float4*)(x + ((size_t)b*128 + k0+k)*4096 + pl0 + mm);
      *(float4*)&As[k][mm] = a;
    }
    {
      int k = tid >> 4, n = (tid & 15)*4;
      *(float4*)&Bs[k][n] = *(const float4*)(peT + (size_t)(k0+k)*128 + n0+n);
    }
    __syncthreads();
    #pragma unroll
    for (int k = 0; k < 16; k++){
      float2 av = *(const float2*)&As[k][ty*2];
      float4 bv = *(const float4*)&Bs[k][tx*4];
      acc[0][0] += av.x*bv.x; acc[0][1] += av.x*bv.y; acc[0][2] += av.x*bv.z; acc[0][3] += av.x*bv.w;
      acc[1][0] += av.y*bv.x; acc[1][1] += av.y*bv.y; acc[1][2] += av.y*bv.z; acc[1][3] += av.y*bv.w;
    }
    __syncthreads();
  }
  float4 bias = *(const float4*)(pe_b + n0 + tx*4);
  float s1 = 0.f, s2 = 0.f;
  #pragma unroll
  for (int i = 0; i < 2; i++){
    float4 st;
    st.x = acc[i][0]+bias.x; st.y = acc[i][1]+bias.y;
    st.z = acc[i][2]+bias.z; st.w = acc[i][3]+bias.w;
    s1 += st.x+st.y+st.z+st.w;
    s2 += st.x*st.x + st.y*st.y + st.z*st.z + st.w*st.w;
    *(float4*)(h1pre + (size_t)(m0 + ty*2 + i)*128 + n0 + tx*4) = st;
  }
  s1 += __shfl_xor(s1,1);  s2 += __shfl_xor(s2,1);
  s1 += __shfl_xor(s1,2);  s2 += __shfl_xor(s2,2);
  s1 += __shfl_xor(s1,4);  s2 += __shfl_xor(s2,4);
  s1 += __shfl_xor(s1,16); s2 += __shfl_xor(s2,16);
  s1 += __shfl_xor(s1,32); s2 += __shfl_xor(s2,32);
  int lane = tid & 63, w = tid >> 6;
  if ((lane & 55) == 0){
    int gl = (lane >> 3) & 1;
    red1[gl][w] = s1; red2[gl][w] = s2;
  }
  __syncthreads();
  if (tid < 8){
    int gg = tid >> 1, which = tid & 1;
    int gl = gg - by*2;
    float v = 0.f;
    if (gl == 0 || gl == 1){
      v = which ? (red2[gl][0]+red2[gl][1]+red2[gl][2]+red2[gl][3])
                : (red1[gl][0]+red1[gl][1]+red1[gl][2]+red1[gl][3]);
    }
    int pblk = b*256 + (bx & 127) + by*128;
    part[(size_t)pblk*8 + tid] = v;
  }
}

// ---------------- spa in-proj GEMM 64x64, fused GN+silu on A, z-silu out -----
__global__ void __launch_bounds__(256)
k_xz(const float* __restrict__ h1pre, const float* __restrict__ inT,
     const float* __restrict__ stats, const float* __restrict__ gng,
     const float* __restrict__ gnb, float* __restrict__ h1,
     float* __restrict__ xz, float* __restrict__ zsil){
  __shared__ float As[16][68];
  __shared__ float Bs[16][64];
  int tid = threadIdx.x;
  int m0 = blockIdx.x*64, n0 = blockIdx.y*64;
  int tx = tid & 15, ty = tid >> 4;
  float acc[4][4];
  #pragma unroll
  for (int i = 0; i < 4; i++)
    #pragma unroll
    for (int j = 0; j < 4; j++) acc[i][j] = 0.f;
  for (int k0 = 0; k0 < 128; k0 += 16){
    {
      int m = tid >> 2, kk = (tid & 3)*4;
      int pixm = m0 + m, c0 = k0 + kk;
      int bb = pixm >> 12, g = c0 >> 5;
      float4 a = *(const float4*)(h1pre + (size_t)pixm*128 + c0);
      float mu = stats[(bb*4+g)*2] * (1.f/NG);
      float var = stats[(bb*4+g)*2+1] * (1.f/NG) - mu*mu;
      float rs = rsqrtf(var + 1e-5f);
      float4 gg = *(const float4*)(gng + c0);
      float4 gb = *(const float4*)(gnb + c0);
      float4 v;
      v.x = siluf((a.x-mu)*rs*gg.x + gb.x);
      v.y = siluf((a.y-mu)*rs*gg.y + gb.y);
      v.z = siluf((a.z-mu)*rs*gg.z + gb.z);
      v.w = siluf((a.w-mu)*rs*gg.w + gb.w);
      As[kk+0][m] = v.x; As[kk+1][m] = v.y; As[kk+2][m] = v.z; As[kk+3][m] = v.w;
      if (blockIdx.y == 0) *(float4*)(h1 + (size_t)pixm*128 + c0) = v;
    }
    {
      int k = tid >> 4, n = (tid & 15)*4;
      *(float4*)&Bs[k][n] = *(const float4*)(inT + (size_t)(k0+k)*512 + n0+n);
    }
    __syncthreads();
    #pragma unroll
    for (int k = 0; k < 16; k++){
      float4 av = *(const float4*)&As[k][ty*4];
      float4 bv = *(const float4*)&Bs[k][tx*4];
      acc[0][0] += av.x*bv.x; acc[0][1] += av.x*bv.y; acc[0][2] += av.x*bv.z; acc[0][3] += av.x*bv.w;
      acc[1][0] += av.y*bv.x; acc[1][1] += av.y*bv.y; acc[1][2] += av.y*bv.z; acc[1][3] += av.y*bv.w;
      acc[2][0] += av.z*bv.x; acc[2][1] += av.z*bv.y; acc[2][2] += av.z*bv.z; acc[2][3] += av.z*bv.w;
      acc[3][0] += av.w*bv.x; acc[3][1] += av.w*bv.y; acc[3][2] += av.w*bv.z; acc[3][3] += av.w*bv.w;
    }
    __syncthreads();
  }
  if (n0 < 256){
    #pragma unroll
    for (int i = 0; i < 4; i++){
      float4 st; st.x = acc[i][0]; st.y = acc[i][1]; st.z = acc[i][2]; st.w = acc[i][3];
      *(float4*)(xz + (size_t)(m0 + ty*4 + i)*512 + n0 + tx*4) = st;
    }
  } else {
    #pragma unroll
    for (int i = 0; i < 4; i++){
      float4 st;
      st.x = siluf(acc[i][0]); st.y = siluf(acc[i][1]);
      st.z = siluf(acc[i][2]); st.w = siluf(acc[i][3]);
      *(float4*)(zsil + (size_t)(m0 + ty*4 + i)*256 + (n0-256) + tx*4) = st;
    }
  }
}

// ---------------- causal depthwise conv K=4 + silu (x-part only) -------------
__global__ void __launch_bounds__(256)
k_conv(const float* __restrict__ xz, const float* __restrict__ cw,
       const float* __restrict__ cb, float* __restrict__ xc){
  int idx = blockIdx.x*256 + threadIdx.x;
  int d = idx & 255;
  int l = (idx >> 8) & 4095;
  int b = idx >> 20;
  float v = cb[d];
  #pragma unroll
  for (int k = 0; k < 4; k++){
    int ls = l - 3 + k;
    if (ls >= 0) v += xz[(size_t)(b*4096 + ls)*512 + d] * cw[d*4 + k];
  }
  xc[idx] = siluf(v);
}

// ---------------- x-proj tiled GEMM: proj[tok][40] ----------------
// grid 256; block = 32 tokens x 8 j-groups (5 outputs each). 8192 tokens.
__global__ void __launch_bounds__(256)
k_proj(const float* __restrict__ xc, const float* __restrict__ xpw,
       float* __restrict__ proj){
  __shared__ float As[32][33];
  int tid = threadIdx.x;
  int t = tid & 31;
  int jg = tid >> 5;
  int tok0 = blockIdx.x * 32;
  float acc[5];
  #pragma unroll
  for (int j = 0; j < 5; j++) acc[j] = 0.f;
  for (int k0 = 0; k0 < 256; k0 += 32){
    {
      int m = tid >> 3, kk = (tid & 7)*4;
      float4 a = *(const float4*)(xc + (size_t)(tok0+m)*256 + k0+kk);
      As[kk+0][m]=a.x; As[kk+1][m]=a.y; As[kk+2][m]=a.z; As[kk+3][m]=a.w;
    }
    __syncthreads();
    #pragma unroll
    for (int k4 = 0; k4 < 8; k4++){
      float a0 = As[k4*4+0][t];
      float a1 = As[k4*4+1][t];
      float a2 = As[k4*4+2][t];
      float a3 = As[k4*4+3][t];
      #pragma unroll
      for (int j = 0; j < 5; j++){
        float4 w = *(const float4*)(xpw + (size_t)(jg*5+j)*256 + k0 + k4*4);
        acc[j] += a0*w.x + a1*w.y + a2*w.z + a3*w.w;
      }
    }
    __syncthreads();
  }
  float* pr = proj + (size_t)(tok0+t)*40 + jg*5;
  #pragma unroll
  for (int j = 0; j < 5; j++) pr[j] = acc[j];
}

// ---------------- scan phase 1: thread=(d, n-quartet), 32-step chunks --------
// grid 1024 = 2b x 128chunk x 4dblk.
__global__ void __launch_bounds__(256)
k_scan1(const float* __restrict__ proj, const float* __restrict__ xc,
        const float* __restrict__ dtw, const float* __restrict__ dtb,
        const float* __restrict__ Alog, float* __restrict__ P,
        float* __restrict__ Q){
  int blk = blockIdx.x;
  int dblk = blk & 3;
  int bc = blk >> 2;                 // b*128 + chunk
  int b = bc >> 7, chunk = bc & 127;
  int tid = threadIdx.x;
  int dl = tid >> 2, ng = tid & 3;
  int d = dblk*64 + dl;
  float4 a4 = *(const float4*)(Alog + (size_t)d*16 + ng*4);
  float An[4] = {-__expf(a4.x), -__expf(a4.y), -__expf(a4.z), -__expf(a4.w)};
  const float4* wr = (const float4*)(dtw + (size_t)d*8);
  float4 w0 = wr[0], w1 = wr[1];
  float bd = dtb[d];
  float Pv[4] = {1.f,1.f,1.f,1.f}, Qv[4] = {0.f,0.f,0.f,0.f};
  size_t row0 = (size_t)(b*4096 + chunk*32);
  for (int l = 0; l < 32; l++){
    size_t r = row0 + l;
    const float4* pr4 = (const float4*)(proj + r*40);
    float4 p0 = pr4[0], p1 = pr4[1];
    float4 bm = pr4[2+ng];
    float dv = softplusf(bd + p0.x*w0.x + p0.y*w0.y + p0.z*w0.z + p0.w*w0.w
                            + p1.x*w1.x + p1.y*w1.y + p1.z*w1.z + p1.w*w1.w);
    float xv = xc[r*256 + d];
    float dBx = dv*xv;
    float bmv[4] = {bm.x, bm.y, bm.z, bm.w};
    #pragma unroll
    for (int k = 0; k < 4; k++){
      float a = __expf(dv*An[k]);
      Qv[k] = a*Qv[k] + bmv[k]*dBx;
      Pv[k] *= a;
    }
  }
  size_t o = (size_t)bc*4096 + dblk*1024 + tid*4;
  float4 pv; pv.x=Pv[0]; pv.y=Pv[1]; pv.z=Pv[2]; pv.w=Pv[3];
  float4 qv; qv.x=Qv[0]; qv.y=Qv[1]; qv.z=Qv[2]; qv.w=Qv[3];
  *(float4*)(P + o) = pv;
  *(float4*)(Q + o) = qv;
}

// ---------------- scan phase 2: 128-chunk scan, lane owns chunk pair ---------
// grid 256: b = blk>>7, dn0 = (blk&127)*32. 32 chains/block.
__global__ void __launch_bounds__(256)
k_scan2(const float* __restrict__ P, const float* __restrict__ Q,
        float* __restrict__ hs){
  __shared__ float Ps[128][33], Qs[128][33];
  int tid = threadIdx.x;
  int b = blockIdx.x >> 7;
  int dn0 = (blockIdx.x & 127) * 32;
  for (int i = tid; i < 128*8; i += 256){
    int ch = i >> 3, c4 = (i & 7)*4;
    size_t g = (size_t)(b*128+ch)*4096 + dn0 + c4;
    float4 p = *(const float4*)(P + g);
    float4 q = *(const float4*)(Q + g);
    Ps[ch][c4]=p.x; Ps[ch][c4+1]=p.y; Ps[ch][c4+2]=p.z; Ps[ch][c4+3]=p.w;
    Qs[ch][c4]=q.x; Qs[ch][c4+1]=q.y; Qs[ch][c4+2]=q.z; Qs[ch][c4+3]=q.w;
  }
  __syncthreads();
  int lane = tid & 63, wv = tid >> 6;
  for (int rep = 0; rep < 8; rep++){
    int c = wv*8 + rep;
    float p0 = Ps[2*lane][c],   q0 = Qs[2*lane][c];
    float p1 = Ps[2*lane+1][c], q1 = Qs[2*lane+1][c];
    float p = p0*p1;
    float q = p1*q0 + q1;
    #pragma unroll
    for (int off = 1; off < 64; off <<= 1){
      float pp = __shfl_up(p, off);
      float qp = __shfl_up(q, off);
      if (lane >= off){ q = p*qp + q; p = p*pp; }
    }
    float hprev = __shfl_up(q, 1);
    if (lane == 0) hprev = 0.f;
    Ps[2*lane][c]   = hprev;
    Ps[2*lane+1][c] = p0*hprev + q0;
  }
  __syncthreads();
  for (int i = tid; i < 128*8; i += 256){
    int ch = i >> 3, c4 = (i & 7)*4;
    size_t g = (size_t)(b*128+ch)*4096 + dn0 + c4;
    float4 h;
    h.x = Ps[ch][c4]; h.y = Ps[ch][c4+1]; h.z = Ps[ch][c4+2]; h.w = Ps[ch][c4+3];
    *(float4*)(hs + g) = h;
  }
}

// ---------------- scan phase 3: replay + y; thread=(d, n-quartet) ------------
__global__ void __launch_bounds__(256)
k_scan3(const float* __restrict__ proj, const float* __restrict__ xc,
        const float* __restrict__ zsil, const float* __restrict__ dtw,
        const float* __restrict__ dtb, const float* __restrict__ Alog,
        const float* __restrict__ Dv, const float* __restrict__ hs,
        float* __restrict__ y){
  int blk = blockIdx.x;
  int dblk = blk & 3;
  int bc = blk >> 2;
  int b = bc >> 7, chunk = bc & 127;
  int tid = threadIdx.x;
  int dl = tid >> 2, ng = tid & 3;
  int d = dblk*64 + dl;
  float4 a4 = *(const float4*)(Alog + (size_t)d*16 + ng*4);
  float An[4] = {-__expf(a4.x), -__expf(a4.y), -__expf(a4.z), -__expf(a4.w)};
  const float4* wr = (const float4*)(dtw + (size_t)d*8);
  float4 w0 = wr[0], w1 = wr[1];
  float bd = dtb[d];
  float Dd = Dv[d];
  float h[4];
  {
    size_t o = (size_t)bc*4096 + dblk*1024 + tid*4;
    float4 hv = *(const float4*)(hs + o);
    h[0]=hv.x; h[1]=hv.y; h[2]=hv.z; h[3]=hv.w;
  }
  size_t row0 = (size_t)(b*4096 + chunk*32);
  for (int l = 0; l < 32; l++){
    size_t r = row0 + l;
    const float4* pr4 = (const float4*)(proj + r*40);
    float4 p0 = pr4[0], p1 = pr4[1];
    float4 bm = pr4[2+ng];
    float4 cm = pr4[6+ng];
    float dv = softplusf(bd + p0.x*w0.x + p0.y*w0.y + p0.z*w0.z + p0.w*w0.w
                            + p1.x*w1.x + p1.y*w1.y + p1.z*w1.z + p1.w*w1.w);
    float xv = xc[r*256 + d];
    float dBx = dv*xv;
    float bmv[4] = {bm.x, bm.y, bm.z, bm.w};
    float cmv[4] = {cm.x, cm.y, cm.z, cm.w};
    float ys = 0.f;
    #pragma unroll
    for (int k = 0; k < 4; k++){
      float a = __expf(dv*An[k]);
      h[k] = a*h[k] + bmv[k]*dBx;
      ys += h[k]*cmv[k];
    }
    ys += __shfl_xor(ys, 1);
    ys += __shfl_xor(ys, 2);
    if (ng == 0){
      float zv = zsil[r*256 + d];
      y[r*256 + d] = (ys + Dd*xv) * zv;
    }
  }
}

// ---------------- spa out-proj: tiled GEMM 32x64 + GN partial stats ----------
__global__ void __launch_bounds__(256)
k_outproj(const float* __restrict__ y, const float* __restrict__ outT,
          float* __restrict__ yproj, float* __restrict__ part){
  __shared__ float As[16][36];
  __shared__ float Bs[16][64];
  __shared__ float red1[2][4], red2[2][4];
  int tid = threadIdx.x;
  int bx = blockIdx.x, by = blockIdx.y;
  int m0 = bx*32, n0 = by*64;
  int b = m0 >> 12;
  int tx = tid & 15, ty = tid >> 4;
  float acc[2][4];
  #pragma unroll
  for (int i = 0; i < 2; i++)
    #pragma unroll
    for (int j = 0; j < 4; j++) acc[i][j] = 0.f;
  for (int k0 = 0; k0 < 256; k0 += 16){
    if (tid < 128){
      int m = tid >> 2, kk = (tid & 3)*4;
      float4 a = *(const float4*)(y + (size_t)(m0+m)*256 + k0+kk);
      As[kk+0][m] = a.x; As[kk+1][m] = a.y; As[kk+2][m] = a.z; As[kk+3][m] = a.w;
    }
    {
      int k = tid >> 4, n = (tid & 15)*4;
      *(float4*)&Bs[k][n] = *(const float4*)(outT + (size_t)(k0+k)*128 + n0+n);
    }
    __syncthreads();
    #pragma unroll
    for (int k = 0; k < 16; k++){
      float2 av = *(const float2*)&As[k][ty*2];
      float4 bv = *(const float4*)&Bs[k][tx*4];
      acc[0][0] += av.x*bv.x; acc[0][1] += av.x*bv.y; acc[0][2] += av.x*bv.z; acc[0][3] += av.x*bv.w;
      acc[1][0] += av.y*bv.x; acc[1][1] += av.y*bv.y; acc[1][2] += av.y*bv.z; acc[1][3] += av.y*bv.w;
    }
    __syncthreads();
  }
  float s1 = 0.f, s2 = 0.f;
  #pragma unroll
  for (int i = 0; i < 2; i++){
    float4 st; st.x = acc[i][0]; st.y = acc[i][1]; st.z = acc[i][2]; st.w = acc[i][3];
    s1 += st.x+st.y+st.z+st.w;
    s2 += st.x*st.x + st.y*st.y + st.z*st.z + st.w*st.w;
    *(float4*)(yproj + (size_t)(m0 + ty*2 + i)*128 + n0 + tx*4) = st;
  }
  s1 += __shfl_xor(s1,1);  s2 += __shfl_xor(s2,1);
  s1 += __shfl_xor(s1,2);  s2 += __shfl_xor(s2,2);
  s1 += __shfl_xor(s1,4);  s2 += __shfl_xor(s2,4);
  s1 += __shfl_xor(s1,16); s2 += __shfl_xor(s2,16);
  s1 += __shfl_xor(s1,32); s2 += __shfl_xor(s2,32);
  int lane = tid & 63, w = tid >> 6;
  if ((lane & 55) == 0){
    int gl = (lane >> 3) & 1;
    red1[gl][w] = s1; red2[gl][w] = s2;
  }
  __syncthreads();
  if (tid < 8){
    int gg = tid >> 1, which = tid & 1;
    int gl = gg - by*2;
    float v = 0.f;
    if (gl == 0 || gl == 1){
      v = which ? (red2[gl][0]+red2[gl][1]+red2[gl][2]+red2[gl][3])
                : (red1[gl][0]+red1[gl][1]+red1[gl][2]+red1[gl][3]);
    }
    int pblk = b*256 + (bx & 127) + by*128;
    part[(size_t)pblk*8 + tid] = v;
  }
}

// ---------------- spe A: in-proj + conv + silu (reg weights, lane=d) ----------
__global__ void __launch_bounds__(256)
k_spe_a(const float* __restrict__ h1, const float* __restrict__ in_w,
        const float* __restrict__ conv_w, const float* __restrict__ conv_b,
        float* __restrict__ xc2, float* __restrict__ xc2T,
        float* __restrict__ zsil2){
  __shared__ float s_in[4][128];
  int tid = threadIdx.x;
  int w = tid >> 6, lane = tid & 63;
  float wx[32], wz[32];
  {
    const float4* rx = (const float4*)(in_w + (size_t)lane*32);
    const float4* rz = (const float4*)(in_w + (size_t)(64+lane)*32);
    #pragma unroll
    for (int k = 0; k < 8; k++){
      float4 a = rx[k]; wx[k*4]=a.x; wx[k*4+1]=a.y; wx[k*4+2]=a.z; wx[k*4+3]=a.w;
      float4 b = rz[k]; wz[k*4]=b.x; wz[k*4+1]=b.y; wz[k*4+2]=b.z; wz[k*4+3]=b.w;
    }
  }
  float4 cwv = ((const float4*)conv_w)[lane];
  float cbv = conv_b[lane];
  for (int i = 0; i < 4; i++){
    int pix = blockIdx.x*16 + w*4 + i;
    float2 hv = ((const float2*)(h1 + (size_t)pix*128))[lane];
    s_in[w][2*lane] = hv.x; s_in[w][2*lane+1] = hv.y;
    float xpr[4], zs[4];
    #pragma unroll
    for (int l = 0; l < 4; l++){
      const float4* sv = (const float4*)&s_in[w][l*32];
      float ax = 0.f, az = 0.f;
      #pragma unroll
      for (int c4 = 0; c4 < 8; c4++){
        float4 v = sv[c4];
        ax += v.x*wx[c4*4] + v.y*wx[c4*4+1] + v.z*wx[c4*4+2] + v.w*wx[c4*4+3];
        az += v.x*wz[c4*4] + v.y*wz[c4*4+1] + v.z*wz[c4*4+2] + v.w*wz[c4*4+3];
      }
      xpr[l] = ax; zs[l] = siluf(az);
    }
    #pragma unroll
    for (int l = 0; l < 4; l++){
      float v = cbv;
      if (l >= 3) v += xpr[l-3]*cwv.x;
      if (l >= 2) v += xpr[l-2]*cwv.y;
      if (l >= 1) v += xpr[l-1]*cwv.z;
      v += xpr[l]*cwv.w;
      float sx = siluf(v);
      int tok = pix*4 + l;
      xc2 [(size_t)tok*64 + lane] = sx;
      xc2T[(size_t)lane*32768 + tok] = sx;
      zsil2[(size_t)tok*64 + lane] = zs[l];
    }
  }
}

// ---------------- spe B: x-proj GEMM, thread = token --------------------------
__global__ void __launch_bounds__(256)
k_spe_b(const float* __restrict__ xc2T, const float* __restrict__ xpw,
        float* __restrict__ proj){
  int tok = blockIdx.x*256 + threadIdx.x;
  float xcv[64];
  #pragma unroll 64
  for (int dd = 0; dd < 64; dd++) xcv[dd] = xc2T[(size_t)dd*32768 + tok];
  float* pr = proj + (size_t)tok*36;
  #pragma unroll 2
  for (int j = 0; j < 34; j++){
    const float4* wr = (const float4*)(xpw + j*64);
    float a = 0.f;
    #pragma unroll
    for (int k = 0; k < 16; k++){
      float4 wv = wr[k];
      a += xcv[k*4]*wv.x + xcv[k*4+1]*wv.y + xcv[k*4+2]*wv.z + xcv[k*4+3]*wv.w;
    }
    pr[j] = a;
  }
}

// ---------------- spe C: delta + scan + gate (lane=d, 4 pixels/wave) ----------
__global__ void __launch_bounds__(256)
k_spe_c(const float* __restrict__ xc2, const float* __restrict__ zsil2,
        const float* __restrict__ proj, const float* __restrict__ dt_w,
        const float* __restrict__ dt_b, const float* __restrict__ Alog,
        const float* __restrict__ Dvec, float* __restrict__ yg){
  int tid = threadIdx.x;
  int w = tid >> 6, lane = tid & 63;
  float2 dtwv = ((const float2*)dt_w)[lane];
  float dbv = dt_b[lane], Dd = Dvec[lane];
  float An[16];
  {
    const float4* ar = (const float4*)(Alog + (size_t)lane*16);
    #pragma unroll
    for (int k = 0; k < 4; k++){
      float4 a = ar[k];
      An[k*4]   = -__expf(a.x); An[k*4+1] = -__expf(a.y);
      An[k*4+2] = -__expf(a.z); An[k*4+3] = -__expf(a.w);
    }
  }
  for (int i = 0; i < 4; i++){
    int pix = blockIdx.x*16 + w*4 + i;
    float h[16];
    #pragma unroll
    for (int n = 0; n < 16; n++) h[n] = 0.f;
    #pragma unroll
    for (int l = 0; l < 4; l++){
      int tok = pix*4 + l;
      float pj[36];
      {
        const float4* pr = (const float4*)(proj + (size_t)tok*36);
        #pragma unroll
        for (int k = 0; k < 9; k++){
          float4 v = pr[k];
          pj[k*4]=v.x; pj[k*4+1]=v.y; pj[k*4+2]=v.z; pj[k*4+3]=v.w;
        }
      }
      float xv = xc2[(size_t)tok*64 + lane];
      float zv = zsil2[(size_t)tok*64 + lane];
      float dt = softplusf(dbv + pj[0]*dtwv.x + pj[1]*dtwv.y);
      float ys = 0.f;
      #pragma unroll
      for (int n = 0; n < 16; n++){
        float a = __expf(dt * An[n]);
        h[n] = a*h[n] + dt * pj[2+n] * xv;
        ys += h[n] * pj[18+n];
      }
      yg[(size_t)tok*64 + lane] = (ys + Dd*xv) * zv;
    }
  }
}

// ---------------- spe D: out-proj GEMM + GN partial stats ---------------------
__global__ void __launch_bounds__(256)
k_spe_d(const float* __restrict__ yg, const float* __restrict__ out_w,
        float* __restrict__ y2, float* __restrict__ part){
  __shared__ float ldsWT[64*32];
  __shared__ float bst[8];
  int tid = threadIdx.x;
  for (int i = tid; i < 2048; i += 256){
    int c2 = i >> 6, dd = i & 63;
    ldsWT[dd*32 + c2] = out_w[i];
  }
  if (tid < 8) bst[tid] = 0.f;
  __syncthreads();
  int w = tid >> 6, lane = tid & 63;
  int c2 = lane & 31, slot = lane >> 5;
  int tokbase = blockIdx.x*64 + w*16 + slot;
  float acc[8];
  #pragma unroll
  for (int i = 0; i < 8; i++) acc[i] = 0.f;
  for (int dd4 = 0; dd4 < 16; dd4++){
    float w0 = ldsWT[(dd4*4+0)*32 + c2];
    float w1 = ldsWT[(dd4*4+1)*32 + c2];
    float w2 = ldsWT[(dd4*4+2)*32 + c2];
    float w3 = ldsWT[(dd4*4+3)*32 + c2];
    #pragma unroll
    for (int i = 0; i < 8; i++){
      int tok = tokbase + 2*i;
      float4 yv = ((const float4*)(yg + (size_t)tok*64))[dd4];
      acc[i] += yv.x*w0 + yv.y*w1 + yv.z*w2 + yv.w*w3;
    }
  }
  #pragma unroll
  for (int i = 0; i < 8; i++){
    int tok = tokbase + 2*i;
    int pix = tok >> 2, l = tok & 3;
    y2[(size_t)pix*128 + l*32 + c2] = acc[i];
    float s1 = acc[i], s2 = acc[i]*acc[i];
    s1 += __shfl_xor(s1,1);  s2 += __shfl_xor(s2,1);
    s1 += __shfl_xor(s1,2);  s2 += __shfl_xor(s2,2);
    s1 += __shfl_xor(s1,4);  s2 += __shfl_xor(s2,4);
    s1 += __shfl_xor(s1,8);  s2 += __shfl_xor(s2,8);
    s1 += __shfl_xor(s1,16); s2 += __shfl_xor(s2,16);
    if (c2 == 0){
      atomicAdd(&bst[l*2+0], s1);
      atomicAdd(&bst[l*2+1], s2);
    }
  }
  __syncthreads();
  if (tid < 8) part[(size_t)blockIdx.x*8 + tid] = bst[tid];
}

// ---------------- fuse: GN(spa)+GN(spe)+h1 -> feat, logits ----------------
__global__ void __launch_bounds__(256)
k_fuse(const float* __restrict__ h1, const float* __restrict__ yproj,
       const float* __restrict__ y2, const float* __restrict__ stats,
       const float* __restrict__ spa_g, const float* __restrict__ spa_b,
       const float* __restrict__ spe_g, const float* __restrict__ spe_b,
       const float* __restrict__ fuse_w, const float* __restrict__ cls_w,
       const float* __restrict__ cls_b, float* __restrict__ feat,
       float* __restrict__ logits){
  __shared__ float ft[2][128];
  int tid = threadIdx.x;
  int pixl = tid >> 7, c = tid & 127;
  int pix = blockIdx.x*2 + pixl;
  int b = pix >> 12, g = c >> 5;
  float m1 = stats[16 + (b*4+g)*2]   * (1.f/NG);
  float v1 = stats[16 + (b*4+g)*2+1] * (1.f/NG) - m1*m1;
  float m2 = stats[32 + (b*4+g)*2]   * (1.f/NG);
  float v2 = stats[32 + (b*4+g)*2+1] * (1.f/NG) - m2*m2;
  float h = h1[(size_t)pix*128 + c];
  float sa = siluf((yproj[(size_t)pix*128+c] - m1)*rsqrtf(v1+1e-5f)*spa_g[c] + spa_b[c]) + h;
  float sp = h + siluf((y2[(size_t)pix*128+c] - m2)*rsqrtf(v2+1e-5f)*spe_g[c] + spe_b[c]);
  float e0 = __expf(fuse_w[0]), e1 = __expf(fuse_w[1]);
  float w0 = e0/(e0+e1), w1 = e1/(e0+e1);
  float f = sa*w0 + sp*w1 + h;
  feat[(size_t)pix*128+c] = f;
  ft[pixl][c] = f;
  __syncthreads();
  if (tid < 20){
    int pl = (tid >= 10) ? 1 : 0;
    int o = tid - pl*10;
    float acc = cls_b[o];
    for (int cc = 0; cc < 128; cc++) acc += ft[pl][cc]*cls_w[o*128+cc];
    logits[(size_t)(blockIdx.x*2 + pl)*16 + o] = acc;
  }
}

// ---------------- depthwise 3x3 on feat + GN partial stats ----------------
__global__ void __launch_bounds__(256)
k_dw(const float* __restrict__ feat, const float* __restrict__ dww,
     float* __restrict__ epre, float* __restrict__ part){
  __shared__ float red1[4][64], red2[4][64];
  int tid = threadIdx.x;
  int pixl = tid >> 7, c = tid & 127;
  int pix = blockIdx.x*2 + pixl;
  int b = pix >> 12, p = pix & 4095, yy = p >> 6, xx = p & 63;
  float acc = 0.f;
  for (int dy = -1; dy <= 1; dy++){
    int ny = yy + dy; if (ny < 0 || ny > 63) continue;
    for (int dx = -1; dx <= 1; dx++){
      int nx = xx + dx; if (nx < 0 || nx > 63) continue;
      acc += feat[(size_t)((b<<12)|(ny<<6)|nx)*128 + c] * dww[c*9 + (dy+1)*3 + (dx+1)];
    }
  }
  epre[(size_t)pix*128 + c] = acc;
  int g = c >> 5;
  int idx = (c & 31) | (pixl << 5);
  red1[g][idx] = acc; red2[g][idx] = acc*acc;
  __syncthreads();
  int rg = tid >> 6, ridx = tid & 63;
  for (int s = 32; s >= 1; s >>= 1){
    if (ridx < s){ red1[rg][ridx] += red1[rg][ridx+s]; red2[rg][ridx] += red2[rg][ridx+s]; }
    __syncthreads();
  }
  if (ridx == 0){
    part[(size_t)blockIdx.x*8 + rg*2+0] = red1[rg][0];
    part[(size_t)blockIdx.x*8 + rg*2+1] = red2[rg][0];
  }
}

// ---------------- edge + local avg + final output ----------------
__global__ void __launch_bounds__(256)
k_final(const float* __restrict__ epre, const float* __restrict__ logits,
        const float* __restrict__ stats, const float* __restrict__ rg_g,
        const float* __restrict__ rg_b, const float* __restrict__ pw_w,
        const float* __restrict__ pw_b, const float* __restrict__ alpha,
        float* __restrict__ outp){
  __shared__ float part[4];
  __shared__ float edge_s[2];
  int tid = threadIdx.x;
  int pixl = tid >> 7, c = tid & 127;
  int pix = blockIdx.x*2 + pixl;
  int b = pix >> 12, p = pix & 4095, yy = p >> 6, xx = p & 63;
  int g = c >> 5;
  float m = stats[48 + (b*4+g)*2]   * (1.f/NG);
  float v = stats[48 + (b*4+g)*2+1] * (1.f/NG) - m*m;
  float e = epre[(size_t)pix*128+c];
  float en = siluf((e-m)*rsqrtf(v+1e-5f)*rg_g[c] + rg_b[c]);
  float pv = en * pw_w[c];
  pv += __shfl_xor(pv,1);  pv += __shfl_xor(pv,2);  pv += __shfl_xor(pv,4);
  pv += __shfl_xor(pv,8);  pv += __shfl_xor(pv,16); pv += __shfl_xor(pv,32);
  if ((tid & 63) == 0) part[tid>>6] = pv;
  __syncthreads();
  if (tid < 2) edge_s[tid] = sigm(part[tid*2] + part[tid*2+1] + pw_b[0]);
  __syncthreads();
  if (c < 10){
    float ed = edge_s[pixl];
    int o = c;
    float lg = logits[(size_t)pix*16 + o];
    float loc = 0.f;
    for (int dy = -1; dy <= 1; dy++){
      int ny = yy+dy; if (ny < 0 || ny > 63) continue;
      for (int dx = -1; dx <= 1; dx++){
        int nx = xx+dx; if (nx < 0 || nx > 63) continue;
        loc += logits[(size_t)((b<<12)|(ny<<6)|nx)*16 + o];
      }
    }
    loc *= (1.f/9.f);
    outp[(size_t)((b*10+o)<<12) + p] = lg + alpha[0]*(1.f-ed)*(loc - lg);
  }
}

extern "C" void kernel_launch(void* const* d_in, const int* in_sizes, int n_in,
                              void* d_out, int out_size, void* d_ws, size_t ws_size,
                              hipStream_t stream){
  const float* x          = (const float*)d_in[0];
  const float* pe_w       = (const float*)d_in[1];
  const float* pe_b       = (const float*)d_in[2];
  const float* pe_gn_g    = (const float*)d_in[3];
  const float* pe_gn_b    = (const float*)d_in[4];
  const float* spa_in_w   = (const float*)d_in[5];
  const float* spa_conv_w = (const float*)d_in[6];
  const float* spa_conv_b = (const float*)d_in[7];
  const float* spa_xproj_w= (const float*)d_in[8];
  const float* spa_dt_w   = (const float*)d_in[9];
  const float* spa_dt_b   = (const float*)d_in[10];
  const float* spa_Alog   = (const float*)d_in[11];
  const float* spa_D      = (const float*)d_in[12];
  const float* spa_out_w  = (const float*)d_in[13];
  const float* spa_gn_g   = (const float*)d_in[14];
  const float* spa_gn_b   = (const float*)d_in[15];
  const float* spe_in_w   = (const float*)d_in[16];
  const float* spe_conv_w = (const float*)d_in[17];
  const float* spe_conv_b = (const float*)d_in[18];
  const float* spe_xproj_w= (const float*)d_in[19];
  const float* spe_dt_w   = (const float*)d_in[20];
  const float* spe_dt_b   = (const float*)d_in[21];
  const float* spe_Alog   = (const float*)d_in[22];
  const float* spe_D      = (const float*)d_in[23];
  const float* spe_out_w  = (const float*)d_in[24];
  const float* spe_gn_g   = (const float*)d_in[25];
  const float* spe_gn_b   = (const float*)d_in[26];
  const float* fuse_w     = (const float*)d_in[27];
  const float* cls_w      = (const float*)d_in[28];
  const float* cls_b      = (const float*)d_in[29];
  const float* ref_dw_w   = (const float*)d_in[30];
  const float* ref_gn_g   = (const float*)d_in[31];
  const float* ref_gn_b   = (const float*)d_in[32];
  const float* ref_pw_w   = (const float*)d_in[33];
  const float* ref_pw_b   = (const float*)d_in[34];
  const float* alpha      = (const float*)d_in[35];
  float* ws  = (float*)d_ws;
  float* out = (float*)d_out;

  // scan buffers (chunk=32 -> 128 chunks): 1M floats each, on dead regions
  float* Pb  = ws + WS_H1PRE;  // h1pre dead after k_xz; yproj written after scan2
  float* Qb  = ws + WS_QB;
  float* HSb = ws + WS_HSB;    // overlaps WS_Y2 front half: y2 written after scan3
  // partials
  float* partPE  = ws + WS_Y;        // dead until scan3 writes y
  float* partSPA = ws + WS_QB;       // Q dead after scan2
  float* partSPE = ws + WS_QB + 16384;
  float* partDW  = ws + WS_QB + 65536;
  // proj + spe scratch
  float* proj  = ws + WS_XZ;         // xz dead after k_conv
  float* xc2   = ws + WS_XC;
  float* xc2T  = ws + WS_ZSIL;
  float* zsil2 = ws + WS_XZ;         // proj dead after scan3
  float* proj2 = ws + WS_XZ + 2097152;
  float* yg    = ws + WS_Y;

  k_transpose<<<64,256,0,stream>>>(pe_w, spa_in_w, spa_out_w,
      ws+WS_PEWT, ws+WS_INWT, ws+WS_OUTWT);
  k_pe<<<dim3(256,2),256,0,stream>>>(x, ws+WS_PEWT, pe_b, ws+WS_H1PRE, partPE);
  k_red<<<16,256,0,stream>>>(partPE, ws+WS_STATS+0, 256);
  k_xz<<<dim3(128,8),256,0,stream>>>(ws+WS_H1PRE, ws+WS_INWT, ws+WS_STATS,
      pe_gn_g, pe_gn_b, ws+WS_H1, ws+WS_XZ, ws+WS_ZSIL);
  k_conv<<<8192,256,0,stream>>>(ws+WS_XZ, spa_conv_w, spa_conv_b, ws+WS_XC);
  k_proj<<<256,256,0,stream>>>(ws+WS_XC, spa_xproj_w, proj);
  k_scan1<<<1024,256,0,stream>>>(proj, ws+WS_XC, spa_dt_w, spa_dt_b, spa_Alog,
      Pb, Qb);
  k_scan2<<<256,256,0,stream>>>(Pb, Qb, HSb);
  k_scan3<<<1024,256,0,stream>>>(proj, ws+WS_XC, ws+WS_ZSIL, spa_dt_w, spa_dt_b,
      spa_Alog, spa_D, HSb, ws+WS_Y);
  k_outproj<<<dim3(256,2),256,0,stream>>>(ws+WS_Y, ws+WS_OUTWT, ws+WS_H1PRE, partSPA);
  k_red<<<16,256,0,stream>>>(partSPA, ws+WS_STATS+16, 256);
  k_spe_a<<<512,256,0,stream>>>(ws+WS_H1, spe_in_w, spe_conv_w, spe_conv_b,
      xc2, xc2T, zsil2);
  k_spe_b<<<128,256,0,stream>>>(xc2T, spe_xproj_w, proj2);
  k_spe_c<<<512,256,0,stream>>>(xc2, zsil2, proj2, spe_dt_w, spe_dt_b,
      spe_Alog, spe_D, yg);
  k_spe_d<<<512,256,0,stream>>>(yg, spe_out_w, ws+WS_Y2, partSPE);
  k_red<<<16,256,0,stream>>>(partSPE, ws+WS_STATS+32, 256);
  k_fuse<<<4096,256,0,stream>>>(ws+WS_H1, ws+WS_H1PRE, ws+WS_Y2, ws+WS_STATS,
      spa_gn_g, spa_gn_b, spe_gn_g, spe_gn_b, fuse_w, cls_w, cls_b,
      ws+WS_FEAT, ws+WS_LOG);
  k_dw<<<4096,256,0,stream>>>(ws+WS_FEAT, ref_dw_w, ws+WS_Y, partDW);
  k_red<<<16,256,0,stream>>>(partDW, ws+WS_STATS+48, 2048);
  k_final<<<4096,256,0,stream>>>(ws+WS_Y, ws+WS_LOG, ws+WS_STATS,
      ref_gn_g, ref_gn_b, ref_pw_w, ref_pw_b, alpha, out);
  (void)in_sizes; (void)n_in; (void)out_size; (void)ws_size;
}

// Round 8
// 387.670 us; speedup vs baseline: 1.2718x; 1.0908x over previous
//
#include <hip/hip_runtime.h>
#include <math.h>

#define DEV __device__ __forceinline__

DEV float sigm(float x){ return 1.f/(1.f+__expf(-x)); }
DEV float siluf(float x){ return x * sigm(x); }
DEV float softplusf(float x){ return x > 20.f ? x : log1pf(__expf(x)); }

static constexpr float NG = 131072.0f;   // group-norm element count per (b,g)
static constexpr float LOG2E = 1.4426950408889634f;

// ---- workspace layout (offsets in floats) ----
static constexpr size_t WS_H1    = 0;          // B*HW*128
static constexpr size_t WS_H1PRE = 1048576;    // h1pre; later yproj
static constexpr size_t WS_XC    = 2097152;    // spa xc; later spe xc2
static constexpr size_t WS_ZSIL  = 4194304;    // spa zsil; later spe xc2T
static constexpr size_t WS_XZ    = 6291456;    // xz x-part; then proj[8192][40]; later spe zsil2
static constexpr size_t WS_QOFF  = 6619136;    // scan Q [512][4096] (2M; spans XZ tail + LOG head)
static constexpr size_t WS_LOG   = 8650752;    // logits (stride 16) — written by k_fuse
static constexpr size_t WS_Y     = 10485760;   // pe partials; delta (aliases y); y; spe yg; e_pre
static constexpr size_t WS_POFF  = 12582912;   // scan P / hs [512][4096] (2M); after: partials
static constexpr size_t WS_Y2    = 14155776;   // B*HW*128 (written by spe_d)
static constexpr size_t WS_FEAT  = 15204352;   // B*HW*128
static constexpr size_t WS_STATS = 16252928;   // 64 floats
static constexpr size_t WS_PEWT  = 16253056;   // 128*128
static constexpr size_t WS_INWT  = WS_PEWT  + 16384;
static constexpr size_t WS_OUTWT = WS_INWT  + 65536;

// ---------------- partial-stats reduction ----------------
__global__ void __launch_bounds__(256)
k_red(const float* __restrict__ part, float* __restrict__ outS, int half){
  __shared__ float red[4];
  int b = blockIdx.x >> 3, j = blockIdx.x & 7;
  float s = 0.f;
  for (int i = b*half + threadIdx.x; i < (b+1)*half; i += 256)
    s += part[(size_t)i*8 + j];
  s += __shfl_xor(s,1); s += __shfl_xor(s,2); s += __shfl_xor(s,4);
  s += __shfl_xor(s,8); s += __shfl_xor(s,16); s += __shfl_xor(s,32);
  if ((threadIdx.x & 63) == 0) red[threadIdx.x>>6] = s;
  __syncthreads();
  if (threadIdx.x == 0) outS[b*8+j] = red[0]+red[1]+red[2]+red[3];
}

// ---------------- transpose weights ----------------
__global__ void __launch_bounds__(256)
k_transpose(const float* __restrict__ pe_w, const float* __restrict__ in_w,
            const float* __restrict__ out_w,
            float* __restrict__ peT, float* __restrict__ inT,
            float* __restrict__ outT){
  int i0 = blockIdx.x*256 + threadIdx.x;
  int nt = gridDim.x*256;
  for (int k = i0; k < 128*128; k += nt){ int r = k >> 7, c = k & 127; peT[c*128 + r] = pe_w[k]; }
  for (int k = i0; k < 512*128; k += nt){ int r = k >> 7, c = k & 127; inT[c*512 + r] = in_w[k]; }
  for (int k = i0; k < 128*256; k += nt){ int r = k >> 8, c = k & 255; outT[c*128 + r] = out_w[k]; }
}

// ---------------- pe 1x1 conv (tiled GEMM 32x64) + GN partial stats ----------
__global__ void __launch_bounds__(256)
k_pe(const float* __restrict__ x, const float* __restrict__ peT,
     const float* __restrict__ pe_b, float* __restrict__ h1pre,
     float* __restrict__ part){
  __shared__ float As[16][36];
  __shared__ float Bs[16][64];
  __shared__ float red1[2][4], red2[2][4];
  int tid = threadIdx.x;
  int bx = blockIdx.x, by = blockIdx.y;
  int m0 = bx*32, n0 = by*64;
  int b = m0 >> 12, pl0 = m0 & 4095;
  int tx = tid & 15, ty = tid >> 4;
  float acc[2][4];
  #pragma unroll
  for (int i = 0; i < 2; i++)
    #pragma unroll
    for (int j = 0; j < 4; j++) acc[i][j] = 0.f;
  for (int k0 = 0; k0 < 128; k0 += 16){
    if (tid < 128){
      int k = tid >> 3, mm = (tid & 7)*4;
      float4 a = *(const float4*)(x + ((size_t)b*128 + k0+k)*4096 + pl0 + mm);
      *(float4*)&As[k][mm] = a;
    }
    {
      int k = tid >> 4, n = (tid & 15)*4;
      *(float4*)&Bs[k][n] = *(const float4*)(peT + (size_t)(k0+k)*128 + n0+n);
    }
    __syncthreads();
    #pragma unroll
    for (int k = 0; k < 16; k++){
      float2 av = *(const float2*)&As[k][ty*2];
      float4 bv = *(const float4*)&Bs[k][tx*4];
      acc[0][0] += av.x*bv.x; acc[0][1] += av.x*bv.y; acc[0][2] += av.x*bv.z; acc[0][3] += av.x*bv.w;
      acc[1][0] += av.y*bv.x; acc[1][1] += av.y*bv.y; acc[1][2] += av.y*bv.z; acc[1][3] += av.y*bv.w;
    }
    __syncthreads();
  }
  float4 bias = *(const float4*)(pe_b + n0 + tx*4);
  float s1 = 0.f, s2 = 0.f;
  #pragma unroll
  for (int i = 0; i < 2; i++){
    float4 st;
    st.x = acc[i][0]+bias.x; st.y = acc[i][1]+bias.y;
    st.z = acc[i][2]+bias.z; st.w = acc[i][3]+bias.w;
    s1 += st.x+st.y+st.z+st.w;
    s2 += st.x*st.x + st.y*st.y + st.z*st.z + st.w*st.w;
    *(float4*)(h1pre + (size_t)(m0 + ty*2 + i)*128 + n0 + tx*4) = st;
  }
  s1 += __shfl_xor(s1,1);  s2 += __shfl_xor(s2,1);
  s1 += __shfl_xor(s1,2);  s2 += __shfl_xor(s2,2);
  s1 += __shfl_xor(s1,4);  s2 += __shfl_xor(s2,4);
  s1 += __shfl_xor(s1,16); s2 += __shfl_xor(s2,16);
  s1 += __shfl_xor(s1,32); s2 += __shfl_xor(s2,32);
  int lane = tid & 63, w = tid >> 6;
  if ((lane & 55) == 0){
    int gl = (lane >> 3) & 1;
    red1[gl][w] = s1; red2[gl][w] = s2;
  }
  __syncthreads();
  if (tid < 8){
    int gg = tid >> 1, which = tid & 1;
    int gl = gg - by*2;
    float v = 0.f;
    if (gl == 0 || gl == 1){
      v = which ? (red2[gl][0]+red2[gl][1]+red2[gl][2]+red2[gl][3])
                : (red1[gl][0]+red1[gl][1]+red1[gl][2]+red1[gl][3]);
    }
    int pblk = b*256 + (bx & 127) + by*128;
    part[(size_t)pblk*8 + tid] = v;
  }
}

// ---------------- spa in-proj GEMM 64x64, fused GN+silu on A, z-silu out -----
__global__ void __launch_bounds__(256)
k_xz(const float* __restrict__ h1pre, const float* __restrict__ inT,
     const float* __restrict__ stats, const float* __restrict__ gng,
     const float* __restrict__ gnb, float* __restrict__ h1,
     float* __restrict__ xz, float* __restrict__ zsil){
  __shared__ float As[16][68];
  __shared__ float Bs[16][64];
  int tid = threadIdx.x;
  int m0 = blockIdx.x*64, n0 = blockIdx.y*64;
  int tx = tid & 15, ty = tid >> 4;
  float acc[4][4];
  #pragma unroll
  for (int i = 0; i < 4; i++)
    #pragma unroll
    for (int j = 0; j < 4; j++) acc[i][j] = 0.f;
  for (int k0 = 0; k0 < 128; k0 += 16){
    {
      int m = tid >> 2, kk = (tid & 3)*4;
      int pixm = m0 + m, c0 = k0 + kk;
      int bb = pixm >> 12, g = c0 >> 5;
      float4 a = *(const float4*)(h1pre + (size_t)pixm*128 + c0);
      float mu = stats[(bb*4+g)*2] * (1.f/NG);
      float var = stats[(bb*4+g)*2+1] * (1.f/NG) - mu*mu;
      float rs = rsqrtf(var + 1e-5f);
      float4 gg = *(const float4*)(gng + c0);
      float4 gb = *(const float4*)(gnb + c0);
      float4 v;
      v.x = siluf((a.x-mu)*rs*gg.x + gb.x);
      v.y = siluf((a.y-mu)*rs*gg.y + gb.y);
      v.z = siluf((a.z-mu)*rs*gg.z + gb.z);
      v.w = siluf((a.w-mu)*rs*gg.w + gb.w);
      As[kk+0][m] = v.x; As[kk+1][m] = v.y; As[kk+2][m] = v.z; As[kk+3][m] = v.w;
      if (blockIdx.y == 0) *(float4*)(h1 + (size_t)pixm*128 + c0) = v;
    }
    {
      int k = tid >> 4, n = (tid & 15)*4;
      *(float4*)&Bs[k][n] = *(const float4*)(inT + (size_t)(k0+k)*512 + n0+n);
    }
    __syncthreads();
    #pragma unroll
    for (int k = 0; k < 16; k++){
      float4 av = *(const float4*)&As[k][ty*4];
      float4 bv = *(const float4*)&Bs[k][tx*4];
      acc[0][0] += av.x*bv.x; acc[0][1] += av.x*bv.y; acc[0][2] += av.x*bv.z; acc[0][3] += av.x*bv.w;
      acc[1][0] += av.y*bv.x; acc[1][1] += av.y*bv.y; acc[1][2] += av.y*bv.z; acc[1][3] += av.y*bv.w;
      acc[2][0] += av.z*bv.x; acc[2][1] += av.z*bv.y; acc[2][2] += av.z*bv.z; acc[2][3] += av.z*bv.w;
      acc[3][0] += av.w*bv.x; acc[3][1] += av.w*bv.y; acc[3][2] += av.w*bv.z; acc[3][3] += av.w*bv.w;
    }
    __syncthreads();
  }
  if (n0 < 256){
    #pragma unroll
    for (int i = 0; i < 4; i++){
      float4 st; st.x = acc[i][0]; st.y = acc[i][1]; st.z = acc[i][2]; st.w = acc[i][3];
      *(float4*)(xz + (size_t)(m0 + ty*4 + i)*512 + n0 + tx*4) = st;
    }
  } else {
    #pragma unroll
    for (int i = 0; i < 4; i++){
      float4 st;
      st.x = siluf(acc[i][0]); st.y = siluf(acc[i][1]);
      st.z = siluf(acc[i][2]); st.w = siluf(acc[i][3]);
      *(float4*)(zsil + (size_t)(m0 + ty*4 + i)*256 + (n0-256) + tx*4) = st;
    }
  }
}

// ---------------- causal depthwise conv K=4 + silu (x-part only) -------------
__global__ void __launch_bounds__(256)
k_conv(const float* __restrict__ xz, const float* __restrict__ cw,
       const float* __restrict__ cb, float* __restrict__ xc){
  int idx = blockIdx.x*256 + threadIdx.x;
  int d = idx & 255;
  int l = (idx >> 8) & 4095;
  int b = idx >> 20;
  float v = cb[d];
  #pragma unroll
  for (int k = 0; k < 4; k++){
    int ls = l - 3 + k;
    if (ls >= 0) v += xz[(size_t)(b*4096 + ls)*512 + d] * cw[d*4 + k];
  }
  xc[idx] = siluf(v);
}

// ---------------- x-proj tiled GEMM: proj[tok][40] ----------------
__global__ void __launch_bounds__(256)
k_proj(const float* __restrict__ xc, const float* __restrict__ xpw,
       float* __restrict__ proj){
  __shared__ float As[32][33];
  int tid = threadIdx.x;
  int t = tid & 31;
  int jg = tid >> 5;
  int tok0 = blockIdx.x * 32;
  float acc[5];
  #pragma unroll
  for (int j = 0; j < 5; j++) acc[j] = 0.f;
  for (int k0 = 0; k0 < 256; k0 += 32){
    {
      int m = tid >> 3, kk = (tid & 7)*4;
      float4 a = *(const float4*)(xc + (size_t)(tok0+m)*256 + k0+kk);
      As[kk+0][m]=a.x; As[kk+1][m]=a.y; As[kk+2][m]=a.z; As[kk+3][m]=a.w;
    }
    __syncthreads();
    #pragma unroll
    for (int k4 = 0; k4 < 8; k4++){
      float a0 = As[k4*4+0][t];
      float a1 = As[k4*4+1][t];
      float a2 = As[k4*4+2][t];
      float a3 = As[k4*4+3][t];
      #pragma unroll
      for (int j = 0; j < 5; j++){
        float4 w = *(const float4*)(xpw + (size_t)(jg*5+j)*256 + k0 + k4*4);
        acc[j] += a0*w.x + a1*w.y + a2*w.z + a3*w.w;
      }
    }
    __syncthreads();
  }
  float* pr = proj + (size_t)(tok0+t)*40 + jg*5;
  #pragma unroll
  for (int j = 0; j < 5; j++) pr[j] = acc[j];
}

// ---------------- delta precompute: delta[tok][256] ----------------
// grid 2048; block = 4 tokens x 64 lanes; lane owns 4 d's.
__global__ void __launch_bounds__(256)
k_delta(const float* __restrict__ proj, const float* __restrict__ dtw,
        const float* __restrict__ dtb, float* __restrict__ delta){
  int tid = threadIdx.x;
  int tok = blockIdx.x*4 + (tid >> 6);
  int lane = tid & 63;
  int d0 = lane*4;
  const float4* pr4 = (const float4*)(proj + (size_t)tok*40);
  float4 p0 = pr4[0], p1 = pr4[1];
  float4 outv;
  float* po = (float*)&outv;
  #pragma unroll
  for (int j = 0; j < 4; j++){
    int d = d0 + j;
    const float4* wr = (const float4*)(dtw + (size_t)d*8);
    float4 w0 = wr[0], w1 = wr[1];
    float v = dtb[d] + p0.x*w0.x + p0.y*w0.y + p0.z*w0.z + p0.w*w0.w
                     + p1.x*w1.x + p1.y*w1.y + p1.z*w1.z + p1.w*w1.w;
    po[j] = softplusf(v);
  }
  *(float4*)(delta + (size_t)tok*256 + d0) = outv;
}

// ---------------- scan phase 1: thread=(d, n-quartet), 16-step chunks --------
// grid 2048 = 2b x 256chunk x 4dblk.
__global__ void __launch_bounds__(256)
k_scan1(const float* __restrict__ delta, const float* __restrict__ proj,
        const float* __restrict__ xc, const float* __restrict__ Alog,
        float* __restrict__ P, float* __restrict__ Q){
  int blk = blockIdx.x;
  int dblk = blk & 3;
  int bc = blk >> 2;                 // b*256 + chunk
  int b = bc >> 8, chunk = bc & 255;
  int tid = threadIdx.x;
  int dl = tid >> 2, ng = tid & 3;
  int d = dblk*64 + dl;
  float4 a4 = *(const float4*)(Alog + (size_t)d*16 + ng*4);
  float An[4] = {-__expf(a4.x)*LOG2E, -__expf(a4.y)*LOG2E,
                 -__expf(a4.z)*LOG2E, -__expf(a4.w)*LOG2E};
  float Pv[4] = {1.f,1.f,1.f,1.f}, Qv[4] = {0.f,0.f,0.f,0.f};
  size_t row0 = (size_t)(b*4096 + chunk*16);
  for (int l = 0; l < 16; l++){
    size_t r = row0 + l;
    float dv = delta[r*256 + d];
    float xv = xc[r*256 + d];
    float4 bm = *(const float4*)(proj + r*40 + 8 + ng*4);
    float dBx = dv*xv;
    float bmv[4] = {bm.x, bm.y, bm.z, bm.w};
    #pragma unroll
    for (int k = 0; k < 4; k++){
      float a = exp2f(dv*An[k]);
      Qv[k] = a*Qv[k] + bmv[k]*dBx;
      Pv[k] *= a;
    }
  }
  size_t o = (size_t)bc*4096 + dblk*1024 + tid*4;
  float4 pv; pv.x=Pv[0]; pv.y=Pv[1]; pv.z=Pv[2]; pv.w=Pv[3];
  float4 qv; qv.x=Qv[0]; qv.y=Qv[1]; qv.z=Qv[2]; qv.w=Qv[3];
  *(float4*)(P + o) = pv;
  *(float4*)(Q + o) = qv;
}

// ---------------- scan phase 2: 256-chunk scan; lane owns 4 chunks -----------
// grid 512: b = blk>>8, dn0 = (blk&255)*16. 16 chains/block. hs may alias P.
__global__ void __launch_bounds__(256)
k_scan2(const float* __restrict__ P, const float* __restrict__ Q,
        float* __restrict__ hs){
  __shared__ float Ps[256][17], Qs[256][17];
  int tid = threadIdx.x;
  int b = blockIdx.x >> 8;
  int dn0 = (blockIdx.x & 255) * 16;
  for (int i = tid; i < 1024; i += 256){
    int ch = i >> 2, g = (i & 3)*4;
    size_t gaddr = (size_t)(b*256+ch)*4096 + dn0 + g;
    float4 p = *(const float4*)(P + gaddr);
    float4 q = *(const float4*)(Q + gaddr);
    Ps[ch][g]=p.x; Ps[ch][g+1]=p.y; Ps[ch][g+2]=p.z; Ps[ch][g+3]=p.w;
    Qs[ch][g]=q.x; Qs[ch][g+1]=q.y; Qs[ch][g+2]=q.z; Qs[ch][g+3]=q.w;
  }
  __syncthreads();
  int lane = tid & 63, wv = tid >> 6;
  for (int rep = 0; rep < 4; rep++){
    int c = wv*4 + rep;
    float p0 = Ps[4*lane+0][c], q0 = Qs[4*lane+0][c];
    float p1 = Ps[4*lane+1][c], q1 = Qs[4*lane+1][c];
    float p2 = Ps[4*lane+2][c], q2 = Qs[4*lane+2][c];
    float p3 = Ps[4*lane+3][c], q3 = Qs[4*lane+3][c];
    float p = p0, q = q0;
    q = p1*q + q1; p *= p1;
    q = p2*q + q2; p *= p2;
    q = p3*q + q3; p *= p3;
    #pragma unroll
    for (int off = 1; off < 64; off <<= 1){
      float pp = __shfl_up(p, off);
      float qp = __shfl_up(q, off);
      if (lane >= off){ q = p*qp + q; p = p*pp; }
    }
    float h0 = __shfl_up(q, 1);
    if (lane == 0) h0 = 0.f;
    float h1 = p0*h0 + q0;
    float h2 = p1*h1 + q1;
    float h3 = p2*h2 + q2;
    Ps[4*lane+0][c] = h0;
    Ps[4*lane+1][c] = h1;
    Ps[4*lane+2][c] = h2;
    Ps[4*lane+3][c] = h3;
  }
  __syncthreads();
  for (int i = tid; i < 1024; i += 256){
    int ch = i >> 2, g = (i & 3)*4;
    size_t gaddr = (size_t)(b*256+ch)*4096 + dn0 + g;
    float4 h;
    h.x = Ps[ch][g]; h.y = Ps[ch][g+1]; h.z = Ps[ch][g+2]; h.w = Ps[ch][g+3];
    *(float4*)(hs + gaddr) = h;
  }
}

// ---------------- scan phase 3: replay + y; thread=(d, n-quartet) ------------
// NOTE: y may alias delta (read of [r,d] strictly precedes write of [r,d]).
__global__ void __launch_bounds__(256)
k_scan3(const float* __restrict__ delta, const float* __restrict__ proj,
        const float* __restrict__ xc, const float* __restrict__ zsil,
        const float* __restrict__ Alog, const float* __restrict__ Dv,
        const float* __restrict__ hs, float* __restrict__ y){
  int blk = blockIdx.x;
  int dblk = blk & 3;
  int bc = blk >> 2;
  int b = bc >> 8, chunk = bc & 255;
  int tid = threadIdx.x;
  int dl = tid >> 2, ng = tid & 3;
  int d = dblk*64 + dl;
  float4 a4 = *(const float4*)(Alog + (size_t)d*16 + ng*4);
  float An[4] = {-__expf(a4.x)*LOG2E, -__expf(a4.y)*LOG2E,
                 -__expf(a4.z)*LOG2E, -__expf(a4.w)*LOG2E};
  float Dd = Dv[d];
  float h[4];
  {
    size_t o = (size_t)bc*4096 + dblk*1024 + tid*4;
    float4 hv = *(const float4*)(hs + o);
    h[0]=hv.x; h[1]=hv.y; h[2]=hv.z; h[3]=hv.w;
  }
  size_t row0 = (size_t)(b*4096 + chunk*16);
  for (int l = 0; l < 16; l++){
    size_t r = row0 + l;
    float dv = delta[r*256 + d];
    float xv = xc[r*256 + d];
    float4 bm = *(const float4*)(proj + r*40 + 8 + ng*4);
    float4 cm = *(const float4*)(proj + r*40 + 24 + ng*4);
    float dBx = dv*xv;
    float bmv[4] = {bm.x, bm.y, bm.z, bm.w};
    float cmv[4] = {cm.x, cm.y, cm.z, cm.w};
    float ys = 0.f;
    #pragma unroll
    for (int k = 0; k < 4; k++){
      float a = exp2f(dv*An[k]);
      h[k] = a*h[k] + bmv[k]*dBx;
      ys += h[k]*cmv[k];
    }
    ys += __shfl_xor(ys, 1);
    ys += __shfl_xor(ys, 2);
    if (ng == 0){
      float zv = zsil[r*256 + d];
      y[r*256 + d] = (ys + Dd*xv) * zv;
    }
  }
}

// ---------------- spa out-proj: tiled GEMM 32x64 + GN partial stats ----------
__global__ void __launch_bounds__(256)
k_outproj(const float* __restrict__ y, const float* __restrict__ outT,
          float* __restrict__ yproj, float* __restrict__ part){
  __shared__ float As[16][36];
  __shared__ float Bs[16][64];
  __shared__ float red1[2][4], red2[2][4];
  int tid = threadIdx.x;
  int bx = blockIdx.x, by = blockIdx.y;
  int m0 = bx*32, n0 = by*64;
  int b = m0 >> 12;
  int tx = tid & 15, ty = tid >> 4;
  float acc[2][4];
  #pragma unroll
  for (int i = 0; i < 2; i++)
    #pragma unroll
    for (int j = 0; j < 4; j++) acc[i][j] = 0.f;
  for (int k0 = 0; k0 < 256; k0 += 16){
    if (tid < 128){
      int m = tid >> 2, kk = (tid & 3)*4;
      float4 a = *(const float4*)(y + (size_t)(m0+m)*256 + k0+kk);
      As[kk+0][m] = a.x; As[kk+1][m] = a.y; As[kk+2][m] = a.z; As[kk+3][m] = a.w;
    }
    {
      int k = tid >> 4, n = (tid & 15)*4;
      *(float4*)&Bs[k][n] = *(const float4*)(outT + (size_t)(k0+k)*128 + n0+n);
    }
    __syncthreads();
    #pragma unroll
    for (int k = 0; k < 16; k++){
      float2 av = *(const float2*)&As[k][ty*2];
      float4 bv = *(const float4*)&Bs[k][tx*4];
      acc[0][0] += av.x*bv.x; acc[0][1] += av.x*bv.y; acc[0][2] += av.x*bv.z; acc[0][3] += av.x*bv.w;
      acc[1][0] += av.y*bv.x; acc[1][1] += av.y*bv.y; acc[1][2] += av.y*bv.z; acc[1][3] += av.y*bv.w;
    }
    __syncthreads();
  }
  float s1 = 0.f, s2 = 0.f;
  #pragma unroll
  for (int i = 0; i < 2; i++){
    float4 st; st.x = acc[i][0]; st.y = acc[i][1]; st.z = acc[i][2]; st.w = acc[i][3];
    s1 += st.x+st.y+st.z+st.w;
    s2 += st.x*st.x + st.y*st.y + st.z*st.z + st.w*st.w;
    *(float4*)(yproj + (size_t)(m0 + ty*2 + i)*128 + n0 + tx*4) = st;
  }
  s1 += __shfl_xor(s1,1);  s2 += __shfl_xor(s2,1);
  s1 += __shfl_xor(s1,2);  s2 += __shfl_xor(s2,2);
  s1 += __shfl_xor(s1,4);  s2 += __shfl_xor(s2,4);
  s1 += __shfl_xor(s1,16); s2 += __shfl_xor(s2,16);
  s1 += __shfl_xor(s1,32); s2 += __shfl_xor(s2,32);
  int lane = tid & 63, w = tid >> 6;
  if ((lane & 55) == 0){
    int gl = (lane >> 3) & 1;
    red1[gl][w] = s1; red2[gl][w] = s2;
  }
  __syncthreads();
  if (tid < 8){
    int gg = tid >> 1, which = tid & 1;
    int gl = gg - by*2;
    float v = 0.f;
    if (gl == 0 || gl == 1){
      v = which ? (red2[gl][0]+red2[gl][1]+red2[gl][2]+red2[gl][3])
                : (red1[gl][0]+red1[gl][1]+red1[gl][2]+red1[gl][3]);
    }
    int pblk = b*256 + (bx & 127) + by*128;
    part[(size_t)pblk*8 + tid] = v;
  }
}

// ---------------- spe A: in-proj + conv + silu ----------
__global__ void __launch_bounds__(256)
k_spe_a(const float* __restrict__ h1, const float* __restrict__ in_w,
        const float* __restrict__ conv_w, const float* __restrict__ conv_b,
        float* __restrict__ xc2, float* __restrict__ xc2T,
        float* __restrict__ zsil2){
  __shared__ float s_in[4][128];
  int tid = threadIdx.x;
  int w = tid >> 6, lane = tid & 63;
  float wx[32], wz[32];
  {
    const float4* rx = (const float4*)(in_w + (size_t)lane*32);
    const float4* rz = (const float4*)(in_w + (size_t)(64+lane)*32);
    #pragma unroll
    for (int k = 0; k < 8; k++){
      float4 a = rx[k]; wx[k*4]=a.x; wx[k*4+1]=a.y; wx[k*4+2]=a.z; wx[k*4+3]=a.w;
      float4 b = rz[k]; wz[k*4]=b.x; wz[k*4+1]=b.y; wz[k*4+2]=b.z; wz[k*4+3]=b.w;
    }
  }
  float4 cwv = ((const float4*)conv_w)[lane];
  float cbv = conv_b[lane];
  for (int i = 0; i < 4; i++){
    int pix = blockIdx.x*16 + w*4 + i;
    float2 hv = ((const float2*)(h1 + (size_t)pix*128))[lane];
    s_in[w][2*lane] = hv.x; s_in[w][2*lane+1] = hv.y;
    float xpr[4], zs[4];
    #pragma unroll
    for (int l = 0; l < 4; l++){
      const float4* sv = (const float4*)&s_in[w][l*32];
      float ax = 0.f, az = 0.f;
      #pragma unroll
      for (int c4 = 0; c4 < 8; c4++){
        float4 v = sv[c4];
        ax += v.x*wx[c4*4] + v.y*wx[c4*4+1] + v.z*wx[c4*4+2] + v.w*wx[c4*4+3];
        az += v.x*wz[c4*4] + v.y*wz[c4*4+1] + v.z*wz[c4*4+2] + v.w*wz[c4*4+3];
      }
      xpr[l] = ax; zs[l] = siluf(az);
    }
    #pragma unroll
    for (int l = 0; l < 4; l++){
      float v = cbv;
      if (l >= 3) v += xpr[l-3]*cwv.x;
      if (l >= 2) v += xpr[l-2]*cwv.y;
      if (l >= 1) v += xpr[l-1]*cwv.z;
      v += xpr[l]*cwv.w;
      float sx = siluf(v);
      int tok = pix*4 + l;
      xc2 [(size_t)tok*64 + lane] = sx;
      xc2T[(size_t)lane*32768 + tok] = sx;
      zsil2[(size_t)tok*64 + lane] = zs[l];
    }
  }
}

// ---------------- spe B: x-proj GEMM, thread = token --------------------------
__global__ void __launch_bounds__(256)
k_spe_b(const float* __restrict__ xc2T, const float* __restrict__ xpw,
        float* __restrict__ proj){
  int tok = blockIdx.x*256 + threadIdx.x;
  float xcv[64];
  #pragma unroll 64
  for (int dd = 0; dd < 64; dd++) xcv[dd] = xc2T[(size_t)dd*32768 + tok];
  float* pr = proj + (size_t)tok*36;
  #pragma unroll 2
  for (int j = 0; j < 34; j++){
    const float4* wr = (const float4*)(xpw + j*64);
    float a = 0.f;
    #pragma unroll
    for (int k = 0; k < 16; k++){
      float4 wv = wr[k];
      a += xcv[k*4]*wv.x + xcv[k*4+1]*wv.y + xcv[k*4+2]*wv.z + xcv[k*4+3]*wv.w;
    }
    pr[j] = a;
  }
}

// ---------------- spe C: delta + scan + gate ----------
__global__ void __launch_bounds__(256)
k_spe_c(const float* __restrict__ xc2, const float* __restrict__ zsil2,
        const float* __restrict__ proj, const float* __restrict__ dt_w,
        const float* __restrict__ dt_b, const float* __restrict__ Alog,
        const float* __restrict__ Dvec, float* __restrict__ yg){
  int tid = threadIdx.x;
  int w = tid >> 6, lane = tid & 63;
  float2 dtwv = ((const float2*)dt_w)[lane];
  float dbv = dt_b[lane], Dd = Dvec[lane];
  float An[16];
  {
    const float4* ar = (const float4*)(Alog + (size_t)lane*16);
    #pragma unroll
    for (int k = 0; k < 4; k++){
      float4 a = ar[k];
      An[k*4]   = -__expf(a.x)*LOG2E; An[k*4+1] = -__expf(a.y)*LOG2E;
      An[k*4+2] = -__expf(a.z)*LOG2E; An[k*4+3] = -__expf(a.w)*LOG2E;
    }
  }
  for (int i = 0; i < 4; i++){
    int pix = blockIdx.x*16 + w*4 + i;
    float h[16];
    #pragma unroll
    for (int n = 0; n < 16; n++) h[n] = 0.f;
    #pragma unroll
    for (int l = 0; l < 4; l++){
      int tok = pix*4 + l;
      float pj[36];
      {
        const float4* pr = (const float4*)(proj + (size_t)tok*36);
        #pragma unroll
        for (int k = 0; k < 9; k++){
          float4 v = pr[k];
          pj[k*4]=v.x; pj[k*4+1]=v.y; pj[k*4+2]=v.z; pj[k*4+3]=v.w;
        }
      }
      float xv = xc2[(size_t)tok*64 + lane];
      float zv = zsil2[(size_t)tok*64 + lane];
      float dt = softplusf(dbv + pj[0]*dtwv.x + pj[1]*dtwv.y);
      float ys = 0.f;
      #pragma unroll
      for (int n = 0; n < 16; n++){
        float a = exp2f(dt * An[n]);
        h[n] = a*h[n] + dt * pj[2+n] * xv;
        ys += h[n] * pj[18+n];
      }
      yg[(size_t)tok*64 + lane] = (ys + Dd*xv) * zv;
    }
  }
}

// ---------------- spe D: out-proj GEMM + GN partial stats ---------------------
__global__ void __launch_bounds__(256)
k_spe_d(const float* __restrict__ yg, const float* __restrict__ out_w,
        float* __restrict__ y2, float* __restrict__ part){
  __shared__ float ldsWT[64*32];
  __shared__ float bst[8];
  int tid = threadIdx.x;
  for (int i = tid; i < 2048; i += 256){
    int c2 = i >> 6, dd = i & 63;
    ldsWT[dd*32 + c2] = out_w[i];
  }
  if (tid < 8) bst[tid] = 0.f;
  __syncthreads();
  int w = tid >> 6, lane = tid & 63;
  int c2 = lane & 31, slot = lane >> 5;
  int tokbase = blockIdx.x*64 + w*16 + slot;
  float acc[8];
  #pragma unroll
  for (int i = 0; i < 8; i++) acc[i] = 0.f;
  for (int dd4 = 0; dd4 < 16; dd4++){
    float w0 = ldsWT[(dd4*4+0)*32 + c2];
    float w1 = ldsWT[(dd4*4+1)*32 + c2];
    float w2 = ldsWT[(dd4*4+2)*32 + c2];
    float w3 = ldsWT[(dd4*4+3)*32 + c2];
    #pragma unroll
    for (int i = 0; i < 8; i++){
      int tok = tokbase + 2*i;
      float4 yv = ((const float4*)(yg + (size_t)tok*64))[dd4];
      acc[i] += yv.x*w0 + yv.y*w1 + yv.z*w2 + yv.w*w3;
    }
  }
  #pragma unroll
  for (int i = 0; i < 8; i++){
    int tok = tokbase + 2*i;
    int pix = tok >> 2, l = tok & 3;
    y2[(size_t)pix*128 + l*32 + c2] = acc[i];
    float s1 = acc[i], s2 = acc[i]*acc[i];
    s1 += __shfl_xor(s1,1);  s2 += __shfl_xor(s2,1);
    s1 += __shfl_xor(s1,2);  s2 += __shfl_xor(s2,2);
    s1 += __shfl_xor(s1,4);  s2 += __shfl_xor(s2,4);
    s1 += __shfl_xor(s1,8);  s2 += __shfl_xor(s2,8);
    s1 += __shfl_xor(s1,16); s2 += __shfl_xor(s2,16);
    if (c2 == 0){
      atomicAdd(&bst[l*2+0], s1);
      atomicAdd(&bst[l*2+1], s2);
    }
  }
  __syncthreads();
  if (tid < 8) part[(size_t)blockIdx.x*8 + tid] = bst[tid];
}

// ---------------- fuse: GN(spa)+GN(spe)+h1 -> feat, logits ----------------
__global__ void __launch_bounds__(256)
k_fuse(const float* __restrict__ h1, const float* __restrict__ yproj,
       const float* __restrict__ y2, const float* __restrict__ stats,
       const float* __restrict__ spa_g, const float* __restrict__ spa_b,
       const float* __restrict__ spe_g, const float* __restrict__ spe_b,
       const float* __restrict__ fuse_w, const float* __restrict__ cls_w,
       const float* __restrict__ cls_b, float* __restrict__ feat,
       float* __restrict__ logits){
  __shared__ float ft[2][128];
  int tid = threadIdx.x;
  int pixl = tid >> 7, c = tid & 127;
  int pix = blockIdx.x*2 + pixl;
  int b = pix >> 12, g = c >> 5;
  float m1 = stats[16 + (b*4+g)*2]   * (1.f/NG);
  float v1 = stats[16 + (b*4+g)*2+1] * (1.f/NG) - m1*m1;
  float m2 = stats[32 + (b*4+g)*2]   * (1.f/NG);
  float v2 = stats[32 + (b*4+g)*2+1] * (1.f/NG) - m2*m2;
  float h = h1[(size_t)pix*128 + c];
  float sa = siluf((yproj[(size_t)pix*128+c] - m1)*rsqrtf(v1+1e-5f)*spa_g[c] + spa_b[c]) + h;
  float sp = h + siluf((y2[(size_t)pix*128+c] - m2)*rsqrtf(v2+1e-5f)*spe_g[c] + spe_b[c]);
  float e0 = __expf(fuse_w[0]), e1 = __expf(fuse_w[1]);
  float w0 = e0/(e0+e1), w1 = e1/(e0+e1);
  float f = sa*w0 + sp*w1 + h;
  feat[(size_t)pix*128+c] = f;
  ft[pixl][c] = f;
  __syncthreads();
  if (tid < 20){
    int pl = (tid >= 10) ? 1 : 0;
    int o = tid - pl*10;
    float acc = cls_b[o];
    for (int cc = 0; cc < 128; cc++) acc += ft[pl][cc]*cls_w[o*128+cc];
    logits[(size_t)(blockIdx.x*2 + pl)*16 + o] = acc;
  }
}

// ---------------- depthwise 3x3 on feat + GN partial stats ----------------
__global__ void __launch_bounds__(256)
k_dw(const float* __restrict__ feat, const float* __restrict__ dww,
     float* __restrict__ epre, float* __restrict__ part){
  __shared__ float red1[4][64], red2[4][64];
  int tid = threadIdx.x;
  int pixl = tid >> 7, c = tid & 127;
  int pix = blockIdx.x*2 + pixl;
  int b = pix >> 12, p = pix & 4095, yy = p >> 6, xx = p & 63;
  float acc = 0.f;
  for (int dy = -1; dy <= 1; dy++){
    int ny = yy + dy; if (ny < 0 || ny > 63) continue;
    for (int dx = -1; dx <= 1; dx++){
      int nx = xx + dx; if (nx < 0 || nx > 63) continue;
      acc += feat[(size_t)((b<<12)|(ny<<6)|nx)*128 + c] * dww[c*9 + (dy+1)*3 + (dx+1)];
    }
  }
  epre[(size_t)pix*128 + c] = acc;
  int g = c >> 5;
  int idx = (c & 31) | (pixl << 5);
  red1[g][idx] = acc; red2[g][idx] = acc*acc;
  __syncthreads();
  int rg = tid >> 6, ridx = tid & 63;
  for (int s = 32; s >= 1; s >>= 1){
    if (ridx < s){ red1[rg][ridx] += red1[rg][ridx+s]; red2[rg][ridx] += red2[rg][ridx+s]; }
    __syncthreads();
  }
  if (ridx == 0){
    part[(size_t)blockIdx.x*8 + rg*2+0] = red1[rg][0];
    part[(size_t)blockIdx.x*8 + rg*2+1] = red2[rg][0];
  }
}

// ---------------- edge + local avg + final output ----------------
__global__ void __launch_bounds__(256)
k_final(const float* __restrict__ epre, const float* __restrict__ logits,
        const float* __restrict__ stats, const float* __restrict__ rg_g,
        const float* __restrict__ rg_b, const float* __restrict__ pw_w,
        const float* __restrict__ pw_b, const float* __restrict__ alpha,
        float* __restrict__ outp){
  __shared__ float part[4];
  __shared__ float edge_s[2];
  int tid = threadIdx.x;
  int pixl = tid >> 7, c = tid & 127;
  int pix = blockIdx.x*2 + pixl;
  int b = pix >> 12, p = pix & 4095, yy = p >> 6, xx = p & 63;
  int g = c >> 5;
  float m = stats[48 + (b*4+g)*2]   * (1.f/NG);
  float v = stats[48 + (b*4+g)*2+1] * (1.f/NG) - m*m;
  float e = epre[(size_t)pix*128+c];
  float en = siluf((e-m)*rsqrtf(v+1e-5f)*rg_g[c] + rg_b[c]);
  float pv = en * pw_w[c];
  pv += __shfl_xor(pv,1);  pv += __shfl_xor(pv,2);  pv += __shfl_xor(pv,4);
  pv += __shfl_xor(pv,8);  pv += __shfl_xor(pv,16); pv += __shfl_xor(pv,32);
  if ((tid & 63) == 0) part[tid>>6] = pv;
  __syncthreads();
  if (tid < 2) edge_s[tid] = sigm(part[tid*2] + part[tid*2+1] + pw_b[0]);
  __syncthreads();
  if (c < 10){
    float ed = edge_s[pixl];
    int o = c;
    float lg = logits[(size_t)pix*16 + o];
    float loc = 0.f;
    for (int dy = -1; dy <= 1; dy++){
      int ny = yy+dy; if (ny < 0 || ny > 63) continue;
      for (int dx = -1; dx <= 1; dx++){
        int nx = xx+dx; if (nx < 0 || nx > 63) continue;
        loc += logits[(size_t)((b<<12)|(ny<<6)|nx)*16 + o];
      }
    }
    loc *= (1.f/9.f);
    outp[(size_t)((b*10+o)<<12) + p] = lg + alpha[0]*(1.f-ed)*(loc - lg);
  }
}

extern "C" void kernel_launch(void* const* d_in, const int* in_sizes, int n_in,
                              void* d_out, int out_size, void* d_ws, size_t ws_size,
                              hipStream_t stream){
  const float* x          = (const float*)d_in[0];
  const float* pe_w       = (const float*)d_in[1];
  const float* pe_b       = (const float*)d_in[2];
  const float* pe_gn_g    = (const float*)d_in[3];
  const float* pe_gn_b    = (const float*)d_in[4];
  const float* spa_in_w   = (const float*)d_in[5];
  const float* spa_conv_w = (const float*)d_in[6];
  const float* spa_conv_b = (const float*)d_in[7];
  const float* spa_xproj_w= (const float*)d_in[8];
  const float* spa_dt_w   = (const float*)d_in[9];
  const float* spa_dt_b   = (const float*)d_in[10];
  const float* spa_Alog   = (const float*)d_in[11];
  const float* spa_D      = (const float*)d_in[12];
  const float* spa_out_w  = (const float*)d_in[13];
  const float* spa_gn_g   = (const float*)d_in[14];
  const float* spa_gn_b   = (const float*)d_in[15];
  const float* spe_in_w   = (const float*)d_in[16];
  const float* spe_conv_w = (const float*)d_in[17];
  const float* spe_conv_b = (const float*)d_in[18];
  const float* spe_xproj_w= (const float*)d_in[19];
  const float* spe_dt_w   = (const float*)d_in[20];
  const float* spe_dt_b   = (const float*)d_in[21];
  const float* spe_Alog   = (const float*)d_in[22];
  const float* spe_D      = (const float*)d_in[23];
  const float* spe_out_w  = (const float*)d_in[24];
  const float* spe_gn_g   = (const float*)d_in[25];
  const float* spe_gn_b   = (const float*)d_in[26];
  const float* fuse_w     = (const float*)d_in[27];
  const float* cls_w      = (const float*)d_in[28];
  const float* cls_b      = (const float*)d_in[29];
  const float* ref_dw_w   = (const float*)d_in[30];
  const float* ref_gn_g   = (const float*)d_in[31];
  const float* ref_gn_b   = (const float*)d_in[32];
  const float* ref_pw_w   = (const float*)d_in[33];
  const float* ref_pw_b   = (const float*)d_in[34];
  const float* alpha      = (const float*)d_in[35];
  float* ws  = (float*)d_ws;
  float* out = (float*)d_out;

  // scan buffers (chunk=16 -> 256 chunks): 2M floats each
  float* Pb    = ws + WS_POFF;   // [512][4096]; hs aliases Pb (scan2 in-place)
  float* Qb    = ws + WS_QOFF;   // [512][4096]
  float* HSb   = Pb;
  float* dely  = ws + WS_Y;      // delta aliases y (safe: per-(r,d) read-before-write)
  // partials
  float* partPE  = ws + WS_Y;          // used before k_delta overwrites
  float* partSPA = ws + WS_POFF;       // hs dead after scan3
  float* partSPE = ws + WS_POFF + 16384;
  float* partDW  = ws + WS_POFF + 65536;
  // proj + spe scratch
  float* proj  = ws + WS_XZ;           // 8192*40 = 327,680 floats
  float* xc2   = ws + WS_XC;
  float* xc2T  = ws + WS_ZSIL;
  float* zsil2 = ws + WS_XZ;           // proj dead after scan3
  float* proj2 = ws + WS_XZ + 2097152;
  float* yg    = ws + WS_Y;            // y dead after k_outproj

  k_transpose<<<64,256,0,stream>>>(pe_w, spa_in_w, spa_out_w,
      ws+WS_PEWT, ws+WS_INWT, ws+WS_OUTWT);
  k_pe<<<dim3(256,2),256,0,stream>>>(x, ws+WS_PEWT, pe_b, ws+WS_H1PRE, partPE);
  k_red<<<16,256,0,stream>>>(partPE, ws+WS_STATS+0, 256);
  k_xz<<<dim3(128,8),256,0,stream>>>(ws+WS_H1PRE, ws+WS_INWT, ws+WS_STATS,
      pe_gn_g, pe_gn_b, ws+WS_H1, ws+WS_XZ, ws+WS_ZSIL);
  k_conv<<<8192,256,0,stream>>>(ws+WS_XZ, spa_conv_w, spa_conv_b, ws+WS_XC);
  k_proj<<<256,256,0,stream>>>(ws+WS_XC, spa_xproj_w, proj);
  k_delta<<<2048,256,0,stream>>>(proj, spa_dt_w, spa_dt_b, dely);
  k_scan1<<<2048,256,0,stream>>>(dely, proj, ws+WS_XC, spa_Alog, Pb, Qb);
  k_scan2<<<512,256,0,stream>>>(Pb, Qb, HSb);
  k_scan3<<<2048,256,0,stream>>>(dely, proj, ws+WS_XC, ws+WS_ZSIL,
      spa_Alog, spa_D, HSb, dely /* y aliases delta */);
  k_outproj<<<dim3(256,2),256,0,stream>>>(dely, ws+WS_OUTWT, ws+WS_H1PRE, partSPA);
  k_red<<<16,256,0,stream>>>(partSPA, ws+WS_STATS+16, 256);
  k_spe_a<<<512,256,0,stream>>>(ws+WS_H1, spe_in_w, spe_conv_w, spe_conv_b,
      xc2, xc2T, zsil2);
  k_spe_b<<<128,256,0,stream>>>(xc2T, spe_xproj_w, proj2);
  k_spe_c<<<512,256,0,stream>>>(xc2, zsil2, proj2, spe_dt_w, spe_dt_b,
      spe_Alog, spe_D, yg);
  k_spe_d<<<512,256,0,stream>>>(yg, spe_out_w, ws+WS_Y2, partSPE);
  k_red<<<16,256,0,stream>>>(partSPE, ws+WS_STATS+32, 256);
  k_fuse<<<4096,256,0,stream>>>(ws+WS_H1, ws+WS_H1PRE, ws+WS_Y2, ws+WS_STATS,
      spa_gn_g, spa_gn_b, spe_gn_g, spe_gn_b, fuse_w, cls_w, cls_b,
      ws+WS_FEAT, ws+WS_LOG);
  k_dw<<<4096,256,0,stream>>>(ws+WS_FEAT, ref_dw_w, ws+WS_Y, partDW);
  k_red<<<16,256,0,stream>>>(partDW, ws+WS_STATS+48, 2048);
  k_final<<<4096,256,0,stream>>>(ws+WS_Y, ws+WS_LOG, ws+WS_STATS,
      ref_gn_g, ref_gn_b, ref_pw_w, ref_pw_b, alpha, out);
  (void)in_sizes; (void)n_in; (void)out_size; (void)ws_size;
}

// Round 9
// 384.120 us; speedup vs baseline: 1.2835x; 1.0092x over previous
//
#include <hip/hip_runtime.h>
#include <math.h>

#define DEV __device__ __forceinline__

DEV float sigm(float x){ return 1.f/(1.f+__expf(-x)); }
DEV float siluf(float x){ return x * sigm(x); }
DEV float softplusf(float x){ return x > 20.f ? x : log1pf(__expf(x)); }

static constexpr float NG = 131072.0f;   // group-norm element count per (b,g)
static constexpr float LOG2E = 1.4426950408889634f;

// ---- workspace layout (offsets in floats) ----
static constexpr size_t WS_H1    = 0;          // B*HW*128
static constexpr size_t WS_H1PRE = 1048576;    // h1pre; later yproj
static constexpr size_t WS_XC    = 2097152;    // spa xc; later spe xc2
static constexpr size_t WS_ZSIL  = 4194304;    // spa zsil; later spe xc2T
static constexpr size_t WS_XZ    = 6291456;    // xz x-part [8192][512] sparse; later Q/logits/spe scratch
static constexpr size_t WS_QOFF  = 6619136;    // scan Q [512][4096] (2M) — xz dead by scan1
static constexpr size_t WS_LOG   = 8650752;    // logits (stride 16) — written by k_fuse
static constexpr size_t WS_Y     = 10485760;   // pe partials; delta (aliases y); y; spe yg; e_pre
static constexpr size_t WS_POFF  = 12582912;   // scan P / hs (2M); after: partials
static constexpr size_t WS_Y2    = 14155776;   // B*HW*128 (written by spe_d)
static constexpr size_t WS_FEAT  = 15204352;   // proj[8192][40] (early); feat (late)
static constexpr size_t WS_STATS = 16252928;   // 64 floats

// ---------------- partial-stats reduction ----------------
__global__ void __launch_bounds__(256)
k_red(const float* __restrict__ part, float* __restrict__ outS, int half){
  __shared__ float red[4];
  int b = blockIdx.x >> 3, j = blockIdx.x & 7;
  float s = 0.f;
  for (int i = b*half + threadIdx.x; i < (b+1)*half; i += 256)
    s += part[(size_t)i*8 + j];
  s += __shfl_xor(s,1); s += __shfl_xor(s,2); s += __shfl_xor(s,4);
  s += __shfl_xor(s,8); s += __shfl_xor(s,16); s += __shfl_xor(s,32);
  if ((threadIdx.x & 63) == 0) red[threadIdx.x>>6] = s;
  __syncthreads();
  if (threadIdx.x == 0) outS[b*8+j] = red[0]+red[1]+red[2]+red[3];
}

// ---------------- pe 1x1 conv (tiled GEMM 32x64) + GN partial stats ----------
// grid dim3(2,256): bx = n-slice, by = m-tile (L2 locality: n-slices adjacent).
__global__ void __launch_bounds__(256)
k_pe(const float* __restrict__ x, const float* __restrict__ pe_w,
     const float* __restrict__ pe_b, float* __restrict__ h1pre,
     float* __restrict__ part){
  __shared__ float As[16][36];
  __shared__ float Bs[16][64];
  __shared__ float red1[2][4], red2[2][4];
  int tid = threadIdx.x;
  int nx = blockIdx.x, my = blockIdx.y;
  int m0 = my*32, n0 = nx*64;
  int b = m0 >> 12, pl0 = m0 & 4095;
  int tx = tid & 15, ty = tid >> 4;
  float acc[2][4];
  #pragma unroll
  for (int i = 0; i < 2; i++)
    #pragma unroll
    for (int j = 0; j < 4; j++) acc[i][j] = 0.f;
  for (int k0 = 0; k0 < 128; k0 += 16){
    if (tid < 128){
      int k = tid >> 3, mm = (tid & 7)*4;
      float4 a = *(const float4*)(x + ((size_t)b*128 + k0+k)*4096 + pl0 + mm);
      *(float4*)&As[k][mm] = a;
    }
    {
      int n = tid >> 2, kq = (tid & 3)*4;
      float4 a = *(const float4*)(pe_w + (size_t)(n0+n)*128 + k0 + kq);
      Bs[kq+0][n] = a.x; Bs[kq+1][n] = a.y; Bs[kq+2][n] = a.z; Bs[kq+3][n] = a.w;
    }
    __syncthreads();
    #pragma unroll
    for (int k = 0; k < 16; k++){
      float2 av = *(const float2*)&As[k][ty*2];
      float4 bv = *(const float4*)&Bs[k][tx*4];
      acc[0][0] += av.x*bv.x; acc[0][1] += av.x*bv.y; acc[0][2] += av.x*bv.z; acc[0][3] += av.x*bv.w;
      acc[1][0] += av.y*bv.x; acc[1][1] += av.y*bv.y; acc[1][2] += av.y*bv.z; acc[1][3] += av.y*bv.w;
    }
    __syncthreads();
  }
  float4 bias = *(const float4*)(pe_b + n0 + tx*4);
  float s1 = 0.f, s2 = 0.f;
  #pragma unroll
  for (int i = 0; i < 2; i++){
    float4 st;
    st.x = acc[i][0]+bias.x; st.y = acc[i][1]+bias.y;
    st.z = acc[i][2]+bias.z; st.w = acc[i][3]+bias.w;
    s1 += st.x+st.y+st.z+st.w;
    s2 += st.x*st.x + st.y*st.y + st.z*st.z + st.w*st.w;
    *(float4*)(h1pre + (size_t)(m0 + ty*2 + i)*128 + n0 + tx*4) = st;
  }
  s1 += __shfl_xor(s1,1);  s2 += __shfl_xor(s2,1);
  s1 += __shfl_xor(s1,2);  s2 += __shfl_xor(s2,2);
  s1 += __shfl_xor(s1,4);  s2 += __shfl_xor(s2,4);
  s1 += __shfl_xor(s1,16); s2 += __shfl_xor(s2,16);
  s1 += __shfl_xor(s1,32); s2 += __shfl_xor(s2,32);
  int lane = tid & 63, w = tid >> 6;
  if ((lane & 55) == 0){
    int gl = (lane >> 3) & 1;
    red1[gl][w] = s1; red2[gl][w] = s2;
  }
  __syncthreads();
  if (tid < 8){
    int gg = tid >> 1, which = tid & 1;
    int gl = gg - nx*2;
    float v = 0.f;
    if (gl == 0 || gl == 1){
      v = which ? (red2[gl][0]+red2[gl][1]+red2[gl][2]+red2[gl][3])
                : (red1[gl][0]+red1[gl][1]+red1[gl][2]+red1[gl][3]);
    }
    int pblk = b*256 + (my & 127)*2 + nx;
    part[(size_t)pblk*8 + tid] = v;
  }
}

// ---------------- spa in-proj GEMM 64x64, fused GN+silu on A, z-silu out -----
// grid dim3(8,128): bx = n-slice, by = m-tile.
__global__ void __launch_bounds__(256)
k_xz(const float* __restrict__ h1pre, const float* __restrict__ in_w,
     const float* __restrict__ stats, const float* __restrict__ gng,
     const float* __restrict__ gnb, float* __restrict__ h1,
     float* __restrict__ xz, float* __restrict__ zsil){
  __shared__ float As[16][68];
  __shared__ float Bs[16][64];
  int tid = threadIdx.x;
  int m0 = blockIdx.y*64, n0 = blockIdx.x*64;
  int tx = tid & 15, ty = tid >> 4;
  float acc[4][4];
  #pragma unroll
  for (int i = 0; i < 4; i++)
    #pragma unroll
    for (int j = 0; j < 4; j++) acc[i][j] = 0.f;
  for (int k0 = 0; k0 < 128; k0 += 16){
    {
      int m = tid >> 2, kk = (tid & 3)*4;
      int pixm = m0 + m, c0 = k0 + kk;
      int bb = pixm >> 12, g = c0 >> 5;
      float4 a = *(const float4*)(h1pre + (size_t)pixm*128 + c0);
      float mu = stats[(bb*4+g)*2] * (1.f/NG);
      float var = stats[(bb*4+g)*2+1] * (1.f/NG) - mu*mu;
      float rs = rsqrtf(var + 1e-5f);
      float4 gg = *(const float4*)(gng + c0);
      float4 gb = *(const float4*)(gnb + c0);
      float4 v;
      v.x = siluf((a.x-mu)*rs*gg.x + gb.x);
      v.y = siluf((a.y-mu)*rs*gg.y + gb.y);
      v.z = siluf((a.z-mu)*rs*gg.z + gb.z);
      v.w = siluf((a.w-mu)*rs*gg.w + gb.w);
      As[kk+0][m] = v.x; As[kk+1][m] = v.y; As[kk+2][m] = v.z; As[kk+3][m] = v.w;
      if (blockIdx.x == 0) *(float4*)(h1 + (size_t)pixm*128 + c0) = v;
    }
    {
      int n = tid >> 2, kq = (tid & 3)*4;
      float4 a = *(const float4*)(in_w + (size_t)(n0+n)*128 + k0 + kq);
      Bs[kq+0][n] = a.x; Bs[kq+1][n] = a.y; Bs[kq+2][n] = a.z; Bs[kq+3][n] = a.w;
    }
    __syncthreads();
    #pragma unroll
    for (int k = 0; k < 16; k++){
      float4 av = *(const float4*)&As[k][ty*4];
      float4 bv = *(const float4*)&Bs[k][tx*4];
      acc[0][0] += av.x*bv.x; acc[0][1] += av.x*bv.y; acc[0][2] += av.x*bv.z; acc[0][3] += av.x*bv.w;
      acc[1][0] += av.y*bv.x; acc[1][1] += av.y*bv.y; acc[1][2] += av.y*bv.z; acc[1][3] += av.y*bv.w;
      acc[2][0] += av.z*bv.x; acc[2][1] += av.z*bv.y; acc[2][2] += av.z*bv.z; acc[2][3] += av.z*bv.w;
      acc[3][0] += av.w*bv.x; acc[3][1] += av.w*bv.y; acc[3][2] += av.w*bv.z; acc[3][3] += av.w*bv.w;
    }
    __syncthreads();
  }
  if (n0 < 256){
    #pragma unroll
    for (int i = 0; i < 4; i++){
      float4 st; st.x = acc[i][0]; st.y = acc[i][1]; st.z = acc[i][2]; st.w = acc[i][3];
      *(float4*)(xz + (size_t)(m0 + ty*4 + i)*512 + n0 + tx*4) = st;
    }
  } else {
    #pragma unroll
    for (int i = 0; i < 4; i++){
      float4 st;
      st.x = siluf(acc[i][0]); st.y = siluf(acc[i][1]);
      st.z = siluf(acc[i][2]); st.w = siluf(acc[i][3]);
      *(float4*)(zsil + (size_t)(m0 + ty*4 + i)*256 + (n0-256) + tx*4) = st;
    }
  }
}

// ---------------- fused conv + x-proj: xc + proj[tok][40] ----------------
// grid 512; block = 16 tokens.
__global__ void __launch_bounds__(256)
k_projc(const float* __restrict__ xz, const float* __restrict__ cw,
        const float* __restrict__ cb, const float* __restrict__ xpw,
        float* __restrict__ xc, float* __restrict__ proj){
  __shared__ float xct[16*260];
  int tid = threadIdx.x;
  int m0 = blockIdx.x * 16;
  {
    int slot = tid >> 6, lane = tid & 63;
    int d4 = lane*4;
    float4 cbv = *(const float4*)(cb + d4);
    float4 cw0 = *(const float4*)(cw + (size_t)(d4+0)*4);
    float4 cw1 = *(const float4*)(cw + (size_t)(d4+1)*4);
    float4 cw2 = *(const float4*)(cw + (size_t)(d4+2)*4);
    float4 cw3 = *(const float4*)(cw + (size_t)(d4+3)*4);
    const float* c0p = (const float*)&cw0;
    const float* c1p = (const float*)&cw1;
    const float* c2p = (const float*)&cw2;
    const float* c3p = (const float*)&cw3;
    for (int i = 0; i < 4; i++){
      int t = slot*4 + i;
      int tok = m0 + t;
      int l = tok & 4095;
      float4 acc = cbv;
      #pragma unroll
      for (int k = 0; k < 4; k++){
        int ls = l - 3 + k;
        if (ls >= 0){
          float4 xv = *(const float4*)(xz + (size_t)(tok-3+k)*512 + d4);
          acc.x += xv.x * c0p[k];
          acc.y += xv.y * c1p[k];
          acc.z += xv.z * c2p[k];
          acc.w += xv.w * c3p[k];
        }
      }
      float4 s;
      s.x = siluf(acc.x); s.y = siluf(acc.y); s.z = siluf(acc.z); s.w = siluf(acc.w);
      *(float4*)&xct[t*260 + d4] = s;
      *(float4*)(xc + (size_t)tok*256 + d4) = s;
    }
  }
  __syncthreads();
  {
    int t = tid & 15, jq = tid >> 4;
    int tok = m0 + t;
    float a0 = 0.f, a1 = 0.f, a2 = 0.f;
    for (int k0 = 0; k0 < 256; k0 += 4){
      float4 av = *(const float4*)&xct[t*260 + k0];
      float4 w0 = *(const float4*)(xpw + (size_t)jq*256 + k0);
      float4 w1 = *(const float4*)(xpw + (size_t)(jq+16)*256 + k0);
      a0 += av.x*w0.x + av.y*w0.y + av.z*w0.z + av.w*w0.w;
      a1 += av.x*w1.x + av.y*w1.y + av.z*w1.z + av.w*w1.w;
      if (jq < 8){
        float4 w2 = *(const float4*)(xpw + (size_t)(jq+32)*256 + k0);
        a2 += av.x*w2.x + av.y*w2.y + av.z*w2.z + av.w*w2.w;
      }
    }
    float* pr = proj + (size_t)tok*40;
    pr[jq] = a0;
    pr[jq+16] = a1;
    if (jq < 8) pr[jq+32] = a2;
  }
}

// ---------------- delta precompute: delta[tok][256] ----------------
__global__ void __launch_bounds__(256)
k_delta(const float* __restrict__ proj, const float* __restrict__ dtw,
        const float* __restrict__ dtb, float* __restrict__ delta){
  int tid = threadIdx.x;
  int tok = blockIdx.x*4 + (tid >> 6);
  int lane = tid & 63;
  int d0 = lane*4;
  const float4* pr4 = (const float4*)(proj + (size_t)tok*40);
  float4 p0 = pr4[0], p1 = pr4[1];
  float4 outv;
  float* po = (float*)&outv;
  #pragma unroll
  for (int j = 0; j < 4; j++){
    int d = d0 + j;
    const float4* wr = (const float4*)(dtw + (size_t)d*8);
    float4 w0 = wr[0], w1 = wr[1];
    float v = dtb[d] + p0.x*w0.x + p0.y*w0.y + p0.z*w0.z + p0.w*w0.w
                     + p1.x*w1.x + p1.y*w1.y + p1.z*w1.z + p1.w*w1.w;
    po[j] = softplusf(v);
  }
  *(float4*)(delta + (size_t)tok*256 + d0) = outv;
}

// ---------------- scan phase 1: thread=(d, n-quartet), 16-step chunks --------
__global__ void __launch_bounds__(256)
k_scan1(const float* __restrict__ delta, const float* __restrict__ proj,
        const float* __restrict__ xc, const float* __restrict__ Alog,
        float* __restrict__ P, float* __restrict__ Q){
  int blk = blockIdx.x;
  int dblk = blk & 3;
  int bc = blk >> 2;
  int b = bc >> 8, chunk = bc & 255;
  int tid = threadIdx.x;
  int dl = tid >> 2, ng = tid & 3;
  int d = dblk*64 + dl;
  float4 a4 = *(const float4*)(Alog + (size_t)d*16 + ng*4);
  float An[4] = {-__expf(a4.x)*LOG2E, -__expf(a4.y)*LOG2E,
                 -__expf(a4.z)*LOG2E, -__expf(a4.w)*LOG2E};
  float Pv[4] = {1.f,1.f,1.f,1.f}, Qv[4] = {0.f,0.f,0.f,0.f};
  size_t row0 = (size_t)(b*4096 + chunk*16);
  for (int l = 0; l < 16; l++){
    size_t r = row0 + l;
    float dv = delta[r*256 + d];
    float xv = xc[r*256 + d];
    float4 bm = *(const float4*)(proj + r*40 + 8 + ng*4);
    float dBx = dv*xv;
    float bmv[4] = {bm.x, bm.y, bm.z, bm.w};
    #pragma unroll
    for (int k = 0; k < 4; k++){
      float a = exp2f(dv*An[k]);
      Qv[k] = a*Qv[k] + bmv[k]*dBx;
      Pv[k] *= a;
    }
  }
  size_t o = (size_t)bc*4096 + dblk*1024 + tid*4;
  float4 pv; pv.x=Pv[0]; pv.y=Pv[1]; pv.z=Pv[2]; pv.w=Pv[3];
  float4 qv; qv.x=Qv[0]; qv.y=Qv[1]; qv.z=Qv[2]; qv.w=Qv[3];
  *(float4*)(P + o) = pv;
  *(float4*)(Q + o) = qv;
}

// ---------------- scan phase 2: 256-chunk scan; lane owns 4 chunks -----------
__global__ void __launch_bounds__(256)
k_scan2(const float* __restrict__ P, const float* __restrict__ Q,
        float* __restrict__ hs){
  __shared__ float Ps[256][17], Qs[256][17];
  int tid = threadIdx.x;
  int b = blockIdx.x >> 8;
  int dn0 = (blockIdx.x & 255) * 16;
  for (int i = tid; i < 1024; i += 256){
    int ch = i >> 2, g = (i & 3)*4;
    size_t gaddr = (size_t)(b*256+ch)*4096 + dn0 + g;
    float4 p = *(const float4*)(P + gaddr);
    float4 q = *(const float4*)(Q + gaddr);
    Ps[ch][g]=p.x; Ps[ch][g+1]=p.y; Ps[ch][g+2]=p.z; Ps[ch][g+3]=p.w;
    Qs[ch][g]=q.x; Qs[ch][g+1]=q.y; Qs[ch][g+2]=q.z; Qs[ch][g+3]=q.w;
  }
  __syncthreads();
  int lane = tid & 63, wv = tid >> 6;
  for (int rep = 0; rep < 4; rep++){
    int c = wv*4 + rep;
    float p0 = Ps[4*lane+0][c], q0 = Qs[4*lane+0][c];
    float p1 = Ps[4*lane+1][c], q1 = Qs[4*lane+1][c];
    float p2 = Ps[4*lane+2][c], q2 = Qs[4*lane+2][c];
    float p3 = Ps[4*lane+3][c], q3 = Qs[4*lane+3][c];
    float p = p0, q = q0;
    q = p1*q + q1; p *= p1;
    q = p2*q + q2; p *= p2;
    q = p3*q + q3; p *= p3;
    #pragma unroll
    for (int off = 1; off < 64; off <<= 1){
      float pp = __shfl_up(p, off);
      float qp = __shfl_up(q, off);
      if (lane >= off){ q = p*qp + q; p = p*pp; }
    }
    float h0 = __shfl_up(q, 1);
    if (lane == 0) h0 = 0.f;
    float h1 = p0*h0 + q0;
    float h2 = p1*h1 + q1;
    float h3 = p2*h2 + q2;
    Ps[4*lane+0][c] = h0;
    Ps[4*lane+1][c] = h1;
    Ps[4*lane+2][c] = h2;
    Ps[4*lane+3][c] = h3;
  }
  __syncthreads();
  for (int i = tid; i < 1024; i += 256){
    int ch = i >> 2, g = (i & 3)*4;
    size_t gaddr = (size_t)(b*256+ch)*4096 + dn0 + g;
    float4 h;
    h.x = Ps[ch][g]; h.y = Ps[ch][g+1]; h.z = Ps[ch][g+2]; h.w = Ps[ch][g+3];
    *(float4*)(hs + gaddr) = h;
  }
}

// ---------------- scan phase 3: replay + y; thread=(d, n-quartet) ------------
__global__ void __launch_bounds__(256)
k_scan3(const float* __restrict__ delta, const float* __restrict__ proj,
        const float* __restrict__ xc, const float* __restrict__ zsil,
        const float* __restrict__ Alog, const float* __restrict__ Dv,
        const float* __restrict__ hs, float* __restrict__ y){
  int blk = blockIdx.x;
  int dblk = blk & 3;
  int bc = blk >> 2;
  int b = bc >> 8, chunk = bc & 255;
  int tid = threadIdx.x;
  int dl = tid >> 2, ng = tid & 3;
  int d = dblk*64 + dl;
  float4 a4 = *(const float4*)(Alog + (size_t)d*16 + ng*4);
  float An[4] = {-__expf(a4.x)*LOG2E, -__expf(a4.y)*LOG2E,
                 -__expf(a4.z)*LOG2E, -__expf(a4.w)*LOG2E};
  float Dd = Dv[d];
  float h[4];
  {
    size_t o = (size_t)bc*4096 + dblk*1024 + tid*4;
    float4 hv = *(const float4*)(hs + o);
    h[0]=hv.x; h[1]=hv.y; h[2]=hv.z; h[3]=hv.w;
  }
  size_t row0 = (size_t)(b*4096 + chunk*16);
  for (int l = 0; l < 16; l++){
    size_t r = row0 + l;
    float dv = delta[r*256 + d];
    float xv = xc[r*256 + d];
    float4 bm = *(const float4*)(proj + r*40 + 8 + ng*4);
    float4 cm = *(const float4*)(proj + r*40 + 24 + ng*4);
    float dBx = dv*xv;
    float bmv[4] = {bm.x, bm.y, bm.z, bm.w};
    float cmv[4] = {cm.x, cm.y, cm.z, cm.w};
    float ys = 0.f;
    #pragma unroll
    for (int k = 0; k < 4; k++){
      float a = exp2f(dv*An[k]);
      h[k] = a*h[k] + bmv[k]*dBx;
      ys += h[k]*cmv[k];
    }
    ys += __shfl_xor(ys, 1);
    ys += __shfl_xor(ys, 2);
    if (ng == 0){
      float zv = zsil[r*256 + d];
      y[r*256 + d] = (ys + Dd*xv) * zv;
    }
  }
}

// ---------------- spa out-proj: tiled GEMM 32x64 + GN partial stats ----------
// grid dim3(2,256): bx = n-slice, by = m-tile.
__global__ void __launch_bounds__(256)
k_outproj(const float* __restrict__ y, const float* __restrict__ out_w,
          float* __restrict__ yproj, float* __restrict__ part){
  __shared__ float As[16][36];
  __shared__ float Bs[16][64];
  __shared__ float red1[2][4], red2[2][4];
  int tid = threadIdx.x;
  int nx = blockIdx.x, my = blockIdx.y;
  int m0 = my*32, n0 = nx*64;
  int b = m0 >> 12;
  int tx = tid & 15, ty = tid >> 4;
  float acc[2][4];
  #pragma unroll
  for (int i = 0; i < 2; i++)
    #pragma unroll
    for (int j = 0; j < 4; j++) acc[i][j] = 0.f;
  for (int k0 = 0; k0 < 256; k0 += 16){
    if (tid < 128){
      int m = tid >> 2, kk = (tid & 3)*4;
      float4 a = *(const float4*)(y + (size_t)(m0+m)*256 + k0+kk);
      As[kk+0][m] = a.x; As[kk+1][m] = a.y; As[kk+2][m] = a.z; As[kk+3][m] = a.w;
    }
    {
      int n = tid >> 2, kq = (tid & 3)*4;
      float4 a = *(const float4*)(out_w + (size_t)(n0+n)*256 + k0 + kq);
      Bs[kq+0][n] = a.x; Bs[kq+1][n] = a.y; Bs[kq+2][n] = a.z; Bs[kq+3][n] = a.w;
    }
    __syncthreads();
    #pragma unroll
    for (int k = 0; k < 16; k++){
      float2 av = *(const float2*)&As[k][ty*2];
      float4 bv = *(const float4*)&Bs[k][tx*4];
      acc[0][0] += av.x*bv.x; acc[0][1] += av.x*bv.y; acc[0][2] += av.x*bv.z; acc[0][3] += av.x*bv.w;
      acc[1][0] += av.y*bv.x; acc[1][1] += av.y*bv.y; acc[1][2] += av.y*bv.z; acc[1][3] += av.y*bv.w;
    }
    __syncthreads();
  }
  float s1 = 0.f, s2 = 0.f;
  #pragma unroll
  for (int i = 0; i < 2; i++){
    float4 st; st.x = acc[i][0]; st.y = acc[i][1]; st.z = acc[i][2]; st.w = acc[i][3];
    s1 += st.x+st.y+st.z+st.w;
    s2 += st.x*st.x + st.y*st.y + st.z*st.z + st.w*st.w;
    *(float4*)(yproj + (size_t)(m0 + ty*2 + i)*128 + n0 + tx*4) = st;
  }
  s1 += __shfl_xor(s1,1);  s2 += __shfl_xor(s2,1);
  s1 += __shfl_xor(s1,2);  s2 += __shfl_xor(s2,2);
  s1 += __shfl_xor(s1,4);  s2 += __shfl_xor(s2,4);
  s1 += __shfl_xor(s1,16); s2 += __shfl_xor(s2,16);
  s1 += __shfl_xor(s1,32); s2 += __shfl_xor(s2,32);
  int lane = tid & 63, w = tid >> 6;
  if ((lane & 55) == 0){
    int gl = (lane >> 3) & 1;
    red1[gl][w] = s1; red2[gl][w] = s2;
  }
  __syncthreads();
  if (tid < 8){
    int gg = tid >> 1, which = tid & 1;
    int gl = gg - nx*2;
    float v = 0.f;
    if (gl == 0 || gl == 1){
      v = which ? (red2[gl][0]+red2[gl][1]+red2[gl][2]+red2[gl][3])
                : (red1[gl][0]+red1[gl][1]+red1[gl][2]+red1[gl][3]);
    }
    int pblk = b*256 + (my & 127)*2 + nx;
    part[(size_t)pblk*8 + tid] = v;
  }
}

// ---------------- spe A: in-proj + conv + silu ----------
__global__ void __launch_bounds__(256)
k_spe_a(const float* __restrict__ h1, const float* __restrict__ in_w,
        const float* __restrict__ conv_w, const float* __restrict__ conv_b,
        float* __restrict__ xc2, float* __restrict__ xc2T,
        float* __restrict__ zsil2){
  __shared__ float s_in[4][128];
  int tid = threadIdx.x;
  int w = tid >> 6, lane = tid & 63;
  float wx[32], wz[32];
  {
    const float4* rx = (const float4*)(in_w + (size_t)lane*32);
    const float4* rz = (const float4*)(in_w + (size_t)(64+lane)*32);
    #pragma unroll
    for (int k = 0; k < 8; k++){
      float4 a = rx[k]; wx[k*4]=a.x; wx[k*4+1]=a.y; wx[k*4+2]=a.z; wx[k*4+3]=a.w;
      float4 b = rz[k]; wz[k*4]=b.x; wz[k*4+1]=b.y; wz[k*4+2]=b.z; wz[k*4+3]=b.w;
    }
  }
  float4 cwv = ((const float4*)conv_w)[lane];
  float cbv = conv_b[lane];
  for (int i = 0; i < 4; i++){
    int pix = blockIdx.x*16 + w*4 + i;
    float2 hv = ((const float2*)(h1 + (size_t)pix*128))[lane];
    s_in[w][2*lane] = hv.x; s_in[w][2*lane+1] = hv.y;
    float xpr[4], zs[4];
    #pragma unroll
    for (int l = 0; l < 4; l++){
      const float4* sv = (const float4*)&s_in[w][l*32];
      float ax = 0.f, az = 0.f;
      #pragma unroll
      for (int c4 = 0; c4 < 8; c4++){
        float4 v = sv[c4];
        ax += v.x*wx[c4*4] + v.y*wx[c4*4+1] + v.z*wx[c4*4+2] + v.w*wx[c4*4+3];
        az += v.x*wz[c4*4] + v.y*wz[c4*4+1] + v.z*wz[c4*4+2] + v.w*wz[c4*4+3];
      }
      xpr[l] = ax; zs[l] = siluf(az);
    }
    #pragma unroll
    for (int l = 0; l < 4; l++){
      float v = cbv;
      if (l >= 3) v += xpr[l-3]*cwv.x;
      if (l >= 2) v += xpr[l-2]*cwv.y;
      if (l >= 1) v += xpr[l-1]*cwv.z;
      v += xpr[l]*cwv.w;
      float sx = siluf(v);
      int tok = pix*4 + l;
      xc2 [(size_t)tok*64 + lane] = sx;
      xc2T[(size_t)lane*32768 + tok] = sx;
      zsil2[(size_t)tok*64 + lane] = zs[l];
    }
  }
}

// ---------------- spe B: x-proj GEMM, thread = token --------------------------
__global__ void __launch_bounds__(256)
k_spe_b(const float* __restrict__ xc2T, const float* __restrict__ xpw,
        float* __restrict__ proj){
  int tok = blockIdx.x*256 + threadIdx.x;
  float xcv[64];
  #pragma unroll 64
  for (int dd = 0; dd < 64; dd++) xcv[dd] = xc2T[(size_t)dd*32768 + tok];
  float* pr = proj + (size_t)tok*36;
  #pragma unroll 2
  for (int j = 0; j < 34; j++){
    const float4* wr = (const float4*)(xpw + j*64);
    float a = 0.f;
    #pragma unroll
    for (int k = 0; k < 16; k++){
      float4 wv = wr[k];
      a += xcv[k*4]*wv.x + xcv[k*4+1]*wv.y + xcv[k*4+2]*wv.z + xcv[k*4+3]*wv.w;
    }
    pr[j] = a;
  }
}

// ---------------- spe C: delta + scan + gate ----------
__global__ void __launch_bounds__(256)
k_spe_c(const float* __restrict__ xc2, const float* __restrict__ zsil2,
        const float* __restrict__ proj, const float* __restrict__ dt_w,
        const float* __restrict__ dt_b, const float* __restrict__ Alog,
        const float* __restrict__ Dvec, float* __restrict__ yg){
  int tid = threadIdx.x;
  int w = tid >> 6, lane = tid & 63;
  float2 dtwv = ((const float2*)dt_w)[lane];
  float dbv = dt_b[lane], Dd = Dvec[lane];
  float An[16];
  {
    const float4* ar = (const float4*)(Alog + (size_t)lane*16);
    #pragma unroll
    for (int k = 0; k < 4; k++){
      float4 a = ar[k];
      An[k*4]   = -__expf(a.x)*LOG2E; An[k*4+1] = -__expf(a.y)*LOG2E;
      An[k*4+2] = -__expf(a.z)*LOG2E; An[k*4+3] = -__expf(a.w)*LOG2E;
    }
  }
  for (int i = 0; i < 4; i++){
    int pix = blockIdx.x*16 + w*4 + i;
    float h[16];
    #pragma unroll
    for (int n = 0; n < 16; n++) h[n] = 0.f;
    #pragma unroll
    for (int l = 0; l < 4; l++){
      int tok = pix*4 + l;
      float pj[36];
      {
        const float4* pr = (const float4*)(proj + (size_t)tok*36);
        #pragma unroll
        for (int k = 0; k < 9; k++){
          float4 v = pr[k];
          pj[k*4]=v.x; pj[k*4+1]=v.y; pj[k*4+2]=v.z; pj[k*4+3]=v.w;
        }
      }
      float xv = xc2[(size_t)tok*64 + lane];
      float zv = zsil2[(size_t)tok*64 + lane];
      float dt = softplusf(dbv + pj[0]*dtwv.x + pj[1]*dtwv.y);
      float ys = 0.f;
      #pragma unroll
      for (int n = 0; n < 16; n++){
        float a = exp2f(dt * An[n]);
        h[n] = a*h[n] + dt * pj[2+n] * xv;
        ys += h[n] * pj[18+n];
      }
      yg[(size_t)tok*64 + lane] = (ys + Dd*xv) * zv;
    }
  }
}

// ---------------- spe D: out-proj GEMM + GN partial stats ---------------------
__global__ void __launch_bounds__(256)
k_spe_d(const float* __restrict__ yg, const float* __restrict__ out_w,
        float* __restrict__ y2, float* __restrict__ part){
  __shared__ float ldsWT[64*32];
  __shared__ float bst[8];
  int tid = threadIdx.x;
  for (int i = tid; i < 2048; i += 256){
    int c2 = i >> 6, dd = i & 63;
    ldsWT[dd*32 + c2] = out_w[i];
  }
  if (tid < 8) bst[tid] = 0.f;
  __syncthreads();
  int w = tid >> 6, lane = tid & 63;
  int c2 = lane & 31, slot = lane >> 5;
  int tokbase = blockIdx.x*64 + w*16 + slot;
  float acc[8];
  #pragma unroll
  for (int i = 0; i < 8; i++) acc[i] = 0.f;
  for (int dd4 = 0; dd4 < 16; dd4++){
    float w0 = ldsWT[(dd4*4+0)*32 + c2];
    float w1 = ldsWT[(dd4*4+1)*32 + c2];
    float w2 = ldsWT[(dd4*4+2)*32 + c2];
    float w3 = ldsWT[(dd4*4+3)*32 + c2];
    #pragma unroll
    for (int i = 0; i < 8; i++){
      int tok = tokbase + 2*i;
      float4 yv = ((const float4*)(yg + (size_t)tok*64))[dd4];
      acc[i] += yv.x*w0 + yv.y*w1 + yv.z*w2 + yv.w*w3;
    }
  }
  #pragma unroll
  for (int i = 0; i < 8; i++){
    int tok = tokbase + 2*i;
    int pix = tok >> 2, l = tok & 3;
    y2[(size_t)pix*128 + l*32 + c2] = acc[i];
    float s1 = acc[i], s2 = acc[i]*acc[i];
    s1 += __shfl_xor(s1,1);  s2 += __shfl_xor(s2,1);
    s1 += __shfl_xor(s1,2);  s2 += __shfl_xor(s2,2);
    s1 += __shfl_xor(s1,4);  s2 += __shfl_xor(s2,4);
    s1 += __shfl_xor(s1,8);  s2 += __shfl_xor(s2,8);
    s1 += __shfl_xor(s1,16); s2 += __shfl_xor(s2,16);
    if (c2 == 0){
      atomicAdd(&bst[l*2+0], s1);
      atomicAdd(&bst[l*2+1], s2);
    }
  }
  __syncthreads();
  if (tid < 8) part[(size_t)blockIdx.x*8 + tid] = bst[tid];
}

// ---------------- fuse: GN(spa)+GN(spe)+h1 -> feat, logits ----------------
__global__ void __launch_bounds__(256)
k_fuse(const float* __restrict__ h1, const float* __restrict__ yproj,
       const float* __restrict__ y2, const float* __restrict__ stats,
       const float* __restrict__ spa_g, const float* __restrict__ spa_b,
       const float* __restrict__ spe_g, const float* __restrict__ spe_b,
       const float* __restrict__ fuse_w, const float* __restrict__ cls_w,
       const float* __restrict__ cls_b, float* __restrict__ feat,
       float* __restrict__ logits){
  __shared__ float ft[2][128];
  int tid = threadIdx.x;
  int pixl = tid >> 7, c = tid & 127;
  int pix = blockIdx.x*2 + pixl;
  int b = pix >> 12, g = c >> 5;
  float m1 = stats[16 + (b*4+g)*2]   * (1.f/NG);
  float v1 = stats[16 + (b*4+g)*2+1] * (1.f/NG) - m1*m1;
  float m2 = stats[32 + (b*4+g)*2]   * (1.f/NG);
  float v2 = stats[32 + (b*4+g)*2+1] * (1.f/NG) - m2*m2;
  float h = h1[(size_t)pix*128 + c];
  float sa = siluf((yproj[(size_t)pix*128+c] - m1)*rsqrtf(v1+1e-5f)*spa_g[c] + spa_b[c]) + h;
  float sp = h + siluf((y2[(size_t)pix*128+c] - m2)*rsqrtf(v2+1e-5f)*spe_g[c] + spe_b[c]);
  float e0 = __expf(fuse_w[0]), e1 = __expf(fuse_w[1]);
  float w0 = e0/(e0+e1), w1 = e1/(e0+e1);
  float f = sa*w0 + sp*w1 + h;
  feat[(size_t)pix*128+c] = f;
  ft[pixl][c] = f;
  __syncthreads();
  if (tid < 20){
    int pl = (tid >= 10) ? 1 : 0;
    int o = tid - pl*10;
    float acc = cls_b[o];
    for (int cc = 0; cc < 128; cc++) acc += ft[pl][cc]*cls_w[o*128+cc];
    logits[(size_t)(blockIdx.x*2 + pl)*16 + o] = acc;
  }
}

// ---------------- depthwise 3x3, LDS-tiled 8x8 + halo, + GN partials ---------
// grid 128 = 2b x 8ty x 8tx.
__global__ void __launch_bounds__(256)
k_dw(const float* __restrict__ feat, const float* __restrict__ dww,
     float* __restrict__ epre, float* __restrict__ part){
  __shared__ float ft[100*128];
  __shared__ float red1[4][64], red2[4][64];
  int tid = threadIdx.x;
  int blk = blockIdx.x;
  int b = blk >> 6, ty = (blk >> 3) & 7, tx = blk & 7;
  for (int idx = tid; idx < 100*128; idx += 256){
    int row = idx >> 7, c = idx & 127;
    int r10 = row / 10, c10 = row - r10*10;
    int ry = ty*8 + r10 - 1, rx = tx*8 + c10 - 1;
    float v = 0.f;
    if (ry >= 0 && ry < 64 && rx >= 0 && rx < 64)
      v = feat[(size_t)((b<<12)|(ry<<6)|rx)*128 + c];
    ft[idx] = v;
  }
  __syncthreads();
  int c = tid & 127, pl = tid >> 7;
  float w[9];
  #pragma unroll
  for (int k = 0; k < 9; k++) w[k] = dww[c*9+k];
  float s1 = 0.f, s2 = 0.f;
  for (int i = 0; i < 32; i++){
    int pixl = i*2 + pl;
    int py = pixl >> 3, px = pixl & 7;
    float acc = 0.f;
    #pragma unroll
    for (int dy = 0; dy < 3; dy++)
      #pragma unroll
      for (int dx = 0; dx < 3; dx++)
        acc += ft[((py+dy)*10 + (px+dx))*128 + c] * w[dy*3+dx];
    epre[(size_t)((b<<12)|((ty*8+py)<<6)|(tx*8+px))*128 + c] = acc;
    s1 += acc; s2 += acc*acc;
  }
  int g = c >> 5;
  int idx = (c & 31) | (pl << 5);
  red1[g][idx] = s1; red2[g][idx] = s2;
  __syncthreads();
  int rg = tid >> 6, ridx = tid & 63;
  for (int s = 32; s >= 1; s >>= 1){
    if (ridx < s){ red1[rg][ridx] += red1[rg][ridx+s]; red2[rg][ridx] += red2[rg][ridx+s]; }
    __syncthreads();
  }
  if (ridx == 0){
    part[(size_t)blk*8 + rg*2+0] = red1[rg][0];
    part[(size_t)blk*8 + rg*2+1] = red2[rg][0];
  }
}

// ---------------- edge + local avg + final output ----------------
__global__ void __launch_bounds__(256)
k_final(const float* __restrict__ epre, const float* __restrict__ logits,
        const float* __restrict__ stats, const float* __restrict__ rg_g,
        const float* __restrict__ rg_b, const float* __restrict__ pw_w,
        const float* __restrict__ pw_b, const float* __restrict__ alpha,
        float* __restrict__ outp){
  __shared__ float part[4];
  __shared__ float edge_s[2];
  int tid = threadIdx.x;
  int pixl = tid >> 7, c = tid & 127;
  int pix = blockIdx.x*2 + pixl;
  int b = pix >> 12, p = pix & 4095, yy = p >> 6, xx = p & 63;
  int g = c >> 5;
  float m = stats[48 + (b*4+g)*2]   * (1.f/NG);
  float v = stats[48 + (b*4+g)*2+1] * (1.f/NG) - m*m;
  float e = epre[(size_t)pix*128+c];
  float en = siluf((e-m)*rsqrtf(v+1e-5f)*rg_g[c] + rg_b[c]);
  float pv = en * pw_w[c];
  pv += __shfl_xor(pv,1);  pv += __shfl_xor(pv,2);  pv += __shfl_xor(pv,4);
  pv += __shfl_xor(pv,8);  pv += __shfl_xor(pv,16); pv += __shfl_xor(pv,32);
  if ((tid & 63) == 0) part[tid>>6] = pv;
  __syncthreads();
  if (tid < 2) edge_s[tid] = sigm(part[tid*2] + part[tid*2+1] + pw_b[0]);
  __syncthreads();
  if (c < 10){
    float ed = edge_s[pixl];
    int o = c;
    float lg = logits[(size_t)pix*16 + o];
    float loc = 0.f;
    for (int dy = -1; dy <= 1; dy++){
      int ny = yy+dy; if (ny < 0 || ny > 63) continue;
      for (int dx = -1; dx <= 1; dx++){
        int nx = xx+dx; if (nx < 0 || nx > 63) continue;
        loc += logits[(size_t)((b<<12)|(ny<<6)|nx)*16 + o];
      }
    }
    loc *= (1.f/9.f);
    outp[(size_t)((b*10+o)<<12) + p] = lg + alpha[0]*(1.f-ed)*(loc - lg);
  }
}

extern "C" void kernel_launch(void* const* d_in, const int* in_sizes, int n_in,
                              void* d_out, int out_size, void* d_ws, size_t ws_size,
                              hipStream_t stream){
  const float* x          = (const float*)d_in[0];
  const float* pe_w       = (const float*)d_in[1];
  const float* pe_b       = (const float*)d_in[2];
  const float* pe_gn_g    = (const float*)d_in[3];
  const float* pe_gn_b    = (const float*)d_in[4];
  const float* spa_in_w   = (const float*)d_in[5];
  const float* spa_conv_w = (const float*)d_in[6];
  const float* spa_conv_b = (const float*)d_in[7];
  const float* spa_xproj_w= (const float*)d_in[8];
  const float* spa_dt_w   = (const float*)d_in[9];
  const float* spa_dt_b   = (const float*)d_in[10];
  const float* spa_Alog   = (const float*)d_in[11];
  const float* spa_D      = (const float*)d_in[12];
  const float* spa_out_w  = (const float*)d_in[13];
  const float* spa_gn_g   = (const float*)d_in[14];
  const float* spa_gn_b   = (const float*)d_in[15];
  const float* spe_in_w   = (const float*)d_in[16];
  const float* spe_conv_w = (const float*)d_in[17];
  const float* spe_conv_b = (const float*)d_in[18];
  const float* spe_xproj_w= (const float*)d_in[19];
  const float* spe_dt_w   = (const float*)d_in[20];
  const float* spe_dt_b   = (const float*)d_in[21];
  const float* spe_Alog   = (const float*)d_in[22];
  const float* spe_D      = (const float*)d_in[23];
  const float* spe_out_w  = (const float*)d_in[24];
  const float* spe_gn_g   = (const float*)d_in[25];
  const float* spe_gn_b   = (const float*)d_in[26];
  const float* fuse_w     = (const float*)d_in[27];
  const float* cls_w      = (const float*)d_in[28];
  const float* cls_b      = (const float*)d_in[29];
  const float* ref_dw_w   = (const float*)d_in[30];
  const float* ref_gn_g   = (const float*)d_in[31];
  const float* ref_gn_b   = (const float*)d_in[32];
  const float* ref_pw_w   = (const float*)d_in[33];
  const float* ref_pw_b   = (const float*)d_in[34];
  const float* alpha      = (const float*)d_in[35];
  float* ws  = (float*)d_ws;
  float* out = (float*)d_out;

  float* Pb    = ws + WS_POFF;   // hs aliases Pb (scan2 in-place)
  float* Qb    = ws + WS_QOFF;   // xz dead once k_projc completes
  float* HSb   = Pb;
  float* dely  = ws + WS_Y;      // delta aliases y (read-before-write per (r,d))
  float* partPE  = ws + WS_Y;          // consumed by k_red before k_delta overwrites
  float* partSPA = ws + WS_POFF;       // hs dead after scan3
  float* partSPE = ws + WS_POFF + 16384;
  float* partDW  = ws + WS_POFF + 65536;
  float* proj  = ws + WS_FEAT;         // feat written only later by k_fuse
  float* xc2   = ws + WS_XC;
  float* xc2T  = ws + WS_ZSIL;
  float* zsil2 = ws + WS_XZ;           // xz/Q dead by spe_a
  float* proj2 = ws + WS_XZ + 2097152;
  float* yg    = ws + WS_Y;            // y dead after k_outproj

  k_pe<<<dim3(2,256),256,0,stream>>>(x, pe_w, pe_b, ws+WS_H1PRE, partPE);
  k_red<<<16,256,0,stream>>>(partPE, ws+WS_STATS+0, 256);
  k_xz<<<dim3(8,128),256,0,stream>>>(ws+WS_H1PRE, spa_in_w, ws+WS_STATS,
      pe_gn_g, pe_gn_b, ws+WS_H1, ws+WS_XZ, ws+WS_ZSIL);
  k_projc<<<512,256,0,stream>>>(ws+WS_XZ, spa_conv_w, spa_conv_b, spa_xproj_w,
      ws+WS_XC, proj);
  k_delta<<<2048,256,0,stream>>>(proj, spa_dt_w, spa_dt_b, dely);
  k_scan1<<<2048,256,0,stream>>>(dely, proj, ws+WS_XC, spa_Alog, Pb, Qb);
  k_scan2<<<512,256,0,stream>>>(Pb, Qb, HSb);
  k_scan3<<<2048,256,0,stream>>>(dely, proj, ws+WS_XC, ws+WS_ZSIL,
      spa_Alog, spa_D, HSb, dely);
  k_outproj<<<dim3(2,256),256,0,stream>>>(dely, spa_out_w, ws+WS_H1PRE, partSPA);
  k_red<<<16,256,0,stream>>>(partSPA, ws+WS_STATS+16, 256);
  k_spe_a<<<512,256,0,stream>>>(ws+WS_H1, spe_in_w, spe_conv_w, spe_conv_b,
      xc2, xc2T, zsil2);
  k_spe_b<<<128,256,0,stream>>>(xc2T, spe_xproj_w, proj2);
  k_spe_c<<<512,256,0,stream>>>(xc2, zsil2, proj2, spe_dt_w, spe_dt_b,
      spe_Alog, spe_D, yg);
  k_spe_d<<<512,256,0,stream>>>(yg, spe_out_w, ws+WS_Y2, partSPE);
  k_red<<<16,256,0,stream>>>(partSPE, ws+WS_STATS+32, 256);
  k_fuse<<<4096,256,0,stream>>>(ws+WS_H1, ws+WS_H1PRE, ws+WS_Y2, ws+WS_STATS,
      spa_gn_g, spa_gn_b, spe_gn_g, spe_gn_b, fuse_w, cls_w, cls_b,
      ws+WS_FEAT, ws+WS_LOG);
  k_dw<<<128,256,0,stream>>>(ws+WS_FEAT, ref_dw_w, ws+WS_Y, partDW);
  k_red<<<16,256,0,stream>>>(partDW, ws+WS_STATS+48, 64);
  k_final<<<4096,256,0,stream>>>(ws+WS_Y, ws+WS_LOG, ws+WS_STATS,
      ref_gn_g, ref_gn_b, ref_pw_w, ref_pw_b, alpha, out);
  (void)in_sizes; (void)n_in; (void)out_size; (void)ws_size;
}